// Round 12
// baseline (716.801 us; speedup 1.0000x reference)
//
#include <hip/hip_runtime.h>
#include <math.h>

#define B_   128
#define L_   197
#define C_   768
#define Nv_  196
#define Lt_  32
#define Ct_  512
#define H_   12
#define DH_  64
#define DPP_ 256
#define MTOK 25088   // B_*Nv_

typedef __attribute__((ext_vector_type(8))) short bf16x8_t;
typedef __attribute__((ext_vector_type(4))) float f32x4_t;

// split fp32 -> bf16 hi (truncate) + bf16 lo (RNE of remainder)
__device__ __forceinline__ void split_bf16(float a, unsigned &h, unsigned &l) {
    unsigned u = __float_as_uint(a);
    unsigned hu = u & 0xffff0000u;
    h = hu >> 16;
    float lf = a - __uint_as_float(hu);
    unsigned ul = __float_as_uint(lf);
    l = (ul + 0x7fffu + ((ul >> 16) & 1u)) >> 16;
}

__device__ __forceinline__ void split8_pack(const float* av, uint4& Hh, uint4& Ll) {
    unsigned hv[8], lv[8];
#pragma unroll
    for (int j = 0; j < 8; ++j) split_bf16(av[j], hv[j], lv[j]);
    Hh.x = hv[0] | (hv[1] << 16); Hh.y = hv[2] | (hv[3] << 16);
    Hh.z = hv[4] | (hv[5] << 16); Hh.w = hv[6] | (hv[7] << 16);
    Ll.x = lv[0] | (lv[1] << 16); Ll.y = lv[2] | (lv[3] << 16);
    Ll.z = lv[4] | (lv[5] << 16); Ll.w = lv[6] | (lv[7] << 16);
}

// ---------------------------------------------------------------------------
// fused weight pre-split (all 5 weights in one launch) — r9-verified
// ---------------------------------------------------------------------------
#define NWQ 589824
#define NWK 393216
#define NWD 196608
__global__ __launch_bounds__(256)
void split_all(const float* __restrict__ Wq, const float* __restrict__ W1,
               const float* __restrict__ Wk, const float* __restrict__ Wv,
               const float* __restrict__ Wd,
               short* __restrict__ Wq_h, short* __restrict__ Wq_l,
               short* __restrict__ W1_h, short* __restrict__ W1_l,
               short* __restrict__ Wk_h, short* __restrict__ Wk_l,
               short* __restrict__ Wv_h, short* __restrict__ Wv_l,
               short* __restrict__ Wd_h, short* __restrict__ Wd_l)
{
    int j = blockIdx.x * 256 + threadIdx.x;   // total 2,162,688 = 8448*256
    const float* src; short *hi, *lo;
    if (j < NWQ)                { src = Wq; hi = Wq_h; lo = Wq_l; }
    else if ((j -= NWQ) < NWQ)  { src = W1; hi = W1_h; lo = W1_l; }
    else if ((j -= NWQ) < NWK)  { src = Wk; hi = Wk_h; lo = Wk_l; }
    else if ((j -= NWK) < NWK)  { src = Wv; hi = Wv_h; lo = Wv_l; }
    else                        { j -= NWK;  src = Wd; hi = Wd_h; lo = Wd_l; }
    unsigned h, l;
    split_bf16(src[j], h, l);
    hi[j] = (short)h; lo[j] = (short)l;
}

// ---------------------------------------------------------------------------
// activation pre-splits (one pass, vectorized) — r11
// ---------------------------------------------------------------------------
__global__ __launch_bounds__(256)
void split_x(const float* __restrict__ x, short* __restrict__ Xh,
             short* __restrict__ Xl)
{
    int idx = blockIdx.x * 256 + threadIdx.x;    // 2,408,448 chunks of 8
    int m = idx / 96, c8 = (idx - m * 96) * 8;
    int b = m / Nv_, n = m - b * Nv_;
    const float* src = x + ((size_t)(n + 1) * B_ + b) * C_ + c8;
    float av[8];
    *(float4*)&av[0] = *(const float4*)src;
    *(float4*)&av[4] = *(const float4*)(src + 4);
    uint4 Hh, Ll;
    split8_pack(av, Hh, Ll);
    *(uint4*)&Xh[(size_t)m * C_ + c8] = Hh;
    *(uint4*)&Xl[(size_t)m * C_ + c8] = Ll;
}

__global__ __launch_bounds__(256)
void split_text(const float* __restrict__ t, short* __restrict__ Th,
                short* __restrict__ Tl)
{
    int idx = blockIdx.x * 256 + threadIdx.x;    // 262,144 chunks of 8
    const float* src = t + (size_t)idx * 8;
    float av[8];
    *(float4*)&av[0] = *(const float4*)src;
    *(float4*)&av[4] = *(const float4*)(src + 4);
    uint4 Hh, Ll;
    split8_pack(av, Hh, Ll);
    *(uint4*)&Th[(size_t)idx * 8] = Hh;
    *(uint4*)&Tl[(size_t)idx * 8] = Ll;
}

// ---------------------------------------------------------------------------
// 3-term split-bf16 MFMA GEMM, all operands pre-split (r11-verified).
// ---------------------------------------------------------------------------
template<int EPI>
__global__ __launch_bounds__(256)
void mfma_gemm(const short* __restrict__ Ah_g, const short* __restrict__ Al_g,
               const short* __restrict__ Bh_g, const short* __restrict__ Bl_g,
               const float* __restrict__ bias,
               float* __restrict__ Cst, int Nst, int Kd,
               const float* __restrict__ W2, float* __restrict__ partials,
               const short* Bh2, const short* Bl2, const float* bias2,
               float* Cst2)
{
    if (blockIdx.z) { Bh_g = Bh2; Bl_g = Bl2; bias = bias2; Cst = Cst2; }
    __shared__ short Ah[128 * 40], Al[128 * 40], Bh[128 * 40], Bl[128 * 40];
    const int tid = threadIdx.x;
    const int m0 = blockIdx.x * 128, n0 = blockIdx.y * 128;
    const int l = tid & 63, wid = tid >> 6;
    const int wr = wid >> 1, wc = wid & 1;
    const int lr = l & 15, lq = l >> 4;

    const int srow = tid >> 2;
    const int p8 = (tid & 3) << 3;
    const short *ahp[2], *alp[2], *bhp[2], *blp[2];
    int abase[2];
#pragma unroll
    for (int i = 0; i < 2; ++i) {
        int row = srow + i * 64;
        abase[i] = row * 40 + p8;
        int gr = m0 + row;
        int gc = n0 + row;
        ahp[i] = Ah_g + (size_t)gr * Kd + p8;
        alp[i] = Al_g + (size_t)gr * Kd + p8;
        bhp[i] = Bh_g + (size_t)gc * Kd + p8;
        blp[i] = Bl_g + (size_t)gc * Kd + p8;
    }

    f32x4_t acc[4][4];
#pragma unroll
    for (int m = 0; m < 4; ++m)
#pragma unroll
        for (int n = 0; n < 4; ++n) {
            acc[m][n][0] = 0.f; acc[m][n][1] = 0.f;
            acc[m][n][2] = 0.f; acc[m][n][3] = 0.f;
        }

    for (int k0 = 0; k0 < Kd; k0 += 32) {
#pragma unroll
        for (int i = 0; i < 2; ++i) {
            *(uint4*)&Ah[abase[i]] = *(const uint4*)(ahp[i] + k0);
            *(uint4*)&Al[abase[i]] = *(const uint4*)(alp[i] + k0);
            *(uint4*)&Bh[abase[i]] = *(const uint4*)(bhp[i] + k0);
            *(uint4*)&Bl[abase[i]] = *(const uint4*)(blp[i] + k0);
        }
        __syncthreads();

        bf16x8_t ahf[4], alf[4], bhf[4], blf[4];
#pragma unroll
        for (int m = 0; m < 4; ++m) {
            int ro = (wr * 64 + m * 16 + lr) * 40 + lq * 8;
            ahf[m] = *(const bf16x8_t*)&Ah[ro];
            alf[m] = *(const bf16x8_t*)&Al[ro];
        }
#pragma unroll
        for (int n = 0; n < 4; ++n) {
            int ro = (wc * 64 + n * 16 + lr) * 40 + lq * 8;
            bhf[n] = *(const bf16x8_t*)&Bh[ro];
            blf[n] = *(const bf16x8_t*)&Bl[ro];
        }
#pragma unroll
        for (int m = 0; m < 4; ++m)
#pragma unroll
            for (int n = 0; n < 4; ++n) {
                acc[m][n] = __builtin_amdgcn_mfma_f32_16x16x32_bf16(ahf[m], bhf[n], acc[m][n], 0, 0, 0);
                acc[m][n] = __builtin_amdgcn_mfma_f32_16x16x32_bf16(ahf[m], blf[n], acc[m][n], 0, 0, 0);
                acc[m][n] = __builtin_amdgcn_mfma_f32_16x16x32_bf16(alf[m], bhf[n], acc[m][n], 0, 0, 0);
            }
        __syncthreads();
    }

    if constexpr (EPI == 0) {
#pragma unroll
        for (int n = 0; n < 4; ++n) {
            int col = n0 + wc * 64 + n * 16 + lr;
            float bv = bias ? bias[col] : 0.f;
#pragma unroll
            for (int m = 0; m < 4; ++m) {
                int rowb = m0 + wr * 64 + m * 16 + lq * 4;
#pragma unroll
                for (int r = 0; r < 4; ++r)
                    Cst[(size_t)(rowb + r) * Nst + col] = acc[m][n][r] + bv;
            }
        }
    } else {
        int coln[4]; float b1v[4], w20[4], w21[4];
#pragma unroll
        for (int n = 0; n < 4; ++n) {
            coln[n] = n0 + wc * 64 + n * 16 + lr;
            b1v[n] = bias[coln[n]];
            w20[n] = W2[coln[n]];
            w21[n] = W2[C_ + coln[n]];
        }
        const int pi = (blockIdx.y * 2 + wc) * 2;
#pragma unroll
        for (int m = 0; m < 4; ++m)
#pragma unroll
            for (int r = 0; r < 4; ++r) {
                float p0 = 0.f, p1 = 0.f;
#pragma unroll
                for (int n = 0; n < 4; ++n) {
                    float h = acc[m][n][r] + b1v[n];
                    float gl = h / (1.f + expf(-1.702f * h));
                    p0 = fmaf(gl, w20[n], p0);
                    p1 = fmaf(gl, w21[n], p1);
                }
#pragma unroll
                for (int off = 8; off; off >>= 1) {
                    p0 += __shfl_xor(p0, off, 16);
                    p1 += __shfl_xor(p1, off, 16);
                }
                if (lr == 0) {
                    int row = m0 + wr * 64 + m * 16 + lq * 4 + r;
                    partials[(size_t)row * 24 + pi + 0] = p0;
                    partials[(size_t)row * 24 + pi + 1] = p1;
                }
            }
    }
}

// ---------------------------------------------------------------------------
// fp32 NT GEMM (batched gram only). r5-verified.
// ---------------------------------------------------------------------------
template<int GATHER_A, int BOUNDS, int EPI>
__global__ __launch_bounds__(256)
void gemm_nt(const float* __restrict__ A, const float* __restrict__ Bm,
             const float* __restrict__ bias, float* __restrict__ C,
             int M, int N, int K, float scale,
             long strideA, long strideC,
             const float* __restrict__ W2, float* __restrict__ partials)
{
    __shared__ float As[16][132];
    __shared__ float Bs[16][132];
    const int tid = threadIdx.x;
    const int tx = tid & 15, ty = tid >> 4;
    const int m0 = blockIdx.x * 128, n0 = blockIdx.y * 128;
    const int bz = blockIdx.z;
    const float* Ab = A  + (size_t)bz * strideA;
    const float* Bb = Bm + (size_t)bz * strideA;
    float* Cb = C + (size_t)bz * strideC;

    const int lrow = tid >> 2;
    const int lk   = (tid & 3) << 2;

    const float* aptr[2]; const float* bptr[2];
    bool aval[2], bval[2];
#pragma unroll
    for (int Lq = 0; Lq < 2; ++Lq) {
        int row = lrow + Lq * 64;
        int gr = m0 + row;
        aval[Lq] = (!BOUNDS) || (gr < M);
        aptr[Lq] = Ab + (size_t)(aval[Lq] ? gr : 0) * K + lk;
        int gc = n0 + row;
        bval[Lq] = (!BOUNDS) || (gc < N);
        bptr[Lq] = Bb + (size_t)(bval[Lq] ? gc : 0) * K + lk;
    }

    float acc[8][8];
#pragma unroll
    for (int r = 0; r < 8; ++r)
#pragma unroll
        for (int c = 0; c < 8; ++c) acc[r][c] = 0.f;

    for (int k0 = 0; k0 < K; k0 += 16) {
#pragma unroll
        for (int Lq = 0; Lq < 2; ++Lq) {
            int row = lrow + Lq * 64;
            float4 va = aval[Lq] ? *(const float4*)(aptr[Lq] + k0)
                                 : make_float4(0.f, 0.f, 0.f, 0.f);
            As[lk+0][row] = va.x; As[lk+1][row] = va.y;
            As[lk+2][row] = va.z; As[lk+3][row] = va.w;
            float4 vb = bval[Lq] ? *(const float4*)(bptr[Lq] + k0)
                                 : make_float4(0.f, 0.f, 0.f, 0.f);
            Bs[lk+0][row] = vb.x; Bs[lk+1][row] = vb.y;
            Bs[lk+2][row] = vb.z; Bs[lk+3][row] = vb.w;
        }
        __syncthreads();
#pragma unroll
        for (int kk = 0; kk < 16; ++kk) {
            float a[8], bfr[8];
            *(float4*)&a[0]   = *(const float4*)&As[kk][ty * 8];
            *(float4*)&a[4]   = *(const float4*)&As[kk][ty * 8 + 4];
            *(float4*)&bfr[0] = *(const float4*)&Bs[kk][tx * 4];
            *(float4*)&bfr[4] = *(const float4*)&Bs[kk][64 + tx * 4];
#pragma unroll
            for (int r = 0; r < 8; ++r)
#pragma unroll
                for (int c = 0; c < 8; ++c)
                    acc[r][c] = fmaf(a[r], bfr[c], acc[r][c]);
        }
        __syncthreads();
    }

#pragma unroll
    for (int r = 0; r < 8; ++r) {
        int gr = m0 + ty * 8 + r;
        if (BOUNDS && gr >= M) continue;
#pragma unroll
        for (int half = 0; half < 2; ++half) {
            int gc = n0 + half * 64 + tx * 4;
#pragma unroll
            for (int c = 0; c < 4; ++c) {
                if (!BOUNDS || gc + c < N) {
                    float v = acc[r][half*4+c] * scale;
                    if (bias) v += bias[gc+c];
                    Cb[(size_t)gr * N + gc + c] = v;
                }
            }
        }
    }
}

// ---------------------------------------------------------------------------
// Attention per (b,h) — r10/r11-verified (4 rows/wave, all-lane score,
// prefetch; output pre-split to Fh/Fl).
// ---------------------------------------------------------------------------
__global__ __launch_bounds__(256)
void attn_kernel(const float* __restrict__ q, const float* __restrict__ k,
                 const float* __restrict__ v, const float* __restrict__ x,
                 short* __restrict__ Fh, short* __restrict__ Fl)
{
    __shared__ float Ks[Lt_][DH_ + 4];
    __shared__ float Vs[Lt_][DH_ + 1];
    __shared__ float qs[16][DH_];
    __shared__ float as[16][Lt_];
    const int bh = blockIdx.x;
    const int b = bh / H_, h = bh - b * H_;
    const int tid = threadIdx.x;
    const int wv = tid >> 6, lane = tid & 63;
    const int half = lane >> 5;
    const int key = lane & 31;

    for (int idx = tid; idx < Lt_ * 16; idx += 256) {
        int l = idx >> 4, dq = (idx & 15) << 2;
        size_t off = ((size_t)(b * Lt_ + l)) * C_ + h * DH_ + dq;
        float4 kv4 = *(const float4*)(k + off);
        Ks[l][dq] = kv4.x; Ks[l][dq + 1] = kv4.y; Ks[l][dq + 2] = kv4.z; Ks[l][dq + 3] = kv4.w;
        float4 vv4 = *(const float4*)(v + off);
        Vs[l][dq] = vv4.x; Vs[l][dq + 1] = vv4.y; Vs[l][dq + 2] = vv4.z; Vs[l][dq + 3] = vv4.w;
    }
    __syncthreads();

    const size_t qbase = (size_t)b * Nv_ * C_ + h * DH_ + lane;
    const size_t xbase = (size_t)b * C_ + h * DH_ + lane;

    float qv[4], xv[4];
#pragma unroll
    for (int j = 0; j < 4; ++j) {
        qv[j] = q[qbase + (size_t)(wv * 4 + j) * C_];
        xv[j] = x[xbase + (size_t)(wv * 4 + j + 1) * B_ * C_];
    }

    for (int it = 0; it < 13; ++it) {
        const int base = it * 16 + wv * 4;
        if (base > 192) break;
        float cq[4], cx[4];
#pragma unroll
        for (int j = 0; j < 4; ++j) { cq[j] = qv[j]; cx[j] = xv[j]; }
        const int nbase = base + 16;
        if (nbase <= 192) {
#pragma unroll
            for (int j = 0; j < 4; ++j) {
                qv[j] = q[qbase + (size_t)(nbase + j) * C_];
                xv[j] = x[xbase + (size_t)(nbase + j + 1) * B_ * C_];
            }
        }
        const int ws = wv * 4;
#pragma unroll
        for (int j = 0; j < 4; ++j) qs[ws + j][lane] = cq[j];

        const int s0 = ws + half * 2;
        float s1 = 0.f, s2 = 0.f;
#pragma unroll
        for (int d4 = 0; d4 < DH_; d4 += 4) {
            float4 k4  = *(const float4*)&Ks[key][d4];
            float4 q4a = *(const float4*)&qs[s0][d4];
            float4 q4b = *(const float4*)&qs[s0 + 1][d4];
            s1 = fmaf(q4a.x, k4.x, s1); s2 = fmaf(q4b.x, k4.x, s2);
            s1 = fmaf(q4a.y, k4.y, s1); s2 = fmaf(q4b.y, k4.y, s2);
            s1 = fmaf(q4a.z, k4.z, s1); s2 = fmaf(q4b.z, k4.z, s2);
            s1 = fmaf(q4a.w, k4.w, s1); s2 = fmaf(q4b.w, k4.w, s2);
        }
        s1 *= 0.125f; s2 *= 0.125f;
        float mx1 = s1, mx2 = s2;
#pragma unroll
        for (int off = 16; off; off >>= 1) {
            mx1 = fmaxf(mx1, __shfl_xor(mx1, off, 32));
            mx2 = fmaxf(mx2, __shfl_xor(mx2, off, 32));
        }
        float p1v = expf(s1 - mx1);
        float p2v = expf(s2 - mx2);
        float su1 = p1v, su2 = p2v;
#pragma unroll
        for (int off = 16; off; off >>= 1) {
            su1 += __shfl_xor(su1, off, 32);
            su2 += __shfl_xor(su2, off, 32);
        }
        as[s0][key] = p1v / su1;
        as[s0 + 1][key] = p2v / su2;

        float c0 = 0.f, c1 = 0.f, c2 = 0.f, c3 = 0.f;
#pragma unroll
        for (int l4 = 0; l4 < Lt_; l4 += 4) {
            float4 a0 = *(const float4*)&as[ws + 0][l4];
            float4 a1 = *(const float4*)&as[ws + 1][l4];
            float4 a2 = *(const float4*)&as[ws + 2][l4];
            float4 a3 = *(const float4*)&as[ws + 3][l4];
            float v0 = Vs[l4 + 0][lane], v1 = Vs[l4 + 1][lane];
            float v2 = Vs[l4 + 2][lane], v3 = Vs[l4 + 3][lane];
            c0 = fmaf(a0.x, v0, c0); c1 = fmaf(a1.x, v0, c1);
            c2 = fmaf(a2.x, v0, c2); c3 = fmaf(a3.x, v0, c3);
            c0 = fmaf(a0.y, v1, c0); c1 = fmaf(a1.y, v1, c1);
            c2 = fmaf(a2.y, v1, c2); c3 = fmaf(a3.y, v1, c3);
            c0 = fmaf(a0.z, v2, c0); c1 = fmaf(a1.z, v2, c1);
            c2 = fmaf(a2.z, v2, c2); c3 = fmaf(a3.z, v2, c3);
            c0 = fmaf(a0.w, v3, c0); c1 = fmaf(a1.w, v3, c1);
            c2 = fmaf(a2.w, v3, c2); c3 = fmaf(a3.w, v3, c3);
        }
        float fo[4] = {c0 + cx[0], c1 + cx[1], c2 + cx[2], c3 + cx[3]};
#pragma unroll
        for (int j = 0; j < 4; ++j) {
            unsigned hh, ll;
            split_bf16(fo[j], hh, ll);
            Fh[qbase + (size_t)(base + j) * C_] = (short)hh;
            Fl[qbase + (size_t)(base + j) * C_] = (short)ll;
        }
    }
}

// ---------------------------------------------------------------------------
// keep decisions: logits from partials[m][24] (+b2), gumbel, policy, keep_prob
// ---------------------------------------------------------------------------
__global__ __launch_bounds__(256)
void keep_kernel(const float* __restrict__ partials, const float* __restrict__ b2,
                 const float* __restrict__ gumbel, float* __restrict__ policy,
                 float* __restrict__ keep_prob)
{
    int m = blockIdx.x * 256 + threadIdx.x;
    int b = m / Nv_, n = m - b * Nv_;
    float l0 = b2[0], l1 = b2[1];
#pragma unroll
    for (int t = 0; t < 12; ++t) {
        l0 += partials[(size_t)m * 24 + t * 2 + 0];
        l1 += partials[(size_t)m * 24 + t * 2 + 1];
    }
    const float UHI = (float)(1.0 - 1e-6);
    float U0 = fminf(fmaxf(gumbel[(size_t)m * 2 + 0], 1e-6f), UHI);
    float U1 = fminf(fmaxf(gumbel[(size_t)m * 2 + 1], 1e-6f), UHI);
    float t0 = (float)log((double)U0);
    float g0 = -(float)log((double)(-t0));
    float t1 = (float)log((double)U1);
    float g1 = -(float)log((double)(-t1));
    float dlog = (l1 + g1) - (l0 + g0);
    float kp = 1.f / (1.f + expf(-dlog));
    policy[(size_t)b * 197 + 1 + n] = (dlog > 0.f) ? 1.f : 0.f;
    if (n == 0) policy[(size_t)b * 197] = 1.f;
    keep_prob[m] = kp;
}

__global__ __launch_bounds__(256)
void batch_reduce(const float* __restrict__ keep_prob, float* __restrict__ sum_kp)
{
    __shared__ float part[4];
    int b = blockIdx.x, tid = threadIdx.x;
    float vs = (tid < Nv_) ? keep_prob[(size_t)b * Nv_ + tid] : 0.f;
#pragma unroll
    for (int off = 32; off; off >>= 1) vs += __shfl_xor(vs, off, 64);
    if ((tid & 63) == 0) part[tid >> 6] = vs;
    __syncthreads();
    if (tid == 0) sum_kp[b] = part[0] + part[1] + part[2] + part[3];
}

__global__ __launch_bounds__(256)
void pw_scale(float* __restrict__ phi, const float* __restrict__ keep_prob,
              const float* __restrict__ sum_kp)
{
    int m = blockIdx.x * 4 + (threadIdx.x >> 6);
    int lane = threadIdx.x & 63;
    float4* row = (float4*)phi + (size_t)m * 64;
    float4 vv = row[lane];
    float ss = vv.x * vv.x + vv.y * vv.y + vv.z * vv.z + vv.w * vv.w;
#pragma unroll
    for (int off = 32; off; off >>= 1) ss += __shfl_xor(ss, off, 64);
    float nrm = fmaxf(sqrtf(ss), 1e-12f);
    int b = m / Nv_;
    float kp = keep_prob[m];
    float meanw = sum_kp[b] * (1.f / 196.f);
    float wn = fmaxf(kp / (meanw + 1e-12f), 1e-6f);
    float sc = sqrtf(wn) / nrm;
    vv.x *= sc; vv.y *= sc; vv.z *= sc; vv.w *= sc;
    row[lane] = vv;
}

// ---------------------------------------------------------------------------
// Per-batch blocked Cholesky logdet — triangle/TRSM/SYRK form.
// Per panel: (1) wave 0 lanes 0..13 factor the 14x14 triangle entirely
// intra-wave (column broadcast via tiny LDS scratch; lgkmcnt-ordered, NO
// barriers), storing inv pivots; (2) ONE barrier; (3) every sub-diagonal
// row does an independent 14-step forward substitution (triangle reads are
// same-address LDS broadcasts); (4) ONE barrier; (5) SYRK (r8-verified).
// Per-row op sequence & rounding identical to r8/r11 (stored Ltri[k][jj]
// = raw*inv, the same single-rounded product the old code recomputed) ->
// logdet bit-identical. Barriers/panel: 16 -> 3.
// ---------------------------------------------------------------------------
#define LS_   197
#define PBS_  14

__global__ __launch_bounds__(256)
void chol_kernel(const float* __restrict__ G, float* __restrict__ logdet_arr)
{
    extern __shared__ float sm[];
    float* Am   = sm;                       // 196 * 197
    float* tri  = sm + 196 * LS_;           // 16: raw-column scratch (wave 0)
    float* invs = tri + 16;                 // 14: 1/sqrt(piv) per column
    const int b = blockIdx.x, tid = threadIdx.x;
    const float* Gb = G + (size_t)b * Nv_ * Nv_;

    for (int idx = tid; idx < Nv_ * 49; idx += 256) {
        int i = idx / 49, c4 = (idx - i * 49) * 4;
        float4 v = *(const float4*)(Gb + (size_t)i * Nv_ + c4);
        if (i >= c4 && i < c4 + 4) (&v.x)[i - c4] += 1.00001f;
        float* dst = Am + i * LS_ + c4;
        dst[0] = v.x; dst[1] = v.y; dst[2] = v.z; dst[3] = v.w;
    }
    __syncthreads();

    float acc = 0.f;                        // tid 0: sum of log pivots
    const int tx = tid & 15, ty = tid >> 4;

    for (int p = 0; p < Nv_ / PBS_; ++p) {
        const int j0 = p * PBS_;
        const int j1 = j0 + PBS_;

        // ---- (1) triangle factorization: wave 0 only, no barriers ----
        if (tid < 64) {
            const bool own = (tid < PBS_);
            float Rt[PBS_];
            if (own) {
#pragma unroll
                for (int t = 0; t < PBS_; ++t) Rt[t] = Am[(j0 + tid) * LS_ + j0 + t];
            }
            for (int jj = 0; jj < PBS_; ++jj) {
                if (own) tri[tid] = Rt[jj];     // publish raw column jj
                float piv = tri[jj];            // intra-wave lgkmcnt orders this
                if (tid == 0) acc += logf(piv);
                float inv = 1.f / sqrtf(piv);
                if (tid == jj) invs[jj] = inv;
                if (own && tid >= jj) {
                    float lij = Rt[jj] * inv;
                    Rt[jj] = lij;
#pragma unroll
                    for (int t = 0; t < PBS_; ++t) {
                        if (t > jj) {
                            float lk = tri[t] * inv;
                            Rt[t] = fmaf(-lij, lk, Rt[t]);
                        }
                    }
                }
            }
            if (own) {
#pragma unroll
                for (int t = 0; t < PBS_; ++t) Am[(j0 + tid) * LS_ + j0 + t] = Rt[t];
            }
        }
        __syncthreads();

        // ---- (3) TRSM: each sub-diagonal row independent ----
        const int i = tid;
        if (i >= j1 && i < Nv_) {
            float Rp[PBS_];
#pragma unroll
            for (int t = 0; t < PBS_; ++t) Rp[t] = Am[i * LS_ + j0 + t];
            for (int jj = 0; jj < PBS_; ++jj) {
                float lij = Rp[jj] * invs[jj];
                Rp[jj] = lij;
#pragma unroll
                for (int t = 0; t < PBS_; ++t) {
                    if (t > jj) {
                        float ltk = Am[(j0 + t) * LS_ + j0 + jj];  // broadcast
                        Rp[t] = fmaf(-lij, ltk, Rp[t]);
                    }
                }
            }
#pragma unroll
            for (int t = 0; t < PBS_; ++t) Am[i * LS_ + j0 + t] = Rp[t];
        }
        __syncthreads();

        // ---- (5) trailing SYRK (r8-verified) ----
        if (j1 >= Nv_) break;
        const int s = Nv_ - j1;
        const int nb = (s + 63) >> 6;
        for (int rb = 0; rb < nb; ++rb) {
            const int i0 = j1 + rb * 64;
            float Li[4][PBS_];
#pragma unroll
            for (int r = 0; r < 4; ++r) {
                int ir = i0 + ty + 16 * r; if (ir > 195) ir = 195;
#pragma unroll
                for (int t = 0; t < PBS_; ++t) Li[r][t] = Am[ir * LS_ + j0 + t];
            }
            for (int cb = 0; cb <= rb; ++cb) {
                const int k0 = j1 + cb * 64;
                float accs[4][4];
#pragma unroll
                for (int r = 0; r < 4; ++r)
#pragma unroll
                    for (int c = 0; c < 4; ++c) accs[r][c] = 0.f;
#pragma unroll
                for (int t = 0; t < PBS_; ++t) {
                    float Lk[4];
#pragma unroll
                    for (int c = 0; c < 4; ++c) {
                        int kx = k0 + 4 * tx + c; if (kx > 195) kx = 195;
                        Lk[c] = Am[kx * LS_ + j0 + t];
                    }
#pragma unroll
                    for (int r = 0; r < 4; ++r)
#pragma unroll
                        for (int c = 0; c < 4; ++c)
                            accs[r][c] = fmaf(Li[r][t], Lk[c], accs[r][c]);
                }
#pragma unroll
                for (int r = 0; r < 4; ++r) {
                    int ir = i0 + ty + 16 * r;
                    if (ir < Nv_) {
#pragma unroll
                        for (int c = 0; c < 4; ++c) {
                            int kx = k0 + 4 * tx + c;
                            if (kx < Nv_) Am[ir * LS_ + kx] -= accs[r][c];
                        }
                    }
                }
            }
        }
        __syncthreads();
    }
    if (tid == 0) logdet_arr[b] = acc;
}

__global__ void finalize_kernel(const float* __restrict__ sum_kp,
                                const float* __restrict__ logdet_arr,
                                float* __restrict__ out)
{
    float tot = 0.f, ld = 0.f;
    for (int b = 0; b < B_; ++b) { tot += sum_kp[b]; ld += logdet_arr[b]; }
    float mean = tot * (1.f / 25088.f);
    float d = mean - 0.7f;
    out[25216] = d * d;
    out[25217] = -ld * (1.f / 128.f);
}

// ---------------------------------------------------------------------------
extern "C" void kernel_launch(void* const* d_in, const int* in_sizes, int n_in,
                              void* d_out, int out_size, void* d_ws, size_t ws_size,
                              hipStream_t stream)
{
    const float* x      = (const float*)d_in[0];
    const float* text   = (const float*)d_in[1];
    const float* gumbel = (const float*)d_in[2];
    const float* Wq     = (const float*)d_in[3];
    const float* bq     = (const float*)d_in[4];
    const float* Wk     = (const float*)d_in[5];
    const float* bk     = (const float*)d_in[6];
    const float* Wv     = (const float*)d_in[7];
    const float* bv     = (const float*)d_in[8];
    const float* W1     = (const float*)d_in[9];
    const float* b1     = (const float*)d_in[10];
    const float* W2     = (const float*)d_in[11];
    const float* b2     = (const float*)d_in[12];
    const float* Wdpp   = (const float*)d_in[13];
    float* out = (float*)d_out;

    float* ws = (float*)d_ws;
    float* q          = ws;                       // 19,267,584 f ; G overlays
    float* kbuf       = q + 19267584;
    float* vbuf       = kbuf + 3145728;
    float* phi        = vbuf + 3145728;
    float* partials   = phi + 6422528;
    float* keep_prob  = partials + 602112;
    float* sum_kp     = keep_prob + 25088;
    float* logdet_arr = sum_kp + 128;
    float* G          = ws;                       // reuse q (dead after attn)

    short* Wq_h = (short*)(logdet_arr + 128);
    short* Wq_l = Wq_h + 589824;
    short* W1_h = Wq_l + 589824;
    short* W1_l = W1_h + 589824;
    short* Wk_h = W1_l + 589824;
    short* Wk_l = Wk_h + 393216;
    short* Wv_h = Wk_l + 393216;
    short* Wv_l = Wv_h + 393216;
    short* Wd_h = Wv_l + 393216;
    short* Wd_l = Wd_h + 196608;
    short* Xh = Wd_l + 196608;                    // 19,267,584 shorts each
    short* Xl = Xh + 19267584;
    short* Th = Xl + 19267584;                    //  2,097,152 shorts each
    short* Tl = Th + 2097152;
    short* Fh = Xh;                               // overlay: X dead after phi
    short* Fl = Xl;

    dim3 blk(256);

    split_all<<<dim3(8448), blk, 0, stream>>>(Wq, W1, Wk, Wv, Wdpp,
                                              Wq_h, Wq_l, W1_h, W1_l,
                                              Wk_h, Wk_l, Wv_h, Wv_l,
                                              Wd_h, Wd_l);
    split_x<<<dim3(9408), blk, 0, stream>>>(x, Xh, Xl);
    split_text<<<dim3(1024), blk, 0, stream>>>(text, Th, Tl);

    mfma_gemm<0><<<dim3(32,6,2), blk, 0, stream>>>(Th, Tl, Wk_h, Wk_l, bk, kbuf, 768, 512,
                                                   nullptr, nullptr,
                                                   Wv_h, Wv_l, bv, vbuf);
    mfma_gemm<0><<<dim3(196,6,1), blk, 0, stream>>>(Xh, Xl, Wq_h, Wq_l, bq, q, 768, 768,
                                                    nullptr, nullptr,
                                                    Wq_h, Wq_l, bq, q);
    mfma_gemm<0><<<dim3(196,2,1), blk, 0, stream>>>(Xh, Xl, Wd_h, Wd_l, nullptr, phi, 256, 768,
                                                    nullptr, nullptr,
                                                    Wd_h, Wd_l, nullptr, phi);
    attn_kernel<<<dim3(B_*H_), blk, 0, stream>>>(q, kbuf, vbuf, x, Fh, Fl);
    mfma_gemm<1><<<dim3(196,6,1), blk, 0, stream>>>(Fh, Fl, W1_h, W1_l, b1, nullptr, 768, 768,
                                                    W2, partials,
                                                    W1_h, W1_l, b1, nullptr);
    keep_kernel<<<dim3(98), blk, 0, stream>>>(partials, b2, gumbel, out, keep_prob);
    batch_reduce<<<dim3(B_), blk, 0, stream>>>(keep_prob, sum_kp);
    pw_scale<<<dim3(6272), blk, 0, stream>>>(phi, keep_prob, sum_kp);
    gemm_nt<0,1,0><<<dim3(2,2,B_), blk, 0, stream>>>(phi, phi, nullptr, G, Nv_, Nv_, 256,
                                                     1.0f/(256.0f*196.0f*0.01f),
                                                     (long)Nv_*256, (long)Nv_*Nv_, nullptr, nullptr);
    size_t shb = (size_t)(Nv_ * LS_ + 32) * sizeof(float);
    (void)hipFuncSetAttribute((const void*)chol_kernel,
                              hipFuncAttributeMaxDynamicSharedMemorySize, (int)shb);
    chol_kernel<<<dim3(B_), blk, shb, stream>>>(G, logdet_arr);
    finalize_kernel<<<dim3(1), dim3(1), 0, stream>>>(sum_kp, logdet_arr, out);
}

// Round 13
// 712.821 us; speedup vs baseline: 1.0056x; 1.0056x over previous
//
#include <hip/hip_runtime.h>
#include <math.h>

#define B_   128
#define L_   197
#define C_   768
#define Nv_  196
#define Lt_  32
#define Ct_  512
#define H_   12
#define DH_  64
#define DPP_ 256
#define MTOK 25088   // B_*Nv_

typedef __attribute__((ext_vector_type(8))) short bf16x8_t;
typedef __attribute__((ext_vector_type(4))) float f32x4_t;

// split fp32 -> bf16 hi (truncate) + bf16 lo (RNE of remainder)
__device__ __forceinline__ void split_bf16(float a, unsigned &h, unsigned &l) {
    unsigned u = __float_as_uint(a);
    unsigned hu = u & 0xffff0000u;
    h = hu >> 16;
    float lf = a - __uint_as_float(hu);
    unsigned ul = __float_as_uint(lf);
    l = (ul + 0x7fffu + ((ul >> 16) & 1u)) >> 16;
}

__device__ __forceinline__ void split8_pack(const float* av, uint4& Hh, uint4& Ll) {
    unsigned hv[8], lv[8];
#pragma unroll
    for (int j = 0; j < 8; ++j) split_bf16(av[j], hv[j], lv[j]);
    Hh.x = hv[0] | (hv[1] << 16); Hh.y = hv[2] | (hv[3] << 16);
    Hh.z = hv[4] | (hv[5] << 16); Hh.w = hv[6] | (hv[7] << 16);
    Ll.x = lv[0] | (lv[1] << 16); Ll.y = lv[2] | (lv[3] << 16);
    Ll.z = lv[4] | (lv[5] << 16); Ll.w = lv[6] | (lv[7] << 16);
}

// ---------------------------------------------------------------------------
// fused weight pre-split (all 5 weights in one launch) — r9-verified
// ---------------------------------------------------------------------------
#define NWQ 589824
#define NWK 393216
#define NWD 196608
__global__ __launch_bounds__(256)
void split_all(const float* __restrict__ Wq, const float* __restrict__ W1,
               const float* __restrict__ Wk, const float* __restrict__ Wv,
               const float* __restrict__ Wd,
               short* __restrict__ Wq_h, short* __restrict__ Wq_l,
               short* __restrict__ W1_h, short* __restrict__ W1_l,
               short* __restrict__ Wk_h, short* __restrict__ Wk_l,
               short* __restrict__ Wv_h, short* __restrict__ Wv_l,
               short* __restrict__ Wd_h, short* __restrict__ Wd_l)
{
    int j = blockIdx.x * 256 + threadIdx.x;   // total 2,162,688 = 8448*256
    const float* src; short *hi, *lo;
    if (j < NWQ)                { src = Wq; hi = Wq_h; lo = Wq_l; }
    else if ((j -= NWQ) < NWQ)  { src = W1; hi = W1_h; lo = W1_l; }
    else if ((j -= NWQ) < NWK)  { src = Wk; hi = Wk_h; lo = Wk_l; }
    else if ((j -= NWK) < NWK)  { src = Wv; hi = Wv_h; lo = Wv_l; }
    else                        { j -= NWK;  src = Wd; hi = Wd_h; lo = Wd_l; }
    unsigned h, l;
    split_bf16(src[j], h, l);
    hi[j] = (short)h; lo[j] = (short)l;
}

// ---------------------------------------------------------------------------
// activation pre-splits (one pass, vectorized) — r11
// ---------------------------------------------------------------------------
__global__ __launch_bounds__(256)
void split_x(const float* __restrict__ x, short* __restrict__ Xh,
             short* __restrict__ Xl)
{
    int idx = blockIdx.x * 256 + threadIdx.x;    // 2,408,448 chunks of 8
    int m = idx / 96, c8 = (idx - m * 96) * 8;
    int b = m / Nv_, n = m - b * Nv_;
    const float* src = x + ((size_t)(n + 1) * B_ + b) * C_ + c8;
    float av[8];
    *(float4*)&av[0] = *(const float4*)src;
    *(float4*)&av[4] = *(const float4*)(src + 4);
    uint4 Hh, Ll;
    split8_pack(av, Hh, Ll);
    *(uint4*)&Xh[(size_t)m * C_ + c8] = Hh;
    *(uint4*)&Xl[(size_t)m * C_ + c8] = Ll;
}

__global__ __launch_bounds__(256)
void split_text(const float* __restrict__ t, short* __restrict__ Th,
                short* __restrict__ Tl)
{
    int idx = blockIdx.x * 256 + threadIdx.x;    // 262,144 chunks of 8
    const float* src = t + (size_t)idx * 8;
    float av[8];
    *(float4*)&av[0] = *(const float4*)src;
    *(float4*)&av[4] = *(const float4*)(src + 4);
    uint4 Hh, Ll;
    split8_pack(av, Hh, Ll);
    *(uint4*)&Th[(size_t)idx * 8] = Hh;
    *(uint4*)&Tl[(size_t)idx * 8] = Ll;
}

// ---------------------------------------------------------------------------
// 3-term split-bf16 MFMA GEMM, all operands pre-split (r11-verified).
// ---------------------------------------------------------------------------
template<int EPI>
__global__ __launch_bounds__(256)
void mfma_gemm(const short* __restrict__ Ah_g, const short* __restrict__ Al_g,
               const short* __restrict__ Bh_g, const short* __restrict__ Bl_g,
               const float* __restrict__ bias,
               float* __restrict__ Cst, int Nst, int Kd,
               const float* __restrict__ W2, float* __restrict__ partials,
               const short* Bh2, const short* Bl2, const float* bias2,
               float* Cst2)
{
    if (blockIdx.z) { Bh_g = Bh2; Bl_g = Bl2; bias = bias2; Cst = Cst2; }
    __shared__ short Ah[128 * 40], Al[128 * 40], Bh[128 * 40], Bl[128 * 40];
    const int tid = threadIdx.x;
    const int m0 = blockIdx.x * 128, n0 = blockIdx.y * 128;
    const int l = tid & 63, wid = tid >> 6;
    const int wr = wid >> 1, wc = wid & 1;
    const int lr = l & 15, lq = l >> 4;

    const int srow = tid >> 2;
    const int p8 = (tid & 3) << 3;
    const short *ahp[2], *alp[2], *bhp[2], *blp[2];
    int abase[2];
#pragma unroll
    for (int i = 0; i < 2; ++i) {
        int row = srow + i * 64;
        abase[i] = row * 40 + p8;
        int gr = m0 + row;
        int gc = n0 + row;
        ahp[i] = Ah_g + (size_t)gr * Kd + p8;
        alp[i] = Al_g + (size_t)gr * Kd + p8;
        bhp[i] = Bh_g + (size_t)gc * Kd + p8;
        blp[i] = Bl_g + (size_t)gc * Kd + p8;
    }

    f32x4_t acc[4][4];
#pragma unroll
    for (int m = 0; m < 4; ++m)
#pragma unroll
        for (int n = 0; n < 4; ++n) {
            acc[m][n][0] = 0.f; acc[m][n][1] = 0.f;
            acc[m][n][2] = 0.f; acc[m][n][3] = 0.f;
        }

    for (int k0 = 0; k0 < Kd; k0 += 32) {
#pragma unroll
        for (int i = 0; i < 2; ++i) {
            *(uint4*)&Ah[abase[i]] = *(const uint4*)(ahp[i] + k0);
            *(uint4*)&Al[abase[i]] = *(const uint4*)(alp[i] + k0);
            *(uint4*)&Bh[abase[i]] = *(const uint4*)(bhp[i] + k0);
            *(uint4*)&Bl[abase[i]] = *(const uint4*)(blp[i] + k0);
        }
        __syncthreads();

        bf16x8_t ahf[4], alf[4], bhf[4], blf[4];
#pragma unroll
        for (int m = 0; m < 4; ++m) {
            int ro = (wr * 64 + m * 16 + lr) * 40 + lq * 8;
            ahf[m] = *(const bf16x8_t*)&Ah[ro];
            alf[m] = *(const bf16x8_t*)&Al[ro];
        }
#pragma unroll
        for (int n = 0; n < 4; ++n) {
            int ro = (wc * 64 + n * 16 + lr) * 40 + lq * 8;
            bhf[n] = *(const bf16x8_t*)&Bh[ro];
            blf[n] = *(const bf16x8_t*)&Bl[ro];
        }
#pragma unroll
        for (int m = 0; m < 4; ++m)
#pragma unroll
            for (int n = 0; n < 4; ++n) {
                acc[m][n] = __builtin_amdgcn_mfma_f32_16x16x32_bf16(ahf[m], bhf[n], acc[m][n], 0, 0, 0);
                acc[m][n] = __builtin_amdgcn_mfma_f32_16x16x32_bf16(ahf[m], blf[n], acc[m][n], 0, 0, 0);
                acc[m][n] = __builtin_amdgcn_mfma_f32_16x16x32_bf16(alf[m], bhf[n], acc[m][n], 0, 0, 0);
            }
        __syncthreads();
    }

    if constexpr (EPI == 0) {
#pragma unroll
        for (int n = 0; n < 4; ++n) {
            int col = n0 + wc * 64 + n * 16 + lr;
            float bv = bias ? bias[col] : 0.f;
#pragma unroll
            for (int m = 0; m < 4; ++m) {
                int rowb = m0 + wr * 64 + m * 16 + lq * 4;
#pragma unroll
                for (int r = 0; r < 4; ++r)
                    Cst[(size_t)(rowb + r) * Nst + col] = acc[m][n][r] + bv;
            }
        }
    } else {
        int coln[4]; float b1v[4], w20[4], w21[4];
#pragma unroll
        for (int n = 0; n < 4; ++n) {
            coln[n] = n0 + wc * 64 + n * 16 + lr;
            b1v[n] = bias[coln[n]];
            w20[n] = W2[coln[n]];
            w21[n] = W2[C_ + coln[n]];
        }
        const int pi = (blockIdx.y * 2 + wc) * 2;
#pragma unroll
        for (int m = 0; m < 4; ++m)
#pragma unroll
            for (int r = 0; r < 4; ++r) {
                float p0 = 0.f, p1 = 0.f;
#pragma unroll
                for (int n = 0; n < 4; ++n) {
                    float h = acc[m][n][r] + b1v[n];
                    float gl = h / (1.f + expf(-1.702f * h));
                    p0 = fmaf(gl, w20[n], p0);
                    p1 = fmaf(gl, w21[n], p1);
                }
#pragma unroll
                for (int off = 8; off; off >>= 1) {
                    p0 += __shfl_xor(p0, off, 16);
                    p1 += __shfl_xor(p1, off, 16);
                }
                if (lr == 0) {
                    int row = m0 + wr * 64 + m * 16 + lq * 4 + r;
                    partials[(size_t)row * 24 + pi + 0] = p0;
                    partials[(size_t)row * 24 + pi + 1] = p1;
                }
            }
    }
}

// ---------------------------------------------------------------------------
// fp32 NT GEMM (batched gram only). r5-verified.
// ---------------------------------------------------------------------------
template<int GATHER_A, int BOUNDS, int EPI>
__global__ __launch_bounds__(256)
void gemm_nt(const float* __restrict__ A, const float* __restrict__ Bm,
             const float* __restrict__ bias, float* __restrict__ C,
             int M, int N, int K, float scale,
             long strideA, long strideC,
             const float* __restrict__ W2, float* __restrict__ partials)
{
    __shared__ float As[16][132];
    __shared__ float Bs[16][132];
    const int tid = threadIdx.x;
    const int tx = tid & 15, ty = tid >> 4;
    const int m0 = blockIdx.x * 128, n0 = blockIdx.y * 128;
    const int bz = blockIdx.z;
    const float* Ab = A  + (size_t)bz * strideA;
    const float* Bb = Bm + (size_t)bz * strideA;
    float* Cb = C + (size_t)bz * strideC;

    const int lrow = tid >> 2;
    const int lk   = (tid & 3) << 2;

    const float* aptr[2]; const float* bptr[2];
    bool aval[2], bval[2];
#pragma unroll
    for (int Lq = 0; Lq < 2; ++Lq) {
        int row = lrow + Lq * 64;
        int gr = m0 + row;
        aval[Lq] = (!BOUNDS) || (gr < M);
        aptr[Lq] = Ab + (size_t)(aval[Lq] ? gr : 0) * K + lk;
        int gc = n0 + row;
        bval[Lq] = (!BOUNDS) || (gc < N);
        bptr[Lq] = Bb + (size_t)(bval[Lq] ? gc : 0) * K + lk;
    }

    float acc[8][8];
#pragma unroll
    for (int r = 0; r < 8; ++r)
#pragma unroll
        for (int c = 0; c < 8; ++c) acc[r][c] = 0.f;

    for (int k0 = 0; k0 < K; k0 += 16) {
#pragma unroll
        for (int Lq = 0; Lq < 2; ++Lq) {
            int row = lrow + Lq * 64;
            float4 va = aval[Lq] ? *(const float4*)(aptr[Lq] + k0)
                                 : make_float4(0.f, 0.f, 0.f, 0.f);
            As[lk+0][row] = va.x; As[lk+1][row] = va.y;
            As[lk+2][row] = va.z; As[lk+3][row] = va.w;
            float4 vb = bval[Lq] ? *(const float4*)(bptr[Lq] + k0)
                                 : make_float4(0.f, 0.f, 0.f, 0.f);
            Bs[lk+0][row] = vb.x; Bs[lk+1][row] = vb.y;
            Bs[lk+2][row] = vb.z; Bs[lk+3][row] = vb.w;
        }
        __syncthreads();
#pragma unroll
        for (int kk = 0; kk < 16; ++kk) {
            float a[8], bfr[8];
            *(float4*)&a[0]   = *(const float4*)&As[kk][ty * 8];
            *(float4*)&a[4]   = *(const float4*)&As[kk][ty * 8 + 4];
            *(float4*)&bfr[0] = *(const float4*)&Bs[kk][tx * 4];
            *(float4*)&bfr[4] = *(const float4*)&Bs[kk][64 + tx * 4];
#pragma unroll
            for (int r = 0; r < 8; ++r)
#pragma unroll
                for (int c = 0; c < 8; ++c)
                    acc[r][c] = fmaf(a[r], bfr[c], acc[r][c]);
        }
        __syncthreads();
    }

#pragma unroll
    for (int r = 0; r < 8; ++r) {
        int gr = m0 + ty * 8 + r;
        if (BOUNDS && gr >= M) continue;
#pragma unroll
        for (int half = 0; half < 2; ++half) {
            int gc = n0 + half * 64 + tx * 4;
#pragma unroll
            for (int c = 0; c < 4; ++c) {
                if (!BOUNDS || gc + c < N) {
                    float v = acc[r][half*4+c] * scale;
                    if (bias) v += bias[gc+c];
                    Cb[(size_t)gr * N + gc + c] = v;
                }
            }
        }
    }
}

// ---------------------------------------------------------------------------
// Attention per (b,h) — r10/r11-verified (4 rows/wave, all-lane score,
// prefetch; output pre-split to Fh/Fl).
// ---------------------------------------------------------------------------
__global__ __launch_bounds__(256)
void attn_kernel(const float* __restrict__ q, const float* __restrict__ k,
                 const float* __restrict__ v, const float* __restrict__ x,
                 short* __restrict__ Fh, short* __restrict__ Fl)
{
    __shared__ float Ks[Lt_][DH_ + 4];
    __shared__ float Vs[Lt_][DH_ + 1];
    __shared__ float qs[16][DH_];
    __shared__ float as[16][Lt_];
    const int bh = blockIdx.x;
    const int b = bh / H_, h = bh - b * H_;
    const int tid = threadIdx.x;
    const int wv = tid >> 6, lane = tid & 63;
    const int half = lane >> 5;
    const int key = lane & 31;

    for (int idx = tid; idx < Lt_ * 16; idx += 256) {
        int l = idx >> 4, dq = (idx & 15) << 2;
        size_t off = ((size_t)(b * Lt_ + l)) * C_ + h * DH_ + dq;
        float4 kv4 = *(const float4*)(k + off);
        Ks[l][dq] = kv4.x; Ks[l][dq + 1] = kv4.y; Ks[l][dq + 2] = kv4.z; Ks[l][dq + 3] = kv4.w;
        float4 vv4 = *(const float4*)(v + off);
        Vs[l][dq] = vv4.x; Vs[l][dq + 1] = vv4.y; Vs[l][dq + 2] = vv4.z; Vs[l][dq + 3] = vv4.w;
    }
    __syncthreads();

    const size_t qbase = (size_t)b * Nv_ * C_ + h * DH_ + lane;
    const size_t xbase = (size_t)b * C_ + h * DH_ + lane;

    float qv[4], xv[4];
#pragma unroll
    for (int j = 0; j < 4; ++j) {
        qv[j] = q[qbase + (size_t)(wv * 4 + j) * C_];
        xv[j] = x[xbase + (size_t)(wv * 4 + j + 1) * B_ * C_];
    }

    for (int it = 0; it < 13; ++it) {
        const int base = it * 16 + wv * 4;
        if (base > 192) break;
        float cq[4], cx[4];
#pragma unroll
        for (int j = 0; j < 4; ++j) { cq[j] = qv[j]; cx[j] = xv[j]; }
        const int nbase = base + 16;
        if (nbase <= 192) {
#pragma unroll
            for (int j = 0; j < 4; ++j) {
                qv[j] = q[qbase + (size_t)(nbase + j) * C_];
                xv[j] = x[xbase + (size_t)(nbase + j + 1) * B_ * C_];
            }
        }
        const int ws = wv * 4;
#pragma unroll
        for (int j = 0; j < 4; ++j) qs[ws + j][lane] = cq[j];

        const int s0 = ws + half * 2;
        float s1 = 0.f, s2 = 0.f;
#pragma unroll
        for (int d4 = 0; d4 < DH_; d4 += 4) {
            float4 k4  = *(const float4*)&Ks[key][d4];
            float4 q4a = *(const float4*)&qs[s0][d4];
            float4 q4b = *(const float4*)&qs[s0 + 1][d4];
            s1 = fmaf(q4a.x, k4.x, s1); s2 = fmaf(q4b.x, k4.x, s2);
            s1 = fmaf(q4a.y, k4.y, s1); s2 = fmaf(q4b.y, k4.y, s2);
            s1 = fmaf(q4a.z, k4.z, s1); s2 = fmaf(q4b.z, k4.z, s2);
            s1 = fmaf(q4a.w, k4.w, s1); s2 = fmaf(q4b.w, k4.w, s2);
        }
        s1 *= 0.125f; s2 *= 0.125f;
        float mx1 = s1, mx2 = s2;
#pragma unroll
        for (int off = 16; off; off >>= 1) {
            mx1 = fmaxf(mx1, __shfl_xor(mx1, off, 32));
            mx2 = fmaxf(mx2, __shfl_xor(mx2, off, 32));
        }
        float p1v = expf(s1 - mx1);
        float p2v = expf(s2 - mx2);
        float su1 = p1v, su2 = p2v;
#pragma unroll
        for (int off = 16; off; off >>= 1) {
            su1 += __shfl_xor(su1, off, 32);
            su2 += __shfl_xor(su2, off, 32);
        }
        as[s0][key] = p1v / su1;
        as[s0 + 1][key] = p2v / su2;

        float c0 = 0.f, c1 = 0.f, c2 = 0.f, c3 = 0.f;
#pragma unroll
        for (int l4 = 0; l4 < Lt_; l4 += 4) {
            float4 a0 = *(const float4*)&as[ws + 0][l4];
            float4 a1 = *(const float4*)&as[ws + 1][l4];
            float4 a2 = *(const float4*)&as[ws + 2][l4];
            float4 a3 = *(const float4*)&as[ws + 3][l4];
            float v0 = Vs[l4 + 0][lane], v1 = Vs[l4 + 1][lane];
            float v2 = Vs[l4 + 2][lane], v3 = Vs[l4 + 3][lane];
            c0 = fmaf(a0.x, v0, c0); c1 = fmaf(a1.x, v0, c1);
            c2 = fmaf(a2.x, v0, c2); c3 = fmaf(a3.x, v0, c3);
            c0 = fmaf(a0.y, v1, c0); c1 = fmaf(a1.y, v1, c1);
            c2 = fmaf(a2.y, v1, c2); c3 = fmaf(a3.y, v1, c3);
            c0 = fmaf(a0.z, v2, c0); c1 = fmaf(a1.z, v2, c1);
            c2 = fmaf(a2.z, v2, c2); c3 = fmaf(a3.z, v2, c3);
            c0 = fmaf(a0.w, v3, c0); c1 = fmaf(a1.w, v3, c1);
            c2 = fmaf(a2.w, v3, c2); c3 = fmaf(a3.w, v3, c3);
        }
        float fo[4] = {c0 + cx[0], c1 + cx[1], c2 + cx[2], c3 + cx[3]};
#pragma unroll
        for (int j = 0; j < 4; ++j) {
            unsigned hh, ll;
            split_bf16(fo[j], hh, ll);
            Fh[qbase + (size_t)(base + j) * C_] = (short)hh;
            Fl[qbase + (size_t)(base + j) * C_] = (short)ll;
        }
    }
}

// ---------------------------------------------------------------------------
// keep decisions: logits from partials[m][24] (+b2), gumbel, policy, keep_prob
// ---------------------------------------------------------------------------
__global__ __launch_bounds__(256)
void keep_kernel(const float* __restrict__ partials, const float* __restrict__ b2,
                 const float* __restrict__ gumbel, float* __restrict__ policy,
                 float* __restrict__ keep_prob)
{
    int m = blockIdx.x * 256 + threadIdx.x;
    int b = m / Nv_, n = m - b * Nv_;
    float l0 = b2[0], l1 = b2[1];
#pragma unroll
    for (int t = 0; t < 12; ++t) {
        l0 += partials[(size_t)m * 24 + t * 2 + 0];
        l1 += partials[(size_t)m * 24 + t * 2 + 1];
    }
    const float UHI = (float)(1.0 - 1e-6);
    float U0 = fminf(fmaxf(gumbel[(size_t)m * 2 + 0], 1e-6f), UHI);
    float U1 = fminf(fmaxf(gumbel[(size_t)m * 2 + 1], 1e-6f), UHI);
    float t0 = (float)log((double)U0);
    float g0 = -(float)log((double)(-t0));
    float t1 = (float)log((double)U1);
    float g1 = -(float)log((double)(-t1));
    float dlog = (l1 + g1) - (l0 + g0);
    float kp = 1.f / (1.f + expf(-dlog));
    policy[(size_t)b * 197 + 1 + n] = (dlog > 0.f) ? 1.f : 0.f;
    if (n == 0) policy[(size_t)b * 197] = 1.f;
    keep_prob[m] = kp;
}

__global__ __launch_bounds__(256)
void batch_reduce(const float* __restrict__ keep_prob, float* __restrict__ sum_kp)
{
    __shared__ float part[4];
    int b = blockIdx.x, tid = threadIdx.x;
    float vs = (tid < Nv_) ? keep_prob[(size_t)b * Nv_ + tid] : 0.f;
#pragma unroll
    for (int off = 32; off; off >>= 1) vs += __shfl_xor(vs, off, 64);
    if ((tid & 63) == 0) part[tid >> 6] = vs;
    __syncthreads();
    if (tid == 0) sum_kp[b] = part[0] + part[1] + part[2] + part[3];
}

__global__ __launch_bounds__(256)
void pw_scale(float* __restrict__ phi, const float* __restrict__ keep_prob,
              const float* __restrict__ sum_kp)
{
    int m = blockIdx.x * 4 + (threadIdx.x >> 6);
    int lane = threadIdx.x & 63;
    float4* row = (float4*)phi + (size_t)m * 64;
    float4 vv = row[lane];
    float ss = vv.x * vv.x + vv.y * vv.y + vv.z * vv.z + vv.w * vv.w;
#pragma unroll
    for (int off = 32; off; off >>= 1) ss += __shfl_xor(ss, off, 64);
    float nrm = fmaxf(sqrtf(ss), 1e-12f);
    int b = m / Nv_;
    float kp = keep_prob[m];
    float meanw = sum_kp[b] * (1.f / 196.f);
    float wn = fmaxf(kp / (meanw + 1e-12f), 1e-6f);
    float sc = sqrtf(wn) / nrm;
    vv.x *= sc; vv.y *= sc; vv.z *= sc; vv.w *= sc;
    row[lane] = vv;
}

// ---------------------------------------------------------------------------
// Per-batch blocked Cholesky logdet — r8 panel structure with the panel+TRSM
// on ONE wave: lane l owns rows {l, l+64, l+128, l+192}, panel slice in
// registers (Rp[4][14], jj-loop fully unrolled -> all indices compile-time).
// Per column: owners publish next raw column value to colraw (intra-wave
// LDS write->read, lgkmcnt-ordered — r7-verified pattern, NO barrier), all
// lanes update. Op order/rounding identical to r8/r11 -> logdet
// bit-identical. SYRK (256 threads) and load unchanged. 2 barriers/panel.
// ---------------------------------------------------------------------------
#define LS_   197
#define PBS_  14

__global__ __launch_bounds__(256)
void chol_kernel(const float* __restrict__ G, float* __restrict__ logdet_arr)
{
    extern __shared__ float sm[];
    float* Am = sm;                                   // 196 * 197
    float (*colraw)[16] = (float(*)[16])(sm + 196 * LS_);   // [14][16]
    const int b = blockIdx.x, tid = threadIdx.x;
    const float* Gb = G + (size_t)b * Nv_ * Nv_;

    for (int idx = tid; idx < Nv_ * 49; idx += 256) {
        int i = idx / 49, c4 = (idx - i * 49) * 4;
        float4 v = *(const float4*)(Gb + (size_t)i * Nv_ + c4);
        if (i >= c4 && i < c4 + 4) (&v.x)[i - c4] += 1.00001f;
        float* dst = Am + i * LS_ + c4;
        dst[0] = v.x; dst[1] = v.y; dst[2] = v.z; dst[3] = v.w;
    }
    __syncthreads();

    float acc = 0.f;
    const int tx = tid & 15, ty = tid >> 4;

    for (int p = 0; p < Nv_ / PBS_; ++p) {
        const int j0 = p * PBS_;
        const int j1 = j0 + PBS_;

        // ---- panel + TRSM on wave 0 (no barriers inside) ----
        if (tid < 64) {
            int rows[4]; bool act[4];
            float Rp[4][PBS_];
#pragma unroll
            for (int r = 0; r < 4; ++r) {
                rows[r] = tid + 64 * r;
                act[r] = (rows[r] < Nv_) && (rows[r] >= j0);
                if (act[r]) {
#pragma unroll
                    for (int t = 0; t < PBS_; ++t) Rp[r][t] = Am[rows[r] * LS_ + j0 + t];
                    if (rows[r] < j1) colraw[0][rows[r] - j0] = Rp[r][0];
                }
            }
#pragma unroll
            for (int jj = 0; jj < PBS_; ++jj) {
                const int j = j0 + jj;
                float piv = colraw[jj][jj];           // after publish; lgkm-ordered
                if (tid == 0) acc += logf(piv);
                float inv = 1.f / sqrtf(piv);
#pragma unroll
                for (int r = 0; r < 4; ++r) {
                    if (act[r] && rows[r] >= j) {
                        float lij = Rp[r][jj] * inv;
                        Rp[r][jj] = lij;
#pragma unroll
                        for (int t = 0; t < PBS_; ++t) {
                            if (t > jj) {
                                float lk = colraw[jj][t] * inv;
                                Rp[r][t] = fmaf(-lij, lk, Rp[r][t]);
                            }
                        }
                        if (jj < PBS_ - 1 && rows[r] > j && rows[r] < j1)
                            colraw[jj + 1][rows[r] - j0] = Rp[r][jj + 1];
                    }
                }
            }
#pragma unroll
            for (int r = 0; r < 4; ++r) {
                if (act[r]) {
#pragma unroll
                    for (int t = 0; t < PBS_; ++t) Am[rows[r] * LS_ + j0 + t] = Rp[r][t];
                }
            }
        }
        __syncthreads();

        // ---- trailing SYRK (r8-verified, 256 threads) ----
        if (j1 >= Nv_) break;
        const int s = Nv_ - j1;
        const int nb = (s + 63) >> 6;
        for (int rb = 0; rb < nb; ++rb) {
            const int i0 = j1 + rb * 64;
            float Li[4][PBS_];
#pragma unroll
            for (int r = 0; r < 4; ++r) {
                int ir = i0 + ty + 16 * r; if (ir > 195) ir = 195;
#pragma unroll
                for (int t = 0; t < PBS_; ++t) Li[r][t] = Am[ir * LS_ + j0 + t];
            }
            for (int cb = 0; cb <= rb; ++cb) {
                const int k0 = j1 + cb * 64;
                float accs[4][4];
#pragma unroll
                for (int r = 0; r < 4; ++r)
#pragma unroll
                    for (int c = 0; c < 4; ++c) accs[r][c] = 0.f;
#pragma unroll
                for (int t = 0; t < PBS_; ++t) {
                    float Lk[4];
#pragma unroll
                    for (int c = 0; c < 4; ++c) {
                        int kx = k0 + 4 * tx + c; if (kx > 195) kx = 195;
                        Lk[c] = Am[kx * LS_ + j0 + t];
                    }
#pragma unroll
                    for (int r = 0; r < 4; ++r)
#pragma unroll
                        for (int c = 0; c < 4; ++c)
                            accs[r][c] = fmaf(Li[r][t], Lk[c], accs[r][c]);
                }
#pragma unroll
                for (int r = 0; r < 4; ++r) {
                    int ir = i0 + ty + 16 * r;
                    if (ir < Nv_) {
#pragma unroll
                        for (int c = 0; c < 4; ++c) {
                            int kx = k0 + 4 * tx + c;
                            if (kx < Nv_) Am[ir * LS_ + kx] -= accs[r][c];
                        }
                    }
                }
            }
        }
        __syncthreads();
    }
    if (tid == 0) logdet_arr[b] = acc;
}

__global__ void finalize_kernel(const float* __restrict__ sum_kp,
                                const float* __restrict__ logdet_arr,
                                float* __restrict__ out)
{
    float tot = 0.f, ld = 0.f;
    for (int b = 0; b < B_; ++b) { tot += sum_kp[b]; ld += logdet_arr[b]; }
    float mean = tot * (1.f / 25088.f);
    float d = mean - 0.7f;
    out[25216] = d * d;
    out[25217] = -ld * (1.f / 128.f);
}

// ---------------------------------------------------------------------------
extern "C" void kernel_launch(void* const* d_in, const int* in_sizes, int n_in,
                              void* d_out, int out_size, void* d_ws, size_t ws_size,
                              hipStream_t stream)
{
    const float* x      = (const float*)d_in[0];
    const float* text   = (const float*)d_in[1];
    const float* gumbel = (const float*)d_in[2];
    const float* Wq     = (const float*)d_in[3];
    const float* bq     = (const float*)d_in[4];
    const float* Wk     = (const float*)d_in[5];
    const float* bk     = (const float*)d_in[6];
    const float* Wv     = (const float*)d_in[7];
    const float* bv     = (const float*)d_in[8];
    const float* W1     = (const float*)d_in[9];
    const float* b1     = (const float*)d_in[10];
    const float* W2     = (const float*)d_in[11];
    const float* b2     = (const float*)d_in[12];
    const float* Wdpp   = (const float*)d_in[13];
    float* out = (float*)d_out;

    float* ws = (float*)d_ws;
    float* q          = ws;                       // 19,267,584 f ; G overlays
    float* kbuf       = q + 19267584;
    float* vbuf       = kbuf + 3145728;
    float* phi        = vbuf + 3145728;
    float* partials   = phi + 6422528;
    float* keep_prob  = partials + 602112;
    float* sum_kp     = keep_prob + 25088;
    float* logdet_arr = sum_kp + 128;
    float* G          = ws;                       // reuse q (dead after attn)

    short* Wq_h = (short*)(logdet_arr + 128);
    short* Wq_l = Wq_h + 589824;
    short* W1_h = Wq_l + 589824;
    short* W1_l = W1_h + 589824;
    short* Wk_h = W1_l + 589824;
    short* Wk_l = Wk_h + 393216;
    short* Wv_h = Wk_l + 393216;
    short* Wv_l = Wv_h + 393216;
    short* Wd_h = Wv_l + 393216;
    short* Wd_l = Wd_h + 196608;
    short* Xh = Wd_l + 196608;                    // 19,267,584 shorts each
    short* Xl = Xh + 19267584;
    short* Th = Xl + 19267584;                    //  2,097,152 shorts each
    short* Tl = Th + 2097152;
    short* Fh = Xh;                               // overlay: X dead after phi
    short* Fl = Xl;

    dim3 blk(256);

    split_all<<<dim3(8448), blk, 0, stream>>>(Wq, W1, Wk, Wv, Wdpp,
                                              Wq_h, Wq_l, W1_h, W1_l,
                                              Wk_h, Wk_l, Wv_h, Wv_l,
                                              Wd_h, Wd_l);
    split_x<<<dim3(9408), blk, 0, stream>>>(x, Xh, Xl);
    split_text<<<dim3(1024), blk, 0, stream>>>(text, Th, Tl);

    mfma_gemm<0><<<dim3(32,6,2), blk, 0, stream>>>(Th, Tl, Wk_h, Wk_l, bk, kbuf, 768, 512,
                                                   nullptr, nullptr,
                                                   Wv_h, Wv_l, bv, vbuf);
    mfma_gemm<0><<<dim3(196,6,1), blk, 0, stream>>>(Xh, Xl, Wq_h, Wq_l, bq, q, 768, 768,
                                                    nullptr, nullptr,
                                                    Wq_h, Wq_l, bq, q);
    mfma_gemm<0><<<dim3(196,2,1), blk, 0, stream>>>(Xh, Xl, Wd_h, Wd_l, nullptr, phi, 256, 768,
                                                    nullptr, nullptr,
                                                    Wd_h, Wd_l, nullptr, phi);
    attn_kernel<<<dim3(B_*H_), blk, 0, stream>>>(q, kbuf, vbuf, x, Fh, Fl);
    mfma_gemm<1><<<dim3(196,6,1), blk, 0, stream>>>(Fh, Fl, W1_h, W1_l, b1, nullptr, 768, 768,
                                                    W2, partials,
                                                    W1_h, W1_l, b1, nullptr);
    keep_kernel<<<dim3(98), blk, 0, stream>>>(partials, b2, gumbel, out, keep_prob);
    batch_reduce<<<dim3(B_), blk, 0, stream>>>(keep_prob, sum_kp);
    pw_scale<<<dim3(6272), blk, 0, stream>>>(phi, keep_prob, sum_kp);
    gemm_nt<0,1,0><<<dim3(2,2,B_), blk, 0, stream>>>(phi, phi, nullptr, G, Nv_, Nv_, 256,
                                                     1.0f/(256.0f*196.0f*0.01f),
                                                     (long)Nv_*256, (long)Nv_*Nv_, nullptr, nullptr);
    size_t shb = (size_t)(Nv_ * LS_ + 256) * sizeof(float);
    (void)hipFuncSetAttribute((const void*)chol_kernel,
                              hipFuncAttributeMaxDynamicSharedMemorySize, (int)shb);
    chol_kernel<<<dim3(B_), blk, shb, stream>>>(G, logdet_arr);
    finalize_kernel<<<dim3(1), dim3(1), 0, stream>>>(sum_kp, logdet_arr, out);
}

// Round 14
// 614.519 us; speedup vs baseline: 1.1664x; 1.1600x over previous
//
#include <hip/hip_runtime.h>
#include <math.h>

#define B_   128
#define L_   197
#define C_   768
#define Nv_  196
#define Lt_  32
#define Ct_  512
#define H_   12
#define DH_  64
#define DPP_ 256
#define MTOK 25088   // B_*Nv_
#define MLD_ 208     // padded row stride of M (196 cols + 12 zero pad)

typedef __attribute__((ext_vector_type(8))) short bf16x8_t;
typedef __attribute__((ext_vector_type(4))) float f32x4_t;

// split fp32 -> bf16 hi (truncate) + bf16 lo (RNE of remainder)
__device__ __forceinline__ void split_bf16(float a, unsigned &h, unsigned &l) {
    unsigned u = __float_as_uint(a);
    unsigned hu = u & 0xffff0000u;
    h = hu >> 16;
    float lf = a - __uint_as_float(hu);
    unsigned ul = __float_as_uint(lf);
    l = (ul + 0x7fffu + ((ul >> 16) & 1u)) >> 16;
}

__device__ __forceinline__ void split8_pack(const float* av, uint4& Hh, uint4& Ll) {
    unsigned hv[8], lv[8];
#pragma unroll
    for (int j = 0; j < 8; ++j) split_bf16(av[j], hv[j], lv[j]);
    Hh.x = hv[0] | (hv[1] << 16); Hh.y = hv[2] | (hv[3] << 16);
    Hh.z = hv[4] | (hv[5] << 16); Hh.w = hv[6] | (hv[7] << 16);
    Ll.x = lv[0] | (lv[1] << 16); Ll.y = lv[2] | (lv[3] << 16);
    Ll.z = lv[4] | (lv[5] << 16); Ll.w = lv[6] | (lv[7] << 16);
}

// ---------------------------------------------------------------------------
// fused weight pre-split (all 5 weights in one launch) — r9-verified
// ---------------------------------------------------------------------------
#define NWQ 589824
#define NWK 393216
#define NWD 196608
__global__ __launch_bounds__(256)
void split_all(const float* __restrict__ Wq, const float* __restrict__ W1,
               const float* __restrict__ Wk, const float* __restrict__ Wv,
               const float* __restrict__ Wd,
               short* __restrict__ Wq_h, short* __restrict__ Wq_l,
               short* __restrict__ W1_h, short* __restrict__ W1_l,
               short* __restrict__ Wk_h, short* __restrict__ Wk_l,
               short* __restrict__ Wv_h, short* __restrict__ Wv_l,
               short* __restrict__ Wd_h, short* __restrict__ Wd_l)
{
    int j = blockIdx.x * 256 + threadIdx.x;   // total 2,162,688 = 8448*256
    const float* src; short *hi, *lo;
    if (j < NWQ)                { src = Wq; hi = Wq_h; lo = Wq_l; }
    else if ((j -= NWQ) < NWQ)  { src = W1; hi = W1_h; lo = W1_l; }
    else if ((j -= NWQ) < NWK)  { src = Wk; hi = Wk_h; lo = Wk_l; }
    else if ((j -= NWK) < NWK)  { src = Wv; hi = Wv_h; lo = Wv_l; }
    else                        { j -= NWK;  src = Wd; hi = Wd_h; lo = Wd_l; }
    unsigned h, l;
    split_bf16(src[j], h, l);
    hi[j] = (short)h; lo[j] = (short)l;
}

// ---------------------------------------------------------------------------
// activation pre-splits (one pass, vectorized) — r11
// ---------------------------------------------------------------------------
__global__ __launch_bounds__(256)
void split_x(const float* __restrict__ x, short* __restrict__ Xh,
             short* __restrict__ Xl)
{
    int idx = blockIdx.x * 256 + threadIdx.x;    // 2,408,448 chunks of 8
    int m = idx / 96, c8 = (idx - m * 96) * 8;
    int b = m / Nv_, n = m - b * Nv_;
    const float* src = x + ((size_t)(n + 1) * B_ + b) * C_ + c8;
    float av[8];
    *(float4*)&av[0] = *(const float4*)src;
    *(float4*)&av[4] = *(const float4*)(src + 4);
    uint4 Hh, Ll;
    split8_pack(av, Hh, Ll);
    *(uint4*)&Xh[(size_t)m * C_ + c8] = Hh;
    *(uint4*)&Xl[(size_t)m * C_ + c8] = Ll;
}

__global__ __launch_bounds__(256)
void split_text(const float* __restrict__ t, short* __restrict__ Th,
                short* __restrict__ Tl)
{
    int idx = blockIdx.x * 256 + threadIdx.x;    // 262,144 chunks of 8
    const float* src = t + (size_t)idx * 8;
    float av[8];
    *(float4*)&av[0] = *(const float4*)src;
    *(float4*)&av[4] = *(const float4*)(src + 4);
    uint4 Hh, Ll;
    split8_pack(av, Hh, Ll);
    *(uint4*)&Th[(size_t)idx * 8] = Hh;
    *(uint4*)&Tl[(size_t)idx * 8] = Ll;
}

// ---------------------------------------------------------------------------
// 3-term split-bf16 MFMA GEMM, all operands pre-split (r11-verified).
// ---------------------------------------------------------------------------
template<int EPI>
__global__ __launch_bounds__(256)
void mfma_gemm(const short* __restrict__ Ah_g, const short* __restrict__ Al_g,
               const short* __restrict__ Bh_g, const short* __restrict__ Bl_g,
               const float* __restrict__ bias,
               float* __restrict__ Cst, int Nst, int Kd,
               const float* __restrict__ W2, float* __restrict__ partials,
               const short* Bh2, const short* Bl2, const float* bias2,
               float* Cst2)
{
    if (blockIdx.z) { Bh_g = Bh2; Bl_g = Bl2; bias = bias2; Cst = Cst2; }
    __shared__ short Ah[128 * 40], Al[128 * 40], Bh[128 * 40], Bl[128 * 40];
    const int tid = threadIdx.x;
    const int m0 = blockIdx.x * 128, n0 = blockIdx.y * 128;
    const int l = tid & 63, wid = tid >> 6;
    const int wr = wid >> 1, wc = wid & 1;
    const int lr = l & 15, lq = l >> 4;

    const int srow = tid >> 2;
    const int p8 = (tid & 3) << 3;
    const short *ahp[2], *alp[2], *bhp[2], *blp[2];
    int abase[2];
#pragma unroll
    for (int i = 0; i < 2; ++i) {
        int row = srow + i * 64;
        abase[i] = row * 40 + p8;
        int gr = m0 + row;
        int gc = n0 + row;
        ahp[i] = Ah_g + (size_t)gr * Kd + p8;
        alp[i] = Al_g + (size_t)gr * Kd + p8;
        bhp[i] = Bh_g + (size_t)gc * Kd + p8;
        blp[i] = Bl_g + (size_t)gc * Kd + p8;
    }

    f32x4_t acc[4][4];
#pragma unroll
    for (int m = 0; m < 4; ++m)
#pragma unroll
        for (int n = 0; n < 4; ++n) {
            acc[m][n][0] = 0.f; acc[m][n][1] = 0.f;
            acc[m][n][2] = 0.f; acc[m][n][3] = 0.f;
        }

    for (int k0 = 0; k0 < Kd; k0 += 32) {
#pragma unroll
        for (int i = 0; i < 2; ++i) {
            *(uint4*)&Ah[abase[i]] = *(const uint4*)(ahp[i] + k0);
            *(uint4*)&Al[abase[i]] = *(const uint4*)(alp[i] + k0);
            *(uint4*)&Bh[abase[i]] = *(const uint4*)(bhp[i] + k0);
            *(uint4*)&Bl[abase[i]] = *(const uint4*)(blp[i] + k0);
        }
        __syncthreads();

        bf16x8_t ahf[4], alf[4], bhf[4], blf[4];
#pragma unroll
        for (int m = 0; m < 4; ++m) {
            int ro = (wr * 64 + m * 16 + lr) * 40 + lq * 8;
            ahf[m] = *(const bf16x8_t*)&Ah[ro];
            alf[m] = *(const bf16x8_t*)&Al[ro];
        }
#pragma unroll
        for (int n = 0; n < 4; ++n) {
            int ro = (wc * 64 + n * 16 + lr) * 40 + lq * 8;
            bhf[n] = *(const bf16x8_t*)&Bh[ro];
            blf[n] = *(const bf16x8_t*)&Bl[ro];
        }
#pragma unroll
        for (int m = 0; m < 4; ++m)
#pragma unroll
            for (int n = 0; n < 4; ++n) {
                acc[m][n] = __builtin_amdgcn_mfma_f32_16x16x32_bf16(ahf[m], bhf[n], acc[m][n], 0, 0, 0);
                acc[m][n] = __builtin_amdgcn_mfma_f32_16x16x32_bf16(ahf[m], blf[n], acc[m][n], 0, 0, 0);
                acc[m][n] = __builtin_amdgcn_mfma_f32_16x16x32_bf16(alf[m], bhf[n], acc[m][n], 0, 0, 0);
            }
        __syncthreads();
    }

    if constexpr (EPI == 0) {
#pragma unroll
        for (int n = 0; n < 4; ++n) {
            int col = n0 + wc * 64 + n * 16 + lr;
            float bv = bias ? bias[col] : 0.f;
#pragma unroll
            for (int m = 0; m < 4; ++m) {
                int rowb = m0 + wr * 64 + m * 16 + lq * 4;
#pragma unroll
                for (int r = 0; r < 4; ++r)
                    Cst[(size_t)(rowb + r) * Nst + col] = acc[m][n][r] + bv;
            }
        }
    } else {
        int coln[4]; float b1v[4], w20[4], w21[4];
#pragma unroll
        for (int n = 0; n < 4; ++n) {
            coln[n] = n0 + wc * 64 + n * 16 + lr;
            b1v[n] = bias[coln[n]];
            w20[n] = W2[coln[n]];
            w21[n] = W2[C_ + coln[n]];
        }
        const int pi = (blockIdx.y * 2 + wc) * 2;
#pragma unroll
        for (int m = 0; m < 4; ++m)
#pragma unroll
            for (int r = 0; r < 4; ++r) {
                float p0 = 0.f, p1 = 0.f;
#pragma unroll
                for (int n = 0; n < 4; ++n) {
                    float h = acc[m][n][r] + b1v[n];
                    float gl = h / (1.f + expf(-1.702f * h));
                    p0 = fmaf(gl, w20[n], p0);
                    p1 = fmaf(gl, w21[n], p1);
                }
#pragma unroll
                for (int off = 8; off; off >>= 1) {
                    p0 += __shfl_xor(p0, off, 16);
                    p1 += __shfl_xor(p1, off, 16);
                }
                if (lr == 0) {
                    int row = m0 + wr * 64 + m * 16 + lq * 4 + r;
                    partials[(size_t)row * 24 + pi + 0] = p0;
                    partials[(size_t)row * 24 + pi + 1] = p1;
                }
            }
    }
}

// ---------------------------------------------------------------------------
// gram: M = phi@phi^T * scale + 1e-5*I, row stride MLD_=208, cols 196..207
// zero-filled (so taylor_gemm's K-loop needs no K guards). fp32, r5-verified
// GEMM body.
// ---------------------------------------------------------------------------
__global__ __launch_bounds__(256)
void gram_kernel(const float* __restrict__ A, float* __restrict__ Mout,
                 float scale)
{
    __shared__ float As[16][132];
    __shared__ float Bs[16][132];
    const int tid = threadIdx.x;
    const int tx = tid & 15, ty = tid >> 4;
    const int m0 = blockIdx.x * 128, n0 = blockIdx.y * 128;
    const int bz = blockIdx.z;
    const float* Ab = A + (size_t)bz * Nv_ * DPP_;
    float* Mb = Mout + (size_t)bz * Nv_ * MLD_;

    const int lrow = tid >> 2;
    const int lk   = (tid & 3) << 2;

    const float* aptr[2]; const float* bptr[2];
    bool aval[2], bval[2];
#pragma unroll
    for (int Lq = 0; Lq < 2; ++Lq) {
        int row = lrow + Lq * 64;
        int gr = m0 + row;
        aval[Lq] = (gr < Nv_);
        aptr[Lq] = Ab + (size_t)(aval[Lq] ? gr : 0) * DPP_ + lk;
        int gc = n0 + row;
        bval[Lq] = (gc < Nv_);
        bptr[Lq] = Ab + (size_t)(bval[Lq] ? gc : 0) * DPP_ + lk;
    }

    float acc[8][8];
#pragma unroll
    for (int r = 0; r < 8; ++r)
#pragma unroll
        for (int c = 0; c < 8; ++c) acc[r][c] = 0.f;

    for (int k0 = 0; k0 < DPP_; k0 += 16) {
#pragma unroll
        for (int Lq = 0; Lq < 2; ++Lq) {
            int row = lrow + Lq * 64;
            float4 va = aval[Lq] ? *(const float4*)(aptr[Lq] + k0)
                                 : make_float4(0.f, 0.f, 0.f, 0.f);
            As[lk+0][row] = va.x; As[lk+1][row] = va.y;
            As[lk+2][row] = va.z; As[lk+3][row] = va.w;
            float4 vb = bval[Lq] ? *(const float4*)(bptr[Lq] + k0)
                                 : make_float4(0.f, 0.f, 0.f, 0.f);
            Bs[lk+0][row] = vb.x; Bs[lk+1][row] = vb.y;
            Bs[lk+2][row] = vb.z; Bs[lk+3][row] = vb.w;
        }
        __syncthreads();
#pragma unroll
        for (int kk = 0; kk < 16; ++kk) {
            float a[8], bfr[8];
            *(float4*)&a[0]   = *(const float4*)&As[kk][ty * 8];
            *(float4*)&a[4]   = *(const float4*)&As[kk][ty * 8 + 4];
            *(float4*)&bfr[0] = *(const float4*)&Bs[kk][tx * 4];
            *(float4*)&bfr[4] = *(const float4*)&Bs[kk][64 + tx * 4];
#pragma unroll
            for (int r = 0; r < 8; ++r)
#pragma unroll
                for (int c = 0; c < 8; ++c)
                    acc[r][c] = fmaf(a[r], bfr[c], acc[r][c]);
        }
        __syncthreads();
    }

#pragma unroll
    for (int r = 0; r < 8; ++r) {
        int gr = m0 + ty * 8 + r;
        if (gr >= Nv_) continue;
#pragma unroll
        for (int half = 0; half < 2; ++half) {
            int gc0 = n0 + half * 64 + tx * 4;
#pragma unroll
            for (int c = 0; c < 4; ++c) {
                int gc = gc0 + c;
                if (gc < Nv_) {
                    float v = acc[r][half*4+c] * scale;
                    if (gr == gc) v += 1e-5f;   // M = G + eps*I
                    Mb[(size_t)gr * MLD_ + gc] = v;
                } else if (gc < MLD_) {
                    Mb[(size_t)gr * MLD_ + gc] = 0.f;   // zero pad
                }
            }
        }
    }
}

// ---------------------------------------------------------------------------
// taylor_gemm: computes M2 = M@M^T tile (K=MLD_, pad cols are zero) and, in
// the epilogue, per-block partial traces (never materializing M2):
//   t1 = sum diag(M), t2 = sum M_ij^2 (=tr M^2),
//   t3 = sum M2_ij*M_ij (=tr M^3), t4 = sum M2_ij^2 (=tr M^4)
// -> tpart[bz][blk][4], blk = blockIdx.y*2+blockIdx.x. Deterministic
// (fixed shuffle tree + per-wave LDS combine).
// logdet = tr(M) - tr(M^2)/2 + tr(M^3)/3 - tr(M^4)/4 + O(196*lam^5/5),
// lam ~ 1.4e-2 -> error ~2e-8 (threshold 2e-2).
// ---------------------------------------------------------------------------
__global__ __launch_bounds__(256)
void taylor_gemm(const float* __restrict__ Mg, float* __restrict__ tpart)
{
    __shared__ float As[16][132];
    __shared__ float Bs[16][132];
    __shared__ float wred[4][4];
    const int tid = threadIdx.x;
    const int tx = tid & 15, ty = tid >> 4;
    const int m0 = blockIdx.x * 128, n0 = blockIdx.y * 128;
    const int bz = blockIdx.z;
    const float* Mb = Mg + (size_t)bz * Nv_ * MLD_;

    const int lrow = tid >> 2;
    const int lk   = (tid & 3) << 2;

    const float* aptr[2]; const float* bptr[2];
    bool aval[2], bval[2];
#pragma unroll
    for (int Lq = 0; Lq < 2; ++Lq) {
        int row = lrow + Lq * 64;
        int gr = m0 + row;
        aval[Lq] = (gr < Nv_);
        aptr[Lq] = Mb + (size_t)(aval[Lq] ? gr : 0) * MLD_ + lk;
        int gc = n0 + row;
        bval[Lq] = (gc < Nv_);
        bptr[Lq] = Mb + (size_t)(bval[Lq] ? gc : 0) * MLD_ + lk;
    }

    float acc[8][8];
#pragma unroll
    for (int r = 0; r < 8; ++r)
#pragma unroll
        for (int c = 0; c < 8; ++c) acc[r][c] = 0.f;

    for (int k0 = 0; k0 < MLD_; k0 += 16) {   // 13 tiles; pad cols are zero
#pragma unroll
        for (int Lq = 0; Lq < 2; ++Lq) {
            int row = lrow + Lq * 64;
            float4 va = aval[Lq] ? *(const float4*)(aptr[Lq] + k0)
                                 : make_float4(0.f, 0.f, 0.f, 0.f);
            As[lk+0][row] = va.x; As[lk+1][row] = va.y;
            As[lk+2][row] = va.z; As[lk+3][row] = va.w;
            float4 vb = bval[Lq] ? *(const float4*)(bptr[Lq] + k0)
                                 : make_float4(0.f, 0.f, 0.f, 0.f);
            Bs[lk+0][row] = vb.x; Bs[lk+1][row] = vb.y;
            Bs[lk+2][row] = vb.z; Bs[lk+3][row] = vb.w;
        }
        __syncthreads();
#pragma unroll
        for (int kk = 0; kk < 16; ++kk) {
            float a[8], bfr[8];
            *(float4*)&a[0]   = *(const float4*)&As[kk][ty * 8];
            *(float4*)&a[4]   = *(const float4*)&As[kk][ty * 8 + 4];
            *(float4*)&bfr[0] = *(const float4*)&Bs[kk][tx * 4];
            *(float4*)&bfr[4] = *(const float4*)&Bs[kk][64 + tx * 4];
#pragma unroll
            for (int r = 0; r < 8; ++r)
#pragma unroll
                for (int c = 0; c < 8; ++c)
                    acc[r][c] = fmaf(a[r], bfr[c], acc[r][c]);
        }
        __syncthreads();
    }

    // epilogue: partial traces over this block's output tile
    float t1 = 0.f, t2 = 0.f, t3 = 0.f, t4 = 0.f;
#pragma unroll
    for (int r = 0; r < 8; ++r) {
        int gr = m0 + ty * 8 + r;
        if (gr >= Nv_) continue;
#pragma unroll
        for (int half = 0; half < 2; ++half) {
            int gc0 = n0 + half * 64 + tx * 4;
#pragma unroll
            for (int c = 0; c < 4; ++c) {
                int gc = gc0 + c;
                if (gc < Nv_) {
                    float mij = Mb[(size_t)gr * MLD_ + gc];
                    float m2  = acc[r][half*4+c];
                    if (gr == gc) t1 += mij;
                    t2 = fmaf(mij, mij, t2);
                    t3 = fmaf(m2, mij, t3);
                    t4 = fmaf(m2, m2, t4);
                }
            }
        }
    }
#pragma unroll
    for (int off = 32; off; off >>= 1) {
        t1 += __shfl_xor(t1, off, 64);
        t2 += __shfl_xor(t2, off, 64);
        t3 += __shfl_xor(t3, off, 64);
        t4 += __shfl_xor(t4, off, 64);
    }
    const int wv = tid >> 6;
    if ((tid & 63) == 0) {
        wred[wv][0] = t1; wred[wv][1] = t2; wred[wv][2] = t3; wred[wv][3] = t4;
    }
    __syncthreads();
    if (tid == 0) {
        const int blk = blockIdx.y * 2 + blockIdx.x;
        float* dst = tpart + ((size_t)bz * 4 + blk) * 4;
        dst[0] = wred[0][0] + wred[1][0] + wred[2][0] + wred[3][0];
        dst[1] = wred[0][1] + wred[1][1] + wred[2][1] + wred[3][1];
        dst[2] = wred[0][2] + wred[1][2] + wred[2][2] + wred[3][2];
        dst[3] = wred[0][3] + wred[1][3] + wred[2][3] + wred[3][3];
    }
}

// ---------------------------------------------------------------------------
// Attention per (b,h) — r10/r11-verified (4 rows/wave, all-lane score,
// prefetch; output pre-split to Fh/Fl).
// ---------------------------------------------------------------------------
__global__ __launch_bounds__(256)
void attn_kernel(const float* __restrict__ q, const float* __restrict__ k,
                 const float* __restrict__ v, const float* __restrict__ x,
                 short* __restrict__ Fh, short* __restrict__ Fl)
{
    __shared__ float Ks[Lt_][DH_ + 4];
    __shared__ float Vs[Lt_][DH_ + 1];
    __shared__ float qs[16][DH_];
    __shared__ float as[16][Lt_];
    const int bh = blockIdx.x;
    const int b = bh / H_, h = bh - b * H_;
    const int tid = threadIdx.x;
    const int wv = tid >> 6, lane = tid & 63;
    const int half = lane >> 5;
    const int key = lane & 31;

    for (int idx = tid; idx < Lt_ * 16; idx += 256) {
        int l = idx >> 4, dq = (idx & 15) << 2;
        size_t off = ((size_t)(b * Lt_ + l)) * C_ + h * DH_ + dq;
        float4 kv4 = *(const float4*)(k + off);
        Ks[l][dq] = kv4.x; Ks[l][dq + 1] = kv4.y; Ks[l][dq + 2] = kv4.z; Ks[l][dq + 3] = kv4.w;
        float4 vv4 = *(const float4*)(v + off);
        Vs[l][dq] = vv4.x; Vs[l][dq + 1] = vv4.y; Vs[l][dq + 2] = vv4.z; Vs[l][dq + 3] = vv4.w;
    }
    __syncthreads();

    const size_t qbase = (size_t)b * Nv_ * C_ + h * DH_ + lane;
    const size_t xbase = (size_t)b * C_ + h * DH_ + lane;

    float qv[4], xv[4];
#pragma unroll
    for (int j = 0; j < 4; ++j) {
        qv[j] = q[qbase + (size_t)(wv * 4 + j) * C_];
        xv[j] = x[xbase + (size_t)(wv * 4 + j + 1) * B_ * C_];
    }

    for (int it = 0; it < 13; ++it) {
        const int base = it * 16 + wv * 4;
        if (base > 192) break;
        float cq[4], cx[4];
#pragma unroll
        for (int j = 0; j < 4; ++j) { cq[j] = qv[j]; cx[j] = xv[j]; }
        const int nbase = base + 16;
        if (nbase <= 192) {
#pragma unroll
            for (int j = 0; j < 4; ++j) {
                qv[j] = q[qbase + (size_t)(nbase + j) * C_];
                xv[j] = x[xbase + (size_t)(nbase + j + 1) * B_ * C_];
            }
        }
        const int ws = wv * 4;
#pragma unroll
        for (int j = 0; j < 4; ++j) qs[ws + j][lane] = cq[j];

        const int s0 = ws + half * 2;
        float s1 = 0.f, s2 = 0.f;
#pragma unroll
        for (int d4 = 0; d4 < DH_; d4 += 4) {
            float4 k4  = *(const float4*)&Ks[key][d4];
            float4 q4a = *(const float4*)&qs[s0][d4];
            float4 q4b = *(const float4*)&qs[s0 + 1][d4];
            s1 = fmaf(q4a.x, k4.x, s1); s2 = fmaf(q4b.x, k4.x, s2);
            s1 = fmaf(q4a.y, k4.y, s1); s2 = fmaf(q4b.y, k4.y, s2);
            s1 = fmaf(q4a.z, k4.z, s1); s2 = fmaf(q4b.z, k4.z, s2);
            s1 = fmaf(q4a.w, k4.w, s1); s2 = fmaf(q4b.w, k4.w, s2);
        }
        s1 *= 0.125f; s2 *= 0.125f;
        float mx1 = s1, mx2 = s2;
#pragma unroll
        for (int off = 16; off; off >>= 1) {
            mx1 = fmaxf(mx1, __shfl_xor(mx1, off, 32));
            mx2 = fmaxf(mx2, __shfl_xor(mx2, off, 32));
        }
        float p1v = expf(s1 - mx1);
        float p2v = expf(s2 - mx2);
        float su1 = p1v, su2 = p2v;
#pragma unroll
        for (int off = 16; off; off >>= 1) {
            su1 += __shfl_xor(su1, off, 32);
            su2 += __shfl_xor(su2, off, 32);
        }
        as[s0][key] = p1v / su1;
        as[s0 + 1][key] = p2v / su2;

        float c0 = 0.f, c1 = 0.f, c2 = 0.f, c3 = 0.f;
#pragma unroll
        for (int l4 = 0; l4 < Lt_; l4 += 4) {
            float4 a0 = *(const float4*)&as[ws + 0][l4];
            float4 a1 = *(const float4*)&as[ws + 1][l4];
            float4 a2 = *(const float4*)&as[ws + 2][l4];
            float4 a3 = *(const float4*)&as[ws + 3][l4];
            float v0 = Vs[l4 + 0][lane], v1 = Vs[l4 + 1][lane];
            float v2 = Vs[l4 + 2][lane], v3 = Vs[l4 + 3][lane];
            c0 = fmaf(a0.x, v0, c0); c1 = fmaf(a1.x, v0, c1);
            c2 = fmaf(a2.x, v0, c2); c3 = fmaf(a3.x, v0, c3);
            c0 = fmaf(a0.y, v1, c0); c1 = fmaf(a1.y, v1, c1);
            c2 = fmaf(a2.y, v1, c2); c3 = fmaf(a3.y, v1, c3);
            c0 = fmaf(a0.z, v2, c0); c1 = fmaf(a1.z, v2, c1);
            c2 = fmaf(a2.z, v2, c2); c3 = fmaf(a3.z, v2, c3);
            c0 = fmaf(a0.w, v3, c0); c1 = fmaf(a1.w, v3, c1);
            c2 = fmaf(a2.w, v3, c2); c3 = fmaf(a3.w, v3, c3);
        }
        float fo[4] = {c0 + cx[0], c1 + cx[1], c2 + cx[2], c3 + cx[3]};
#pragma unroll
        for (int j = 0; j < 4; ++j) {
            unsigned hh, ll;
            split_bf16(fo[j], hh, ll);
            Fh[qbase + (size_t)(base + j) * C_] = (short)hh;
            Fl[qbase + (size_t)(base + j) * C_] = (short)ll;
        }
    }
}

// ---------------------------------------------------------------------------
// keep decisions: logits from partials[m][24] (+b2), gumbel, policy, keep_prob
// ---------------------------------------------------------------------------
__global__ __launch_bounds__(256)
void keep_kernel(const float* __restrict__ partials, const float* __restrict__ b2,
                 const float* __restrict__ gumbel, float* __restrict__ policy,
                 float* __restrict__ keep_prob)
{
    int m = blockIdx.x * 256 + threadIdx.x;
    int b = m / Nv_, n = m - b * Nv_;
    float l0 = b2[0], l1 = b2[1];
#pragma unroll
    for (int t = 0; t < 12; ++t) {
        l0 += partials[(size_t)m * 24 + t * 2 + 0];
        l1 += partials[(size_t)m * 24 + t * 2 + 1];
    }
    const float UHI = (float)(1.0 - 1e-6);
    float U0 = fminf(fmaxf(gumbel[(size_t)m * 2 + 0], 1e-6f), UHI);
    float U1 = fminf(fmaxf(gumbel[(size_t)m * 2 + 1], 1e-6f), UHI);
    float t0 = (float)log((double)U0);
    float g0 = -(float)log((double)(-t0));
    float t1 = (float)log((double)U1);
    float g1 = -(float)log((double)(-t1));
    float dlog = (l1 + g1) - (l0 + g0);
    float kp = 1.f / (1.f + expf(-dlog));
    policy[(size_t)b * 197 + 1 + n] = (dlog > 0.f) ? 1.f : 0.f;
    if (n == 0) policy[(size_t)b * 197] = 1.f;
    keep_prob[m] = kp;
}

__global__ __launch_bounds__(256)
void batch_reduce(const float* __restrict__ keep_prob, float* __restrict__ sum_kp)
{
    __shared__ float part[4];
    int b = blockIdx.x, tid = threadIdx.x;
    float vs = (tid < Nv_) ? keep_prob[(size_t)b * Nv_ + tid] : 0.f;
#pragma unroll
    for (int off = 32; off; off >>= 1) vs += __shfl_xor(vs, off, 64);
    if ((tid & 63) == 0) part[tid >> 6] = vs;
    __syncthreads();
    if (tid == 0) sum_kp[b] = part[0] + part[1] + part[2] + part[3];
}

__global__ __launch_bounds__(256)
void pw_scale(float* __restrict__ phi, const float* __restrict__ keep_prob,
              const float* __restrict__ sum_kp)
{
    int m = blockIdx.x * 4 + (threadIdx.x >> 6);
    int lane = threadIdx.x & 63;
    float4* row = (float4*)phi + (size_t)m * 64;
    float4 vv = row[lane];
    float ss = vv.x * vv.x + vv.y * vv.y + vv.z * vv.z + vv.w * vv.w;
#pragma unroll
    for (int off = 32; off; off >>= 1) ss += __shfl_xor(ss, off, 64);
    float nrm = fmaxf(sqrtf(ss), 1e-12f);
    int b = m / Nv_;
    float kp = keep_prob[m];
    float meanw = sum_kp[b] * (1.f / 196.f);
    float wn = fmaxf(kp / (meanw + 1e-12f), 1e-6f);
    float sc = sqrtf(wn) / nrm;
    vv.x *= sc; vv.y *= sc; vv.z *= sc; vv.w *= sc;
    row[lane] = vv;
}

// deterministic serial finalize: loss_ratio + Taylor logdet combine
__global__ void finalize_kernel(const float* __restrict__ sum_kp,
                                const float* __restrict__ tpart,
                                float* __restrict__ out)
{
    float tot = 0.f, ld = 0.f;
    for (int b = 0; b < B_; ++b) {
        tot += sum_kp[b];
        float s1 = 0.f, s2 = 0.f, s3 = 0.f, s4 = 0.f;
        for (int blk = 0; blk < 4; ++blk) {
            const float* p = tpart + ((size_t)b * 4 + blk) * 4;
            s1 += p[0]; s2 += p[1]; s3 += p[2]; s4 += p[3];
        }
        ld += s1 - 0.5f * s2 + (1.f / 3.f) * s3 - 0.25f * s4;
    }
    float mean = tot * (1.f / 25088.f);
    float d = mean - 0.7f;
    out[25216] = d * d;
    out[25217] = -ld * (1.f / 128.f);
}

// ---------------------------------------------------------------------------
extern "C" void kernel_launch(void* const* d_in, const int* in_sizes, int n_in,
                              void* d_out, int out_size, void* d_ws, size_t ws_size,
                              hipStream_t stream)
{
    const float* x      = (const float*)d_in[0];
    const float* text   = (const float*)d_in[1];
    const float* gumbel = (const float*)d_in[2];
    const float* Wq     = (const float*)d_in[3];
    const float* bq     = (const float*)d_in[4];
    const float* Wk     = (const float*)d_in[5];
    const float* bk     = (const float*)d_in[6];
    const float* Wv     = (const float*)d_in[7];
    const float* bv     = (const float*)d_in[8];
    const float* W1     = (const float*)d_in[9];
    const float* b1     = (const float*)d_in[10];
    const float* W2     = (const float*)d_in[11];
    const float* b2     = (const float*)d_in[12];
    const float* Wdpp   = (const float*)d_in[13];
    float* out = (float*)d_out;

    float* ws = (float*)d_ws;
    float* q          = ws;                       // 19,267,584 f ; M overlays
    float* kbuf       = q + 19267584;
    float* vbuf       = kbuf + 3145728;
    float* phi        = vbuf + 3145728;
    float* partials   = phi + 6422528;            // 602,112 f; tpart overlays
    float* keep_prob  = partials + 602112;
    float* sum_kp     = keep_prob + 25088;
    float* logdet_arr = sum_kp + 128;             // (unused, kept for layout)
    float* M          = ws;                       // 128*196*208 = 5,218,304 f
    float* tpart      = partials;                 // 2048 f (dead after keep)

    short* Wq_h = (short*)(logdet_arr + 128);
    short* Wq_l = Wq_h + 589824;
    short* W1_h = Wq_l + 589824;
    short* W1_l = W1_h + 589824;
    short* Wk_h = W1_l + 589824;
    short* Wk_l = Wk_h + 393216;
    short* Wv_h = Wk_l + 393216;
    short* Wv_l = Wv_h + 393216;
    short* Wd_h = Wv_l + 393216;
    short* Wd_l = Wd_h + 196608;
    short* Xh = Wd_l + 196608;                    // 19,267,584 shorts each
    short* Xl = Xh + 19267584;
    short* Th = Xl + 19267584;                    //  2,097,152 shorts each
    short* Tl = Th + 2097152;
    short* Fh = Xh;                               // overlay: X dead after phi
    short* Fl = Xl;

    dim3 blk(256);

    split_all<<<dim3(8448), blk, 0, stream>>>(Wq, W1, Wk, Wv, Wdpp,
                                              Wq_h, Wq_l, W1_h, W1_l,
                                              Wk_h, Wk_l, Wv_h, Wv_l,
                                              Wd_h, Wd_l);
    split_x<<<dim3(9408), blk, 0, stream>>>(x, Xh, Xl);
    split_text<<<dim3(1024), blk, 0, stream>>>(text, Th, Tl);

    mfma_gemm<0><<<dim3(32,6,2), blk, 0, stream>>>(Th, Tl, Wk_h, Wk_l, bk, kbuf, 768, 512,
                                                   nullptr, nullptr,
                                                   Wv_h, Wv_l, bv, vbuf);
    mfma_gemm<0><<<dim3(196,6,1), blk, 0, stream>>>(Xh, Xl, Wq_h, Wq_l, bq, q, 768, 768,
                                                    nullptr, nullptr,
                                                    Wq_h, Wq_l, bq, q);
    mfma_gemm<0><<<dim3(196,2,1), blk, 0, stream>>>(Xh, Xl, Wd_h, Wd_l, nullptr, phi, 256, 768,
                                                    nullptr, nullptr,
                                                    Wd_h, Wd_l, nullptr, phi);
    attn_kernel<<<dim3(B_*H_), blk, 0, stream>>>(q, kbuf, vbuf, x, Fh, Fl);
    mfma_gemm<1><<<dim3(196,6,1), blk, 0, stream>>>(Fh, Fl, W1_h, W1_l, b1, nullptr, 768, 768,
                                                    W2, partials,
                                                    W1_h, W1_l, b1, nullptr);
    keep_kernel<<<dim3(98), blk, 0, stream>>>(partials, b2, gumbel, out, keep_prob);
    batch_reduce<<<dim3(B_), blk, 0, stream>>>(keep_prob, sum_kp);
    pw_scale<<<dim3(6272), blk, 0, stream>>>(phi, keep_prob, sum_kp);
    // M = phi@phi^T*scale + eps*I (stride 208, zero pad) into dead q region
    gram_kernel<<<dim3(2,2,B_), blk, 0, stream>>>(phi, M,
                                                  1.0f/(256.0f*196.0f*0.01f));
    // partial traces of M^2/M^3/M^4 (tpart overlays dead partials region)
    taylor_gemm<<<dim3(2,2,B_), blk, 0, stream>>>(M, tpart);
    finalize_kernel<<<dim3(1), dim3(1), 0, stream>>>(sum_kp, tpart, out);
}

// Round 15
// 609.863 us; speedup vs baseline: 1.1753x; 1.0076x over previous
//
#include <hip/hip_runtime.h>
#include <math.h>

#define B_   128
#define L_   197
#define C_   768
#define Nv_  196
#define Lt_  32
#define Ct_  512
#define H_   12
#define DH_  64
#define DPP_ 256
#define MTOK 25088   // B_*Nv_
#define MLD_ 208     // padded row stride of M (196 cols + 12 zero pad)

typedef __attribute__((ext_vector_type(8))) short bf16x8_t;
typedef __attribute__((ext_vector_type(4))) float f32x4_t;

// async global->LDS, 16B per lane; dest = wave-uniform base + lane*16
__device__ __forceinline__ void gload_lds16(const short* g, short* l) {
    __builtin_amdgcn_global_load_lds(
        (const __attribute__((address_space(1))) unsigned int*)g,
        (__attribute__((address_space(3))) unsigned int*)l,
        16, 0, 0);
}

// split fp32 -> bf16 hi (truncate) + bf16 lo (RNE of remainder)
__device__ __forceinline__ void split_bf16(float a, unsigned &h, unsigned &l) {
    unsigned u = __float_as_uint(a);
    unsigned hu = u & 0xffff0000u;
    h = hu >> 16;
    float lf = a - __uint_as_float(hu);
    unsigned ul = __float_as_uint(lf);
    l = (ul + 0x7fffu + ((ul >> 16) & 1u)) >> 16;
}

__device__ __forceinline__ void split8_pack(const float* av, uint4& Hh, uint4& Ll) {
    unsigned hv[8], lv[8];
#pragma unroll
    for (int j = 0; j < 8; ++j) split_bf16(av[j], hv[j], lv[j]);
    Hh.x = hv[0] | (hv[1] << 16); Hh.y = hv[2] | (hv[3] << 16);
    Hh.z = hv[4] | (hv[5] << 16); Hh.w = hv[6] | (hv[7] << 16);
    Ll.x = lv[0] | (lv[1] << 16); Ll.y = lv[2] | (lv[3] << 16);
    Ll.z = lv[4] | (lv[5] << 16); Ll.w = lv[6] | (lv[7] << 16);
}

// ---------------------------------------------------------------------------
// fused weight pre-split (all 5 weights in one launch) — r9-verified
// ---------------------------------------------------------------------------
#define NWQ 589824
#define NWK 393216
#define NWD 196608
__global__ __launch_bounds__(256)
void split_all(const float* __restrict__ Wq, const float* __restrict__ W1,
               const float* __restrict__ Wk, const float* __restrict__ Wv,
               const float* __restrict__ Wd,
               short* __restrict__ Wq_h, short* __restrict__ Wq_l,
               short* __restrict__ W1_h, short* __restrict__ W1_l,
               short* __restrict__ Wk_h, short* __restrict__ Wk_l,
               short* __restrict__ Wv_h, short* __restrict__ Wv_l,
               short* __restrict__ Wd_h, short* __restrict__ Wd_l)
{
    int j = blockIdx.x * 256 + threadIdx.x;   // total 2,162,688 = 8448*256
    const float* src; short *hi, *lo;
    if (j < NWQ)                { src = Wq; hi = Wq_h; lo = Wq_l; }
    else if ((j -= NWQ) < NWQ)  { src = W1; hi = W1_h; lo = W1_l; }
    else if ((j -= NWQ) < NWK)  { src = Wk; hi = Wk_h; lo = Wk_l; }
    else if ((j -= NWK) < NWK)  { src = Wv; hi = Wv_h; lo = Wv_l; }
    else                        { j -= NWK;  src = Wd; hi = Wd_h; lo = Wd_l; }
    unsigned h, l;
    split_bf16(src[j], h, l);
    hi[j] = (short)h; lo[j] = (short)l;
}

// ---------------------------------------------------------------------------
// activation pre-splits (one pass, vectorized) — r11
// ---------------------------------------------------------------------------
__global__ __launch_bounds__(256)
void split_x(const float* __restrict__ x, short* __restrict__ Xh,
             short* __restrict__ Xl)
{
    int idx = blockIdx.x * 256 + threadIdx.x;    // 2,408,448 chunks of 8
    int m = idx / 96, c8 = (idx - m * 96) * 8;
    int b = m / Nv_, n = m - b * Nv_;
    const float* src = x + ((size_t)(n + 1) * B_ + b) * C_ + c8;
    float av[8];
    *(float4*)&av[0] = *(const float4*)src;
    *(float4*)&av[4] = *(const float4*)(src + 4);
    uint4 Hh, Ll;
    split8_pack(av, Hh, Ll);
    *(uint4*)&Xh[(size_t)m * C_ + c8] = Hh;
    *(uint4*)&Xl[(size_t)m * C_ + c8] = Ll;
}

__global__ __launch_bounds__(256)
void split_text(const float* __restrict__ t, short* __restrict__ Th,
                short* __restrict__ Tl)
{
    int idx = blockIdx.x * 256 + threadIdx.x;    // 262,144 chunks of 8
    const float* src = t + (size_t)idx * 8;
    float av[8];
    *(float4*)&av[0] = *(const float4*)src;
    *(float4*)&av[4] = *(const float4*)(src + 4);
    uint4 Hh, Ll;
    split8_pack(av, Hh, Ll);
    *(uint4*)&Th[(size_t)idx * 8] = Hh;
    *(uint4*)&Tl[(size_t)idx * 8] = Ll;
}

// ---------------------------------------------------------------------------
// 3-term split-bf16 MFMA GEMM via global_load_lds (width 16).
// LDS: linear [128][32] shorts per array (64B rows, 8KB/array, 32KB total).
// Swizzle (rule 21, both sides): LDS(row, c) holds global chunk c ^ f(row),
// f(row)=(row>>1)&3. Staging: wave w covers rows w*32..+31; lane l deposits
// 16B at linear base + l*16 (HW), source chunk = (l&3)^((l>>3)&3).
// Frag read: chunk' = lq ^ ((lr>>1)&3) -> every b128 access hits each of the
// 8 (parity,chunk) 4-bank slots exactly 8x/wave = data-volume minimum.
// Operand VALUES identical to r14 -> MFMA outputs bit-identical.
// ---------------------------------------------------------------------------
template<int EPI>
__global__ __launch_bounds__(256)
void mfma_gemm(const short* __restrict__ Ah_g, const short* __restrict__ Al_g,
               const short* __restrict__ Bh_g, const short* __restrict__ Bl_g,
               const float* __restrict__ bias,
               float* __restrict__ Cst, int Nst, int Kd,
               const float* __restrict__ W2, float* __restrict__ partials,
               const short* Bh2, const short* Bl2, const float* bias2,
               float* Cst2)
{
    if (blockIdx.z) { Bh_g = Bh2; Bl_g = Bl2; bias = bias2; Cst = Cst2; }
    __shared__ short Ah[128 * 32], Al[128 * 32], Bh[128 * 32], Bl[128 * 32];
    const int tid = threadIdx.x;
    const int m0 = blockIdx.x * 128, n0 = blockIdx.y * 128;
    const int l = tid & 63, wid = tid >> 6;
    const int wr = wid >> 1, wc = wid & 1;
    const int lr = l & 15, lq = l >> 4;

    // staging source pointers: seg0 row = wid*32 + (l>>2); seg1 = +16
    const int sr = wid * 32 + (l >> 2);
    const int sc = 8 * ((l & 3) ^ ((l >> 3) & 3));   // pre-swizzled chunk
    const short* a0  = Ah_g + (size_t)(m0 + sr) * Kd + sc;
    const short* a1  = Ah_g + (size_t)(m0 + sr + 16) * Kd + sc;
    const short* al0 = Al_g + (size_t)(m0 + sr) * Kd + sc;
    const short* al1 = Al_g + (size_t)(m0 + sr + 16) * Kd + sc;
    const short* b0  = Bh_g + (size_t)(n0 + sr) * Kd + sc;
    const short* b1  = Bh_g + (size_t)(n0 + sr + 16) * Kd + sc;
    const short* bl0 = Bl_g + (size_t)(n0 + sr) * Kd + sc;
    const short* bl1 = Bl_g + (size_t)(n0 + sr + 16) * Kd + sc;
    short* dA0  = &Ah[(wid * 32) * 32];
    short* dA1  = &Ah[(wid * 32 + 16) * 32];
    short* dAl0 = &Al[(wid * 32) * 32];
    short* dAl1 = &Al[(wid * 32 + 16) * 32];
    short* dB0  = &Bh[(wid * 32) * 32];
    short* dB1  = &Bh[(wid * 32 + 16) * 32];
    short* dBl0 = &Bl[(wid * 32) * 32];
    short* dBl1 = &Bl[(wid * 32 + 16) * 32];

    const int swzr = (lr >> 1) & 3;     // frag-read swizzle

    f32x4_t acc[4][4];
#pragma unroll
    for (int m = 0; m < 4; ++m)
#pragma unroll
        for (int n = 0; n < 4; ++n) {
            acc[m][n][0] = 0.f; acc[m][n][1] = 0.f;
            acc[m][n][2] = 0.f; acc[m][n][3] = 0.f;
        }

    for (int k0 = 0; k0 < Kd; k0 += 32) {
        gload_lds16(a0  + k0, dA0);
        gload_lds16(a1  + k0, dA1);
        gload_lds16(al0 + k0, dAl0);
        gload_lds16(al1 + k0, dAl1);
        gload_lds16(b0  + k0, dB0);
        gload_lds16(b1  + k0, dB1);
        gload_lds16(bl0 + k0, dBl0);
        gload_lds16(bl1 + k0, dBl1);
        __syncthreads();    // drains vmcnt (compiler-inserted) before reads

        bf16x8_t ahf[4], alf[4], bhf[4], blf[4];
#pragma unroll
        for (int m = 0; m < 4; ++m) {
            int ro = (wr * 64 + m * 16 + lr) * 32 + ((lq ^ swzr) * 8);
            ahf[m] = *(const bf16x8_t*)&Ah[ro];
            alf[m] = *(const bf16x8_t*)&Al[ro];
        }
#pragma unroll
        for (int n = 0; n < 4; ++n) {
            int ro = (wc * 64 + n * 16 + lr) * 32 + ((lq ^ swzr) * 8);
            bhf[n] = *(const bf16x8_t*)&Bh[ro];
            blf[n] = *(const bf16x8_t*)&Bl[ro];
        }
#pragma unroll
        for (int m = 0; m < 4; ++m)
#pragma unroll
            for (int n = 0; n < 4; ++n) {
                acc[m][n] = __builtin_amdgcn_mfma_f32_16x16x32_bf16(ahf[m], bhf[n], acc[m][n], 0, 0, 0);
                acc[m][n] = __builtin_amdgcn_mfma_f32_16x16x32_bf16(ahf[m], blf[n], acc[m][n], 0, 0, 0);
                acc[m][n] = __builtin_amdgcn_mfma_f32_16x16x32_bf16(alf[m], bhf[n], acc[m][n], 0, 0, 0);
            }
        __syncthreads();
    }

    if constexpr (EPI == 0) {
#pragma unroll
        for (int n = 0; n < 4; ++n) {
            int col = n0 + wc * 64 + n * 16 + lr;
            float bv = bias ? bias[col] : 0.f;
#pragma unroll
            for (int m = 0; m < 4; ++m) {
                int rowb = m0 + wr * 64 + m * 16 + lq * 4;
#pragma unroll
                for (int r = 0; r < 4; ++r)
                    Cst[(size_t)(rowb + r) * Nst + col] = acc[m][n][r] + bv;
            }
        }
    } else {
        int coln[4]; float b1v[4], w20[4], w21[4];
#pragma unroll
        for (int n = 0; n < 4; ++n) {
            coln[n] = n0 + wc * 64 + n * 16 + lr;
            b1v[n] = bias[coln[n]];
            w20[n] = W2[coln[n]];
            w21[n] = W2[C_ + coln[n]];
        }
        const int pi = (blockIdx.y * 2 + wc) * 2;
#pragma unroll
        for (int m = 0; m < 4; ++m)
#pragma unroll
            for (int r = 0; r < 4; ++r) {
                float p0 = 0.f, p1 = 0.f;
#pragma unroll
                for (int n = 0; n < 4; ++n) {
                    float h = acc[m][n][r] + b1v[n];
                    float gl = h / (1.f + expf(-1.702f * h));
                    p0 = fmaf(gl, w20[n], p0);
                    p1 = fmaf(gl, w21[n], p1);
                }
#pragma unroll
                for (int off = 8; off; off >>= 1) {
                    p0 += __shfl_xor(p0, off, 16);
                    p1 += __shfl_xor(p1, off, 16);
                }
                if (lr == 0) {
                    int row = m0 + wr * 64 + m * 16 + lq * 4 + r;
                    partials[(size_t)row * 24 + pi + 0] = p0;
                    partials[(size_t)row * 24 + pi + 1] = p1;
                }
            }
    }
}

// ---------------------------------------------------------------------------
// gram: M = phi@phi^T * scale + 1e-5*I, row stride MLD_=208, zero pad.
// (r14-verified)
// ---------------------------------------------------------------------------
__global__ __launch_bounds__(256)
void gram_kernel(const float* __restrict__ A, float* __restrict__ Mout,
                 float scale)
{
    __shared__ float As[16][132];
    __shared__ float Bs[16][132];
    const int tid = threadIdx.x;
    const int tx = tid & 15, ty = tid >> 4;
    const int m0 = blockIdx.x * 128, n0 = blockIdx.y * 128;
    const int bz = blockIdx.z;
    const float* Ab = A + (size_t)bz * Nv_ * DPP_;
    float* Mb = Mout + (size_t)bz * Nv_ * MLD_;

    const int lrow = tid >> 2;
    const int lk   = (tid & 3) << 2;

    const float* aptr[2]; const float* bptr[2];
    bool aval[2], bval[2];
#pragma unroll
    for (int Lq = 0; Lq < 2; ++Lq) {
        int row = lrow + Lq * 64;
        int gr = m0 + row;
        aval[Lq] = (gr < Nv_);
        aptr[Lq] = Ab + (size_t)(aval[Lq] ? gr : 0) * DPP_ + lk;
        int gc = n0 + row;
        bval[Lq] = (gc < Nv_);
        bptr[Lq] = Ab + (size_t)(bval[Lq] ? gc : 0) * DPP_ + lk;
    }

    float acc[8][8];
#pragma unroll
    for (int r = 0; r < 8; ++r)
#pragma unroll
        for (int c = 0; c < 8; ++c) acc[r][c] = 0.f;

    for (int k0 = 0; k0 < DPP_; k0 += 16) {
#pragma unroll
        for (int Lq = 0; Lq < 2; ++Lq) {
            int row = lrow + Lq * 64;
            float4 va = aval[Lq] ? *(const float4*)(aptr[Lq] + k0)
                                 : make_float4(0.f, 0.f, 0.f, 0.f);
            As[lk+0][row] = va.x; As[lk+1][row] = va.y;
            As[lk+2][row] = va.z; As[lk+3][row] = va.w;
            float4 vb = bval[Lq] ? *(const float4*)(bptr[Lq] + k0)
                                 : make_float4(0.f, 0.f, 0.f, 0.f);
            Bs[lk+0][row] = vb.x; Bs[lk+1][row] = vb.y;
            Bs[lk+2][row] = vb.z; Bs[lk+3][row] = vb.w;
        }
        __syncthreads();
#pragma unroll
        for (int kk = 0; kk < 16; ++kk) {
            float a[8], bfr[8];
            *(float4*)&a[0]   = *(const float4*)&As[kk][ty * 8];
            *(float4*)&a[4]   = *(const float4*)&As[kk][ty * 8 + 4];
            *(float4*)&bfr[0] = *(const float4*)&Bs[kk][tx * 4];
            *(float4*)&bfr[4] = *(const float4*)&Bs[kk][64 + tx * 4];
#pragma unroll
            for (int r = 0; r < 8; ++r)
#pragma unroll
                for (int c = 0; c < 8; ++c)
                    acc[r][c] = fmaf(a[r], bfr[c], acc[r][c]);
        }
        __syncthreads();
    }

#pragma unroll
    for (int r = 0; r < 8; ++r) {
        int gr = m0 + ty * 8 + r;
        if (gr >= Nv_) continue;
#pragma unroll
        for (int half = 0; half < 2; ++half) {
            int gc0 = n0 + half * 64 + tx * 4;
#pragma unroll
            for (int c = 0; c < 4; ++c) {
                int gc = gc0 + c;
                if (gc < Nv_) {
                    float v = acc[r][half*4+c] * scale;
                    if (gr == gc) v += 1e-5f;   // M = G + eps*I
                    Mb[(size_t)gr * MLD_ + gc] = v;
                } else if (gc < MLD_) {
                    Mb[(size_t)gr * MLD_ + gc] = 0.f;   // zero pad
                }
            }
        }
    }
}

// ---------------------------------------------------------------------------
// taylor_gemm: M2 tile + partial traces (r14-verified).
// logdet = tr(M) - tr(M^2)/2 + tr(M^3)/3 - tr(M^4)/4, err ~2e-8.
// ---------------------------------------------------------------------------
__global__ __launch_bounds__(256)
void taylor_gemm(const float* __restrict__ Mg, float* __restrict__ tpart)
{
    __shared__ float As[16][132];
    __shared__ float Bs[16][132];
    __shared__ float wred[4][4];
    const int tid = threadIdx.x;
    const int tx = tid & 15, ty = tid >> 4;
    const int m0 = blockIdx.x * 128, n0 = blockIdx.y * 128;
    const int bz = blockIdx.z;
    const float* Mb = Mg + (size_t)bz * Nv_ * MLD_;

    const int lrow = tid >> 2;
    const int lk   = (tid & 3) << 2;

    const float* aptr[2]; const float* bptr[2];
    bool aval[2], bval[2];
#pragma unroll
    for (int Lq = 0; Lq < 2; ++Lq) {
        int row = lrow + Lq * 64;
        int gr = m0 + row;
        aval[Lq] = (gr < Nv_);
        aptr[Lq] = Mb + (size_t)(aval[Lq] ? gr : 0) * MLD_ + lk;
        int gc = n0 + row;
        bval[Lq] = (gc < Nv_);
        bptr[Lq] = Mb + (size_t)(bval[Lq] ? gc : 0) * MLD_ + lk;
    }

    float acc[8][8];
#pragma unroll
    for (int r = 0; r < 8; ++r)
#pragma unroll
        for (int c = 0; c < 8; ++c) acc[r][c] = 0.f;

    for (int k0 = 0; k0 < MLD_; k0 += 16) {   // 13 tiles; pad cols are zero
#pragma unroll
        for (int Lq = 0; Lq < 2; ++Lq) {
            int row = lrow + Lq * 64;
            float4 va = aval[Lq] ? *(const float4*)(aptr[Lq] + k0)
                                 : make_float4(0.f, 0.f, 0.f, 0.f);
            As[lk+0][row] = va.x; As[lk+1][row] = va.y;
            As[lk+2][row] = va.z; As[lk+3][row] = va.w;
            float4 vb = bval[Lq] ? *(const float4*)(bptr[Lq] + k0)
                                 : make_float4(0.f, 0.f, 0.f, 0.f);
            Bs[lk+0][row] = vb.x; Bs[lk+1][row] = vb.y;
            Bs[lk+2][row] = vb.z; Bs[lk+3][row] = vb.w;
        }
        __syncthreads();
#pragma unroll
        for (int kk = 0; kk < 16; ++kk) {
            float a[8], bfr[8];
            *(float4*)&a[0]   = *(const float4*)&As[kk][ty * 8];
            *(float4*)&a[4]   = *(const float4*)&As[kk][ty * 8 + 4];
            *(float4*)&bfr[0] = *(const float4*)&Bs[kk][tx * 4];
            *(float4*)&bfr[4] = *(const float4*)&Bs[kk][64 + tx * 4];
#pragma unroll
            for (int r = 0; r < 8; ++r)
#pragma unroll
                for (int c = 0; c < 8; ++c)
                    acc[r][c] = fmaf(a[r], bfr[c], acc[r][c]);
        }
        __syncthreads();
    }

    float t1 = 0.f, t2 = 0.f, t3 = 0.f, t4 = 0.f;
#pragma unroll
    for (int r = 0; r < 8; ++r) {
        int gr = m0 + ty * 8 + r;
        if (gr >= Nv_) continue;
#pragma unroll
        for (int half = 0; half < 2; ++half) {
            int gc0 = n0 + half * 64 + tx * 4;
#pragma unroll
            for (int c = 0; c < 4; ++c) {
                int gc = gc0 + c;
                if (gc < Nv_) {
                    float mij = Mb[(size_t)gr * MLD_ + gc];
                    float m2  = acc[r][half*4+c];
                    if (gr == gc) t1 += mij;
                    t2 = fmaf(mij, mij, t2);
                    t3 = fmaf(m2, mij, t3);
                    t4 = fmaf(m2, m2, t4);
                }
            }
        }
    }
#pragma unroll
    for (int off = 32; off; off >>= 1) {
        t1 += __shfl_xor(t1, off, 64);
        t2 += __shfl_xor(t2, off, 64);
        t3 += __shfl_xor(t3, off, 64);
        t4 += __shfl_xor(t4, off, 64);
    }
    const int wv = tid >> 6;
    if ((tid & 63) == 0) {
        wred[wv][0] = t1; wred[wv][1] = t2; wred[wv][2] = t3; wred[wv][3] = t4;
    }
    __syncthreads();
    if (tid == 0) {
        const int blk = blockIdx.y * 2 + blockIdx.x;
        float* dst = tpart + ((size_t)bz * 4 + blk) * 4;
        dst[0] = wred[0][0] + wred[1][0] + wred[2][0] + wred[3][0];
        dst[1] = wred[0][1] + wred[1][1] + wred[2][1] + wred[3][1];
        dst[2] = wred[0][2] + wred[1][2] + wred[2][2] + wred[3][2];
        dst[3] = wred[0][3] + wred[1][3] + wred[2][3] + wred[3][3];
    }
}

// ---------------------------------------------------------------------------
// Attention per (b,h) — r10/r11-verified (4 rows/wave, all-lane score,
// prefetch; output pre-split to Fh/Fl).
// ---------------------------------------------------------------------------
__global__ __launch_bounds__(256)
void attn_kernel(const float* __restrict__ q, const float* __restrict__ k,
                 const float* __restrict__ v, const float* __restrict__ x,
                 short* __restrict__ Fh, short* __restrict__ Fl)
{
    __shared__ float Ks[Lt_][DH_ + 4];
    __shared__ float Vs[Lt_][DH_ + 1];
    __shared__ float qs[16][DH_];
    __shared__ float as[16][Lt_];
    const int bh = blockIdx.x;
    const int b = bh / H_, h = bh - b * H_;
    const int tid = threadIdx.x;
    const int wv = tid >> 6, lane = tid & 63;
    const int half = lane >> 5;
    const int key = lane & 31;

    for (int idx = tid; idx < Lt_ * 16; idx += 256) {
        int l = idx >> 4, dq = (idx & 15) << 2;
        size_t off = ((size_t)(b * Lt_ + l)) * C_ + h * DH_ + dq;
        float4 kv4 = *(const float4*)(k + off);
        Ks[l][dq] = kv4.x; Ks[l][dq + 1] = kv4.y; Ks[l][dq + 2] = kv4.z; Ks[l][dq + 3] = kv4.w;
        float4 vv4 = *(const float4*)(v + off);
        Vs[l][dq] = vv4.x; Vs[l][dq + 1] = vv4.y; Vs[l][dq + 2] = vv4.z; Vs[l][dq + 3] = vv4.w;
    }
    __syncthreads();

    const size_t qbase = (size_t)b * Nv_ * C_ + h * DH_ + lane;
    const size_t xbase = (size_t)b * C_ + h * DH_ + lane;

    float qv[4], xv[4];
#pragma unroll
    for (int j = 0; j < 4; ++j) {
        qv[j] = q[qbase + (size_t)(wv * 4 + j) * C_];
        xv[j] = x[xbase + (size_t)(wv * 4 + j + 1) * B_ * C_];
    }

    for (int it = 0; it < 13; ++it) {
        const int base = it * 16 + wv * 4;
        if (base > 192) break;
        float cq[4], cx[4];
#pragma unroll
        for (int j = 0; j < 4; ++j) { cq[j] = qv[j]; cx[j] = xv[j]; }
        const int nbase = base + 16;
        if (nbase <= 192) {
#pragma unroll
            for (int j = 0; j < 4; ++j) {
                qv[j] = q[qbase + (size_t)(nbase + j) * C_];
                xv[j] = x[xbase + (size_t)(nbase + j + 1) * B_ * C_];
            }
        }
        const int ws = wv * 4;
#pragma unroll
        for (int j = 0; j < 4; ++j) qs[ws + j][lane] = cq[j];

        const int s0 = ws + half * 2;
        float s1 = 0.f, s2 = 0.f;
#pragma unroll
        for (int d4 = 0; d4 < DH_; d4 += 4) {
            float4 k4  = *(const float4*)&Ks[key][d4];
            float4 q4a = *(const float4*)&qs[s0][d4];
            float4 q4b = *(const float4*)&qs[s0 + 1][d4];
            s1 = fmaf(q4a.x, k4.x, s1); s2 = fmaf(q4b.x, k4.x, s2);
            s1 = fmaf(q4a.y, k4.y, s1); s2 = fmaf(q4b.y, k4.y, s2);
            s1 = fmaf(q4a.z, k4.z, s1); s2 = fmaf(q4b.z, k4.z, s2);
            s1 = fmaf(q4a.w, k4.w, s1); s2 = fmaf(q4b.w, k4.w, s2);
        }
        s1 *= 0.125f; s2 *= 0.125f;
        float mx1 = s1, mx2 = s2;
#pragma unroll
        for (int off = 16; off; off >>= 1) {
            mx1 = fmaxf(mx1, __shfl_xor(mx1, off, 32));
            mx2 = fmaxf(mx2, __shfl_xor(mx2, off, 32));
        }
        float p1v = expf(s1 - mx1);
        float p2v = expf(s2 - mx2);
        float su1 = p1v, su2 = p2v;
#pragma unroll
        for (int off = 16; off; off >>= 1) {
            su1 += __shfl_xor(su1, off, 32);
            su2 += __shfl_xor(su2, off, 32);
        }
        as[s0][key] = p1v / su1;
        as[s0 + 1][key] = p2v / su2;

        float c0 = 0.f, c1 = 0.f, c2 = 0.f, c3 = 0.f;
#pragma unroll
        for (int l4 = 0; l4 < Lt_; l4 += 4) {
            float4 a0 = *(const float4*)&as[ws + 0][l4];
            float4 a1 = *(const float4*)&as[ws + 1][l4];
            float4 a2 = *(const float4*)&as[ws + 2][l4];
            float4 a3 = *(const float4*)&as[ws + 3][l4];
            float v0 = Vs[l4 + 0][lane], v1 = Vs[l4 + 1][lane];
            float v2 = Vs[l4 + 2][lane], v3 = Vs[l4 + 3][lane];
            c0 = fmaf(a0.x, v0, c0); c1 = fmaf(a1.x, v0, c1);
            c2 = fmaf(a2.x, v0, c2); c3 = fmaf(a3.x, v0, c3);
            c0 = fmaf(a0.y, v1, c0); c1 = fmaf(a1.y, v1, c1);
            c2 = fmaf(a2.y, v1, c2); c3 = fmaf(a3.y, v1, c3);
            c0 = fmaf(a0.z, v2, c0); c1 = fmaf(a1.z, v2, c1);
            c2 = fmaf(a2.z, v2, c2); c3 = fmaf(a3.z, v2, c3);
            c0 = fmaf(a0.w, v3, c0); c1 = fmaf(a1.w, v3, c1);
            c2 = fmaf(a2.w, v3, c2); c3 = fmaf(a3.w, v3, c3);
        }
        float fo[4] = {c0 + cx[0], c1 + cx[1], c2 + cx[2], c3 + cx[3]};
#pragma unroll
        for (int j = 0; j < 4; ++j) {
            unsigned hh, ll;
            split_bf16(fo[j], hh, ll);
            Fh[qbase + (size_t)(base + j) * C_] = (short)hh;
            Fl[qbase + (size_t)(base + j) * C_] = (short)ll;
        }
    }
}

// ---------------------------------------------------------------------------
// keep decisions: logits from partials[m][24] (+b2), gumbel, policy, keep_prob
// ---------------------------------------------------------------------------
__global__ __launch_bounds__(256)
void keep_kernel(const float* __restrict__ partials, const float* __restrict__ b2,
                 const float* __restrict__ gumbel, float* __restrict__ policy,
                 float* __restrict__ keep_prob)
{
    int m = blockIdx.x * 256 + threadIdx.x;
    int b = m / Nv_, n = m - b * Nv_;
    float l0 = b2[0], l1 = b2[1];
#pragma unroll
    for (int t = 0; t < 12; ++t) {
        l0 += partials[(size_t)m * 24 + t * 2 + 0];
        l1 += partials[(size_t)m * 24 + t * 2 + 1];
    }
    const float UHI = (float)(1.0 - 1e-6);
    float U0 = fminf(fmaxf(gumbel[(size_t)m * 2 + 0], 1e-6f), UHI);
    float U1 = fminf(fmaxf(gumbel[(size_t)m * 2 + 1], 1e-6f), UHI);
    float t0 = (float)log((double)U0);
    float g0 = -(float)log((double)(-t0));
    float t1 = (float)log((double)U1);
    float g1 = -(float)log((double)(-t1));
    float dlog = (l1 + g1) - (l0 + g0);
    float kp = 1.f / (1.f + expf(-dlog));
    policy[(size_t)b * 197 + 1 + n] = (dlog > 0.f) ? 1.f : 0.f;
    if (n == 0) policy[(size_t)b * 197] = 1.f;
    keep_prob[m] = kp;
}

__global__ __launch_bounds__(256)
void batch_reduce(const float* __restrict__ keep_prob, float* __restrict__ sum_kp)
{
    __shared__ float part[4];
    int b = blockIdx.x, tid = threadIdx.x;
    float vs = (tid < Nv_) ? keep_prob[(size_t)b * Nv_ + tid] : 0.f;
#pragma unroll
    for (int off = 32; off; off >>= 1) vs += __shfl_xor(vs, off, 64);
    if ((tid & 63) == 0) part[tid >> 6] = vs;
    __syncthreads();
    if (tid == 0) sum_kp[b] = part[0] + part[1] + part[2] + part[3];
}

__global__ __launch_bounds__(256)
void pw_scale(float* __restrict__ phi, const float* __restrict__ keep_prob,
              const float* __restrict__ sum_kp)
{
    int m = blockIdx.x * 4 + (threadIdx.x >> 6);
    int lane = threadIdx.x & 63;
    float4* row = (float4*)phi + (size_t)m * 64;
    float4 vv = row[lane];
    float ss = vv.x * vv.x + vv.y * vv.y + vv.z * vv.z + vv.w * vv.w;
#pragma unroll
    for (int off = 32; off; off >>= 1) ss += __shfl_xor(ss, off, 64);
    float nrm = fmaxf(sqrtf(ss), 1e-12f);
    int b = m / Nv_;
    float kp = keep_prob[m];
    float meanw = sum_kp[b] * (1.f / 196.f);
    float wn = fmaxf(kp / (meanw + 1e-12f), 1e-6f);
    float sc = sqrtf(wn) / nrm;
    vv.x *= sc; vv.y *= sc; vv.z *= sc; vv.w *= sc;
    row[lane] = vv;
}

// deterministic serial finalize: loss_ratio + Taylor logdet combine
__global__ void finalize_kernel(const float* __restrict__ sum_kp,
                                const float* __restrict__ tpart,
                                float* __restrict__ out)
{
    float tot = 0.f, ld = 0.f;
    for (int b = 0; b < B_; ++b) {
        tot += sum_kp[b];
        float s1 = 0.f, s2 = 0.f, s3 = 0.f, s4 = 0.f;
        for (int blk = 0; blk < 4; ++blk) {
            const float* p = tpart + ((size_t)b * 4 + blk) * 4;
            s1 += p[0]; s2 += p[1]; s3 += p[2]; s4 += p[3];
        }
        ld += s1 - 0.5f * s2 + (1.f / 3.f) * s3 - 0.25f * s4;
    }
    float mean = tot * (1.f / 25088.f);
    float d = mean - 0.7f;
    out[25216] = d * d;
    out[25217] = -ld * (1.f / 128.f);
}

// ---------------------------------------------------------------------------
extern "C" void kernel_launch(void* const* d_in, const int* in_sizes, int n_in,
                              void* d_out, int out_size, void* d_ws, size_t ws_size,
                              hipStream_t stream)
{
    const float* x      = (const float*)d_in[0];
    const float* text   = (const float*)d_in[1];
    const float* gumbel = (const float*)d_in[2];
    const float* Wq     = (const float*)d_in[3];
    const float* bq     = (const float*)d_in[4];
    const float* Wk     = (const float*)d_in[5];
    const float* bk     = (const float*)d_in[6];
    const float* Wv     = (const float*)d_in[7];
    const float* bv     = (const float*)d_in[8];
    const float* W1     = (const float*)d_in[9];
    const float* b1     = (const float*)d_in[10];
    const float* W2     = (const float*)d_in[11];
    const float* b2     = (const float*)d_in[12];
    const float* Wdpp   = (const float*)d_in[13];
    float* out = (float*)d_out;

    float* ws = (float*)d_ws;
    float* q          = ws;                       // 19,267,584 f ; M overlays
    float* kbuf       = q + 19267584;
    float* vbuf       = kbuf + 3145728;
    float* phi        = vbuf + 3145728;
    float* partials   = phi + 6422528;            // 602,112 f; tpart overlays
    float* keep_prob  = partials + 602112;
    float* sum_kp     = keep_prob + 25088;
    float* logdet_arr = sum_kp + 128;             // (unused, kept for layout)
    float* M          = ws;                       // 128*196*208 floats
    float* tpart      = partials;                 // 2048 f (dead after keep)

    short* Wq_h = (short*)(logdet_arr + 128);
    short* Wq_l = Wq_h + 589824;
    short* W1_h = Wq_l + 589824;
    short* W1_l = W1_h + 589824;
    short* Wk_h = W1_l + 589824;
    short* Wk_l = Wk_h + 393216;
    short* Wv_h = Wk_l + 393216;
    short* Wv_l = Wv_h + 393216;
    short* Wd_h = Wv_l + 393216;
    short* Wd_l = Wd_h + 196608;
    short* Xh = Wd_l + 196608;                    // 19,267,584 shorts each
    short* Xl = Xh + 19267584;
    short* Th = Xl + 19267584;                    //  2,097,152 shorts each
    short* Tl = Th + 2097152;
    short* Fh = Xh;                               // overlay: X dead after phi
    short* Fl = Xl;

    dim3 blk(256);

    split_all<<<dim3(8448), blk, 0, stream>>>(Wq, W1, Wk, Wv, Wdpp,
                                              Wq_h, Wq_l, W1_h, W1_l,
                                              Wk_h, Wk_l, Wv_h, Wv_l,
                                              Wd_h, Wd_l);
    split_x<<<dim3(9408), blk, 0, stream>>>(x, Xh, Xl);
    split_text<<<dim3(1024), blk, 0, stream>>>(text, Th, Tl);

    mfma_gemm<0><<<dim3(32,6,2), blk, 0, stream>>>(Th, Tl, Wk_h, Wk_l, bk, kbuf, 768, 512,
                                                   nullptr, nullptr,
                                                   Wv_h, Wv_l, bv, vbuf);
    mfma_gemm<0><<<dim3(196,6,1), blk, 0, stream>>>(Xh, Xl, Wq_h, Wq_l, bq, q, 768, 768,
                                                    nullptr, nullptr,
                                                    Wq_h, Wq_l, bq, q);
    mfma_gemm<0><<<dim3(196,2,1), blk, 0, stream>>>(Xh, Xl, Wd_h, Wd_l, nullptr, phi, 256, 768,
                                                    nullptr, nullptr,
                                                    Wd_h, Wd_l, nullptr, phi);
    attn_kernel<<<dim3(B_*H_), blk, 0, stream>>>(q, kbuf, vbuf, x, Fh, Fl);
    mfma_gemm<1><<<dim3(196,6,1), blk, 0, stream>>>(Fh, Fl, W1_h, W1_l, b1, nullptr, 768, 768,
                                                    W2, partials,
                                                    W1_h, W1_l, b1, nullptr);
    keep_kernel<<<dim3(98), blk, 0, stream>>>(partials, b2, gumbel, out, keep_prob);
    batch_reduce<<<dim3(B_), blk, 0, stream>>>(keep_prob, sum_kp);
    pw_scale<<<dim3(6272), blk, 0, stream>>>(phi, keep_prob, sum_kp);
    gram_kernel<<<dim3(2,2,B_), blk, 0, stream>>>(phi, M,
                                                  1.0f/(256.0f*196.0f*0.01f));
    taylor_gemm<<<dim3(2,2,B_), blk, 0, stream>>>(M, tpart);
    finalize_kernel<<<dim3(1), dim3(1), 0, stream>>>(sum_kp, tpart, out);
}

// Round 16
// 567.510 us; speedup vs baseline: 1.2631x; 1.0746x over previous
//
#include <hip/hip_runtime.h>
#include <math.h>

#define B_   128
#define L_   197
#define C_   768
#define Nv_  196
#define Lt_  32
#define Ct_  512
#define H_   12
#define DH_  64
#define DPP_ 256
#define MTOK 25088   // B_*Nv_
#define MLD_ 208     // padded row stride of M (196 cols + 12 zero pad)

typedef __attribute__((ext_vector_type(8))) short bf16x8_t;
typedef __attribute__((ext_vector_type(4))) float f32x4_t;

// async global->LDS, 16B per lane; dest = wave-uniform base + lane*16
__device__ __forceinline__ void gload_lds16(const short* g, short* l) {
    __builtin_amdgcn_global_load_lds(
        (const __attribute__((address_space(1))) unsigned int*)g,
        (__attribute__((address_space(3))) unsigned int*)l,
        16, 0, 0);
}

// split fp32 -> bf16 hi (truncate) + bf16 lo (RNE of remainder)
__device__ __forceinline__ void split_bf16(float a, unsigned &h, unsigned &l) {
    unsigned u = __float_as_uint(a);
    unsigned hu = u & 0xffff0000u;
    h = hu >> 16;
    float lf = a - __uint_as_float(hu);
    unsigned ul = __float_as_uint(lf);
    l = (ul + 0x7fffu + ((ul >> 16) & 1u)) >> 16;
}

__device__ __forceinline__ void split8_pack(const float* av, uint4& Hh, uint4& Ll) {
    unsigned hv[8], lv[8];
#pragma unroll
    for (int j = 0; j < 8; ++j) split_bf16(av[j], hv[j], lv[j]);
    Hh.x = hv[0] | (hv[1] << 16); Hh.y = hv[2] | (hv[3] << 16);
    Hh.z = hv[4] | (hv[5] << 16); Hh.w = hv[6] | (hv[7] << 16);
    Ll.x = lv[0] | (lv[1] << 16); Ll.y = lv[2] | (lv[3] << 16);
    Ll.z = lv[4] | (lv[5] << 16); Ll.w = lv[6] | (lv[7] << 16);
}

// ---------------------------------------------------------------------------
// fused weight pre-split (all 5 weights in one launch) — r9-verified
// ---------------------------------------------------------------------------
#define NWQ 589824
#define NWK 393216
#define NWD 196608
__global__ __launch_bounds__(256)
void split_all(const float* __restrict__ Wq, const float* __restrict__ W1,
               const float* __restrict__ Wk, const float* __restrict__ Wv,
               const float* __restrict__ Wd,
               short* __restrict__ Wq_h, short* __restrict__ Wq_l,
               short* __restrict__ W1_h, short* __restrict__ W1_l,
               short* __restrict__ Wk_h, short* __restrict__ Wk_l,
               short* __restrict__ Wv_h, short* __restrict__ Wv_l,
               short* __restrict__ Wd_h, short* __restrict__ Wd_l)
{
    int j = blockIdx.x * 256 + threadIdx.x;   // total 2,162,688 = 8448*256
    const float* src; short *hi, *lo;
    if (j < NWQ)                { src = Wq; hi = Wq_h; lo = Wq_l; }
    else if ((j -= NWQ) < NWQ)  { src = W1; hi = W1_h; lo = W1_l; }
    else if ((j -= NWQ) < NWK)  { src = Wk; hi = Wk_h; lo = Wk_l; }
    else if ((j -= NWK) < NWK)  { src = Wv; hi = Wv_h; lo = Wv_l; }
    else                        { j -= NWK;  src = Wd; hi = Wd_h; lo = Wd_l; }
    unsigned h, l;
    split_bf16(src[j], h, l);
    hi[j] = (short)h; lo[j] = (short)l;
}

// ---------------------------------------------------------------------------
// activation pre-splits (one pass, vectorized) — r11
// ---------------------------------------------------------------------------
__global__ __launch_bounds__(256)
void split_x(const float* __restrict__ x, short* __restrict__ Xh,
             short* __restrict__ Xl)
{
    int idx = blockIdx.x * 256 + threadIdx.x;    // 2,408,448 chunks of 8
    int m = idx / 96, c8 = (idx - m * 96) * 8;
    int b = m / Nv_, n = m - b * Nv_;
    const float* src = x + ((size_t)(n + 1) * B_ + b) * C_ + c8;
    float av[8];
    *(float4*)&av[0] = *(const float4*)src;
    *(float4*)&av[4] = *(const float4*)(src + 4);
    uint4 Hh, Ll;
    split8_pack(av, Hh, Ll);
    *(uint4*)&Xh[(size_t)m * C_ + c8] = Hh;
    *(uint4*)&Xl[(size_t)m * C_ + c8] = Ll;
}

__global__ __launch_bounds__(256)
void split_text(const float* __restrict__ t, short* __restrict__ Th,
                short* __restrict__ Tl)
{
    int idx = blockIdx.x * 256 + threadIdx.x;    // 262,144 chunks of 8
    const float* src = t + (size_t)idx * 8;
    float av[8];
    *(float4*)&av[0] = *(const float4*)src;
    *(float4*)&av[4] = *(const float4*)(src + 4);
    uint4 Hh, Ll;
    split8_pack(av, Hh, Ll);
    *(uint4*)&Th[(size_t)idx * 8] = Hh;
    *(uint4*)&Tl[(size_t)idx * 8] = Ll;
}

// ---------------------------------------------------------------------------
// 3-term split-bf16 MFMA GEMM via global_load_lds (r15-verified inner loop:
// linear LDS 32KB, both-sides XOR swizzle, zero bank conflicts).
// SELY=1: second (B,bias,C,Nst) set selected when by>=6 (merged q+phi).
// SELY=0: selected by blockIdx.z (kv pair).
// SWZ=1: XCD-aware bijective block remap (requires gridX*gridY % 8 == 0):
//   flat = by*NX+bx; g = (flat&7)*(total/8) + flat>>3; bx = g/NY; by = g%NY
//   -> each XCD's L2 sees a contiguous range of A row-panels (all col
//   panels). Pure permutation -> outputs bit-identical.
// ---------------------------------------------------------------------------
template<int EPI, int SELY, int SWZ>
__global__ __launch_bounds__(256)
void mfma_gemm(const short* __restrict__ Ah_g, const short* __restrict__ Al_g,
               const short* __restrict__ Bh1, const short* __restrict__ Bl1,
               const float* __restrict__ bias1, float* __restrict__ C1, int Nst1,
               const short* Bh2, const short* Bl2, const float* bias2,
               float* C2, int Nst2,
               int Kd, const float* __restrict__ W2, float* __restrict__ partials)
{
    int bx = blockIdx.x, by = blockIdx.y;
    if (SWZ) {
        const int NX = gridDim.x, NY = gridDim.y;
        const int total = NX * NY;
        int flat = by * NX + bx;
        int g = (flat & 7) * (total >> 3) + (flat >> 3);
        bx = g / NY; by = g % NY;
    }
    const bool sel = SELY ? (by >= 6) : (blockIdx.z != 0);
    const short* Bh_g = sel ? Bh2 : Bh1;
    const short* Bl_g = sel ? Bl2 : Bl1;
    const float* bias = sel ? bias2 : bias1;
    float* Cst        = sel ? C2 : C1;
    const int Nst     = sel ? Nst2 : Nst1;
    const int yy      = (SELY && sel) ? by - 6 : by;

    __shared__ short Ah[128 * 32], Al[128 * 32], Bh[128 * 32], Bl[128 * 32];
    const int tid = threadIdx.x;
    const int m0 = bx * 128, n0 = yy * 128;
    const int l = tid & 63, wid = tid >> 6;
    const int wr = wid >> 1, wc = wid & 1;
    const int lr = l & 15, lq = l >> 4;

    const int sr = wid * 32 + (l >> 2);
    const int sc = 8 * ((l & 3) ^ ((l >> 3) & 3));   // pre-swizzled chunk
    const short* a0  = Ah_g + (size_t)(m0 + sr) * Kd + sc;
    const short* a1  = Ah_g + (size_t)(m0 + sr + 16) * Kd + sc;
    const short* al0 = Al_g + (size_t)(m0 + sr) * Kd + sc;
    const short* al1 = Al_g + (size_t)(m0 + sr + 16) * Kd + sc;
    const short* b0  = Bh_g + (size_t)(n0 + sr) * Kd + sc;
    const short* b1  = Bh_g + (size_t)(n0 + sr + 16) * Kd + sc;
    const short* bl0 = Bl_g + (size_t)(n0 + sr) * Kd + sc;
    const short* bl1 = Bl_g + (size_t)(n0 + sr + 16) * Kd + sc;
    short* dA0  = &Ah[(wid * 32) * 32];
    short* dA1  = &Ah[(wid * 32 + 16) * 32];
    short* dAl0 = &Al[(wid * 32) * 32];
    short* dAl1 = &Al[(wid * 32 + 16) * 32];
    short* dB0  = &Bh[(wid * 32) * 32];
    short* dB1  = &Bh[(wid * 32 + 16) * 32];
    short* dBl0 = &Bl[(wid * 32) * 32];
    short* dBl1 = &Bl[(wid * 32 + 16) * 32];

    const int swzr = (lr >> 1) & 3;     // frag-read swizzle

    f32x4_t acc[4][4];
#pragma unroll
    for (int m = 0; m < 4; ++m)
#pragma unroll
        for (int n = 0; n < 4; ++n) {
            acc[m][n][0] = 0.f; acc[m][n][1] = 0.f;
            acc[m][n][2] = 0.f; acc[m][n][3] = 0.f;
        }

    for (int k0 = 0; k0 < Kd; k0 += 32) {
        gload_lds16(a0  + k0, dA0);
        gload_lds16(a1  + k0, dA1);
        gload_lds16(al0 + k0, dAl0);
        gload_lds16(al1 + k0, dAl1);
        gload_lds16(b0  + k0, dB0);
        gload_lds16(b1  + k0, dB1);
        gload_lds16(bl0 + k0, dBl0);
        gload_lds16(bl1 + k0, dBl1);
        __syncthreads();    // drains vmcnt before reads

        bf16x8_t ahf[4], alf[4], bhf[4], blf[4];
#pragma unroll
        for (int m = 0; m < 4; ++m) {
            int ro = (wr * 64 + m * 16 + lr) * 32 + ((lq ^ swzr) * 8);
            ahf[m] = *(const bf16x8_t*)&Ah[ro];
            alf[m] = *(const bf16x8_t*)&Al[ro];
        }
#pragma unroll
        for (int n = 0; n < 4; ++n) {
            int ro = (wc * 64 + n * 16 + lr) * 32 + ((lq ^ swzr) * 8);
            bhf[n] = *(const bf16x8_t*)&Bh[ro];
            blf[n] = *(const bf16x8_t*)&Bl[ro];
        }
#pragma unroll
        for (int m = 0; m < 4; ++m)
#pragma unroll
            for (int n = 0; n < 4; ++n) {
                acc[m][n] = __builtin_amdgcn_mfma_f32_16x16x32_bf16(ahf[m], bhf[n], acc[m][n], 0, 0, 0);
                acc[m][n] = __builtin_amdgcn_mfma_f32_16x16x32_bf16(ahf[m], blf[n], acc[m][n], 0, 0, 0);
                acc[m][n] = __builtin_amdgcn_mfma_f32_16x16x32_bf16(alf[m], bhf[n], acc[m][n], 0, 0, 0);
            }
        __syncthreads();
    }

    if constexpr (EPI == 0) {
#pragma unroll
        for (int n = 0; n < 4; ++n) {
            int col = n0 + wc * 64 + n * 16 + lr;
            float bv = bias ? bias[col] : 0.f;
#pragma unroll
            for (int m = 0; m < 4; ++m) {
                int rowb = m0 + wr * 64 + m * 16 + lq * 4;
#pragma unroll
                for (int r = 0; r < 4; ++r)
                    Cst[(size_t)(rowb + r) * Nst + col] = acc[m][n][r] + bv;
            }
        }
    } else {
        int coln[4]; float b1v[4], w20[4], w21[4];
#pragma unroll
        for (int n = 0; n < 4; ++n) {
            coln[n] = n0 + wc * 64 + n * 16 + lr;
            b1v[n] = bias[coln[n]];
            w20[n] = W2[coln[n]];
            w21[n] = W2[C_ + coln[n]];
        }
        const int pi = (yy * 2 + wc) * 2;
#pragma unroll
        for (int m = 0; m < 4; ++m)
#pragma unroll
            for (int r = 0; r < 4; ++r) {
                float p0 = 0.f, p1 = 0.f;
#pragma unroll
                for (int n = 0; n < 4; ++n) {
                    float h = acc[m][n][r] + b1v[n];
                    float gl = h / (1.f + expf(-1.702f * h));
                    p0 = fmaf(gl, w20[n], p0);
                    p1 = fmaf(gl, w21[n], p1);
                }
#pragma unroll
                for (int off = 8; off; off >>= 1) {
                    p0 += __shfl_xor(p0, off, 16);
                    p1 += __shfl_xor(p1, off, 16);
                }
                if (lr == 0) {
                    int row = m0 + wr * 64 + m * 16 + lq * 4 + r;
                    partials[(size_t)row * 24 + pi + 0] = p0;
                    partials[(size_t)row * 24 + pi + 1] = p1;
                }
            }
    }
}

// ---------------------------------------------------------------------------
// gram: M = phi@phi^T * scale + 1e-5*I, stride MLD_, zero pad (r14-verified)
// ---------------------------------------------------------------------------
__global__ __launch_bounds__(256)
void gram_kernel(const float* __restrict__ A, float* __restrict__ Mout,
                 float scale)
{
    __shared__ float As[16][132];
    __shared__ float Bs[16][132];
    const int tid = threadIdx.x;
    const int tx = tid & 15, ty = tid >> 4;
    const int m0 = blockIdx.x * 128, n0 = blockIdx.y * 128;
    const int bz = blockIdx.z;
    const float* Ab = A + (size_t)bz * Nv_ * DPP_;
    float* Mb = Mout + (size_t)bz * Nv_ * MLD_;

    const int lrow = tid >> 2;
    const int lk   = (tid & 3) << 2;

    const float* aptr[2]; const float* bptr[2];
    bool aval[2], bval[2];
#pragma unroll
    for (int Lq = 0; Lq < 2; ++Lq) {
        int row = lrow + Lq * 64;
        int gr = m0 + row;
        aval[Lq] = (gr < Nv_);
        aptr[Lq] = Ab + (size_t)(aval[Lq] ? gr : 0) * DPP_ + lk;
        int gc = n0 + row;
        bval[Lq] = (gc < Nv_);
        bptr[Lq] = Ab + (size_t)(bval[Lq] ? gc : 0) * DPP_ + lk;
    }

    float acc[8][8];
#pragma unroll
    for (int r = 0; r < 8; ++r)
#pragma unroll
        for (int c = 0; c < 8; ++c) acc[r][c] = 0.f;

    for (int k0 = 0; k0 < DPP_; k0 += 16) {
#pragma unroll
        for (int Lq = 0; Lq < 2; ++Lq) {
            int row = lrow + Lq * 64;
            float4 va = aval[Lq] ? *(const float4*)(aptr[Lq] + k0)
                                 : make_float4(0.f, 0.f, 0.f, 0.f);
            As[lk+0][row] = va.x; As[lk+1][row] = va.y;
            As[lk+2][row] = va.z; As[lk+3][row] = va.w;
            float4 vb = bval[Lq] ? *(const float4*)(bptr[Lq] + k0)
                                 : make_float4(0.f, 0.f, 0.f, 0.f);
            Bs[lk+0][row] = vb.x; Bs[lk+1][row] = vb.y;
            Bs[lk+2][row] = vb.z; Bs[lk+3][row] = vb.w;
        }
        __syncthreads();
#pragma unroll
        for (int kk = 0; kk < 16; ++kk) {
            float a[8], bfr[8];
            *(float4*)&a[0]   = *(const float4*)&As[kk][ty * 8];
            *(float4*)&a[4]   = *(const float4*)&As[kk][ty * 8 + 4];
            *(float4*)&bfr[0] = *(const float4*)&Bs[kk][tx * 4];
            *(float4*)&bfr[4] = *(const float4*)&Bs[kk][64 + tx * 4];
#pragma unroll
            for (int r = 0; r < 8; ++r)
#pragma unroll
                for (int c = 0; c < 8; ++c)
                    acc[r][c] = fmaf(a[r], bfr[c], acc[r][c]);
        }
        __syncthreads();
    }

#pragma unroll
    for (int r = 0; r < 8; ++r) {
        int gr = m0 + ty * 8 + r;
        if (gr >= Nv_) continue;
#pragma unroll
        for (int half = 0; half < 2; ++half) {
            int gc0 = n0 + half * 64 + tx * 4;
#pragma unroll
            for (int c = 0; c < 4; ++c) {
                int gc = gc0 + c;
                if (gc < Nv_) {
                    float v = acc[r][half*4+c] * scale;
                    if (gr == gc) v += 1e-5f;   // M = G + eps*I
                    Mb[(size_t)gr * MLD_ + gc] = v;
                } else if (gc < MLD_) {
                    Mb[(size_t)gr * MLD_ + gc] = 0.f;   // zero pad
                }
            }
        }
    }
}

// ---------------------------------------------------------------------------
// taylor_gemm: M2 tile + partial traces (r14-verified).
// logdet = tr(M) - tr(M^2)/2 + tr(M^3)/3 - tr(M^4)/4, err ~2e-8.
// ---------------------------------------------------------------------------
__global__ __launch_bounds__(256)
void taylor_gemm(const float* __restrict__ Mg, float* __restrict__ tpart)
{
    __shared__ float As[16][132];
    __shared__ float Bs[16][132];
    __shared__ float wred[4][4];
    const int tid = threadIdx.x;
    const int tx = tid & 15, ty = tid >> 4;
    const int m0 = blockIdx.x * 128, n0 = blockIdx.y * 128;
    const int bz = blockIdx.z;
    const float* Mb = Mg + (size_t)bz * Nv_ * MLD_;

    const int lrow = tid >> 2;
    const int lk   = (tid & 3) << 2;

    const float* aptr[2]; const float* bptr[2];
    bool aval[2], bval[2];
#pragma unroll
    for (int Lq = 0; Lq < 2; ++Lq) {
        int row = lrow + Lq * 64;
        int gr = m0 + row;
        aval[Lq] = (gr < Nv_);
        aptr[Lq] = Mb + (size_t)(aval[Lq] ? gr : 0) * MLD_ + lk;
        int gc = n0 + row;
        bval[Lq] = (gc < Nv_);
        bptr[Lq] = Mb + (size_t)(bval[Lq] ? gc : 0) * MLD_ + lk;
    }

    float acc[8][8];
#pragma unroll
    for (int r = 0; r < 8; ++r)
#pragma unroll
        for (int c = 0; c < 8; ++c) acc[r][c] = 0.f;

    for (int k0 = 0; k0 < MLD_; k0 += 16) {   // 13 tiles; pad cols are zero
#pragma unroll
        for (int Lq = 0; Lq < 2; ++Lq) {
            int row = lrow + Lq * 64;
            float4 va = aval[Lq] ? *(const float4*)(aptr[Lq] + k0)
                                 : make_float4(0.f, 0.f, 0.f, 0.f);
            As[lk+0][row] = va.x; As[lk+1][row] = va.y;
            As[lk+2][row] = va.z; As[lk+3][row] = va.w;
            float4 vb = bval[Lq] ? *(const float4*)(bptr[Lq] + k0)
                                 : make_float4(0.f, 0.f, 0.f, 0.f);
            Bs[lk+0][row] = vb.x; Bs[lk+1][row] = vb.y;
            Bs[lk+2][row] = vb.z; Bs[lk+3][row] = vb.w;
        }
        __syncthreads();
#pragma unroll
        for (int kk = 0; kk < 16; ++kk) {
            float a[8], bfr[8];
            *(float4*)&a[0]   = *(const float4*)&As[kk][ty * 8];
            *(float4*)&a[4]   = *(const float4*)&As[kk][ty * 8 + 4];
            *(float4*)&bfr[0] = *(const float4*)&Bs[kk][tx * 4];
            *(float4*)&bfr[4] = *(const float4*)&Bs[kk][64 + tx * 4];
#pragma unroll
            for (int r = 0; r < 8; ++r)
#pragma unroll
                for (int c = 0; c < 8; ++c)
                    acc[r][c] = fmaf(a[r], bfr[c], acc[r][c]);
        }
        __syncthreads();
    }

    float t1 = 0.f, t2 = 0.f, t3 = 0.f, t4 = 0.f;
#pragma unroll
    for (int r = 0; r < 8; ++r) {
        int gr = m0 + ty * 8 + r;
        if (gr >= Nv_) continue;
#pragma unroll
        for (int half = 0; half < 2; ++half) {
            int gc0 = n0 + half * 64 + tx * 4;
#pragma unroll
            for (int c = 0; c < 4; ++c) {
                int gc = gc0 + c;
                if (gc < Nv_) {
                    float mij = Mb[(size_t)gr * MLD_ + gc];
                    float m2  = acc[r][half*4+c];
                    if (gr == gc) t1 += mij;
                    t2 = fmaf(mij, mij, t2);
                    t3 = fmaf(m2, mij, t3);
                    t4 = fmaf(m2, m2, t4);
                }
            }
        }
    }
#pragma unroll
    for (int off = 32; off; off >>= 1) {
        t1 += __shfl_xor(t1, off, 64);
        t2 += __shfl_xor(t2, off, 64);
        t3 += __shfl_xor(t3, off, 64);
        t4 += __shfl_xor(t4, off, 64);
    }
    const int wv = tid >> 6;
    if ((tid & 63) == 0) {
        wred[wv][0] = t1; wred[wv][1] = t2; wred[wv][2] = t3; wred[wv][3] = t4;
    }
    __syncthreads();
    if (tid == 0) {
        const int blk = blockIdx.y * 2 + blockIdx.x;
        float* dst = tpart + ((size_t)bz * 4 + blk) * 4;
        dst[0] = wred[0][0] + wred[1][0] + wred[2][0] + wred[3][0];
        dst[1] = wred[0][1] + wred[1][1] + wred[2][1] + wred[3][1];
        dst[2] = wred[0][2] + wred[1][2] + wred[2][2] + wred[3][2];
        dst[3] = wred[0][3] + wred[1][3] + wred[2][3] + wred[3][3];
    }
}

// ---------------------------------------------------------------------------
// Attention per (b,h) — r10/r11-verified (4 rows/wave, all-lane score,
// prefetch; output pre-split to Fh/Fl).
// ---------------------------------------------------------------------------
__global__ __launch_bounds__(256)
void attn_kernel(const float* __restrict__ q, const float* __restrict__ k,
                 const float* __restrict__ v, const float* __restrict__ x,
                 short* __restrict__ Fh, short* __restrict__ Fl)
{
    __shared__ float Ks[Lt_][DH_ + 4];
    __shared__ float Vs[Lt_][DH_ + 1];
    __shared__ float qs[16][DH_];
    __shared__ float as[16][Lt_];
    const int bh = blockIdx.x;
    const int b = bh / H_, h = bh - b * H_;
    const int tid = threadIdx.x;
    const int wv = tid >> 6, lane = tid & 63;
    const int half = lane >> 5;
    const int key = lane & 31;

    for (int idx = tid; idx < Lt_ * 16; idx += 256) {
        int l = idx >> 4, dq = (idx & 15) << 2;
        size_t off = ((size_t)(b * Lt_ + l)) * C_ + h * DH_ + dq;
        float4 kv4 = *(const float4*)(k + off);
        Ks[l][dq] = kv4.x; Ks[l][dq + 1] = kv4.y; Ks[l][dq + 2] = kv4.z; Ks[l][dq + 3] = kv4.w;
        float4 vv4 = *(const float4*)(v + off);
        Vs[l][dq] = vv4.x; Vs[l][dq + 1] = vv4.y; Vs[l][dq + 2] = vv4.z; Vs[l][dq + 3] = vv4.w;
    }
    __syncthreads();

    const size_t qbase = (size_t)b * Nv_ * C_ + h * DH_ + lane;
    const size_t xbase = (size_t)b * C_ + h * DH_ + lane;

    float qv[4], xv[4];
#pragma unroll
    for (int j = 0; j < 4; ++j) {
        qv[j] = q[qbase + (size_t)(wv * 4 + j) * C_];
        xv[j] = x[xbase + (size_t)(wv * 4 + j + 1) * B_ * C_];
    }

    for (int it = 0; it < 13; ++it) {
        const int base = it * 16 + wv * 4;
        if (base > 192) break;
        float cq[4], cx[4];
#pragma unroll
        for (int j = 0; j < 4; ++j) { cq[j] = qv[j]; cx[j] = xv[j]; }
        const int nbase = base + 16;
        if (nbase <= 192) {
#pragma unroll
            for (int j = 0; j < 4; ++j) {
                qv[j] = q[qbase + (size_t)(nbase + j) * C_];
                xv[j] = x[xbase + (size_t)(nbase + j + 1) * B_ * C_];
            }
        }
        const int ws = wv * 4;
#pragma unroll
        for (int j = 0; j < 4; ++j) qs[ws + j][lane] = cq[j];

        const int s0 = ws + half * 2;
        float s1 = 0.f, s2 = 0.f;
#pragma unroll
        for (int d4 = 0; d4 < DH_; d4 += 4) {
            float4 k4  = *(const float4*)&Ks[key][d4];
            float4 q4a = *(const float4*)&qs[s0][d4];
            float4 q4b = *(const float4*)&qs[s0 + 1][d4];
            s1 = fmaf(q4a.x, k4.x, s1); s2 = fmaf(q4b.x, k4.x, s2);
            s1 = fmaf(q4a.y, k4.y, s1); s2 = fmaf(q4b.y, k4.y, s2);
            s1 = fmaf(q4a.z, k4.z, s1); s2 = fmaf(q4b.z, k4.z, s2);
            s1 = fmaf(q4a.w, k4.w, s1); s2 = fmaf(q4b.w, k4.w, s2);
        }
        s1 *= 0.125f; s2 *= 0.125f;
        float mx1 = s1, mx2 = s2;
#pragma unroll
        for (int off = 16; off; off >>= 1) {
            mx1 = fmaxf(mx1, __shfl_xor(mx1, off, 32));
            mx2 = fmaxf(mx2, __shfl_xor(mx2, off, 32));
        }
        float p1v = expf(s1 - mx1);
        float p2v = expf(s2 - mx2);
        float su1 = p1v, su2 = p2v;
#pragma unroll
        for (int off = 16; off; off >>= 1) {
            su1 += __shfl_xor(su1, off, 32);
            su2 += __shfl_xor(su2, off, 32);
        }
        as[s0][key] = p1v / su1;
        as[s0 + 1][key] = p2v / su2;

        float c0 = 0.f, c1 = 0.f, c2 = 0.f, c3 = 0.f;
#pragma unroll
        for (int l4 = 0; l4 < Lt_; l4 += 4) {
            float4 a0 = *(const float4*)&as[ws + 0][l4];
            float4 a1 = *(const float4*)&as[ws + 1][l4];
            float4 a2 = *(const float4*)&as[ws + 2][l4];
            float4 a3 = *(const float4*)&as[ws + 3][l4];
            float v0 = Vs[l4 + 0][lane], v1 = Vs[l4 + 1][lane];
            float v2 = Vs[l4 + 2][lane], v3 = Vs[l4 + 3][lane];
            c0 = fmaf(a0.x, v0, c0); c1 = fmaf(a1.x, v0, c1);
            c2 = fmaf(a2.x, v0, c2); c3 = fmaf(a3.x, v0, c3);
            c0 = fmaf(a0.y, v1, c0); c1 = fmaf(a1.y, v1, c1);
            c2 = fmaf(a2.y, v1, c2); c3 = fmaf(a3.y, v1, c3);
            c0 = fmaf(a0.z, v2, c0); c1 = fmaf(a1.z, v2, c1);
            c2 = fmaf(a2.z, v2, c2); c3 = fmaf(a3.z, v2, c3);
            c0 = fmaf(a0.w, v3, c0); c1 = fmaf(a1.w, v3, c1);
            c2 = fmaf(a2.w, v3, c2); c3 = fmaf(a3.w, v3, c3);
        }
        float fo[4] = {c0 + cx[0], c1 + cx[1], c2 + cx[2], c3 + cx[3]};
#pragma unroll
        for (int j = 0; j < 4; ++j) {
            unsigned hh, ll;
            split_bf16(fo[j], hh, ll);
            Fh[qbase + (size_t)(base + j) * C_] = (short)hh;
            Fl[qbase + (size_t)(base + j) * C_] = (short)ll;
        }
    }
}

// ---------------------------------------------------------------------------
// keep decisions: logits from partials[m][24] (+b2), gumbel, policy, keep_prob
// ---------------------------------------------------------------------------
__global__ __launch_bounds__(256)
void keep_kernel(const float* __restrict__ partials, const float* __restrict__ b2,
                 const float* __restrict__ gumbel, float* __restrict__ policy,
                 float* __restrict__ keep_prob)
{
    int m = blockIdx.x * 256 + threadIdx.x;
    int b = m / Nv_, n = m - b * Nv_;
    float l0 = b2[0], l1 = b2[1];
#pragma unroll
    for (int t = 0; t < 12; ++t) {
        l0 += partials[(size_t)m * 24 + t * 2 + 0];
        l1 += partials[(size_t)m * 24 + t * 2 + 1];
    }
    const float UHI = (float)(1.0 - 1e-6);
    float U0 = fminf(fmaxf(gumbel[(size_t)m * 2 + 0], 1e-6f), UHI);
    float U1 = fminf(fmaxf(gumbel[(size_t)m * 2 + 1], 1e-6f), UHI);
    float t0 = (float)log((double)U0);
    float g0 = -(float)log((double)(-t0));
    float t1 = (float)log((double)U1);
    float g1 = -(float)log((double)(-t1));
    float dlog = (l1 + g1) - (l0 + g0);
    float kp = 1.f / (1.f + expf(-dlog));
    policy[(size_t)b * 197 + 1 + n] = (dlog > 0.f) ? 1.f : 0.f;
    if (n == 0) policy[(size_t)b * 197] = 1.f;
    keep_prob[m] = kp;
}

__global__ __launch_bounds__(256)
void batch_reduce(const float* __restrict__ keep_prob, float* __restrict__ sum_kp)
{
    __shared__ float part[4];
    int b = blockIdx.x, tid = threadIdx.x;
    float vs = (tid < Nv_) ? keep_prob[(size_t)b * Nv_ + tid] : 0.f;
#pragma unroll
    for (int off = 32; off; off >>= 1) vs += __shfl_xor(vs, off, 64);
    if ((tid & 63) == 0) part[tid >> 6] = vs;
    __syncthreads();
    if (tid == 0) sum_kp[b] = part[0] + part[1] + part[2] + part[3];
}

__global__ __launch_bounds__(256)
void pw_scale(float* __restrict__ phi, const float* __restrict__ keep_prob,
              const float* __restrict__ sum_kp)
{
    int m = blockIdx.x * 4 + (threadIdx.x >> 6);
    int lane = threadIdx.x & 63;
    float4* row = (float4*)phi + (size_t)m * 64;
    float4 vv = row[lane];
    float ss = vv.x * vv.x + vv.y * vv.y + vv.z * vv.z + vv.w * vv.w;
#pragma unroll
    for (int off = 32; off; off >>= 1) ss += __shfl_xor(ss, off, 64);
    float nrm = fmaxf(sqrtf(ss), 1e-12f);
    int b = m / Nv_;
    float kp = keep_prob[m];
    float meanw = sum_kp[b] * (1.f / 196.f);
    float wn = fmaxf(kp / (meanw + 1e-12f), 1e-6f);
    float sc = sqrtf(wn) / nrm;
    vv.x *= sc; vv.y *= sc; vv.z *= sc; vv.w *= sc;
    row[lane] = vv;
}

// deterministic serial finalize: loss_ratio + Taylor logdet combine
__global__ void finalize_kernel(const float* __restrict__ sum_kp,
                                const float* __restrict__ tpart,
                                float* __restrict__ out)
{
    float tot = 0.f, ld = 0.f;
    for (int b = 0; b < B_; ++b) {
        tot += sum_kp[b];
        float s1 = 0.f, s2 = 0.f, s3 = 0.f, s4 = 0.f;
        for (int blk = 0; blk < 4; ++blk) {
            const float* p = tpart + ((size_t)b * 4 + blk) * 4;
            s1 += p[0]; s2 += p[1]; s3 += p[2]; s4 += p[3];
        }
        ld += s1 - 0.5f * s2 + (1.f / 3.f) * s3 - 0.25f * s4;
    }
    float mean = tot * (1.f / 25088.f);
    float d = mean - 0.7f;
    out[25216] = d * d;
    out[25217] = -ld * (1.f / 128.f);
}

// ---------------------------------------------------------------------------
extern "C" void kernel_launch(void* const* d_in, const int* in_sizes, int n_in,
                              void* d_out, int out_size, void* d_ws, size_t ws_size,
                              hipStream_t stream)
{
    const float* x      = (const float*)d_in[0];
    const float* text   = (const float*)d_in[1];
    const float* gumbel = (const float*)d_in[2];
    const float* Wq     = (const float*)d_in[3];
    const float* bq     = (const float*)d_in[4];
    const float* Wk     = (const float*)d_in[5];
    const float* bk     = (const float*)d_in[6];
    const float* Wv     = (const float*)d_in[7];
    const float* bv     = (const float*)d_in[8];
    const float* W1     = (const float*)d_in[9];
    const float* b1     = (const float*)d_in[10];
    const float* W2     = (const float*)d_in[11];
    const float* b2     = (const float*)d_in[12];
    const float* Wdpp   = (const float*)d_in[13];
    float* out = (float*)d_out;

    float* ws = (float*)d_ws;
    float* q          = ws;                       // 19,267,584 f ; M overlays
    float* kbuf       = q + 19267584;
    float* vbuf       = kbuf + 3145728;
    float* phi        = vbuf + 3145728;
    float* partials   = phi + 6422528;            // 602,112 f; tpart overlays
    float* keep_prob  = partials + 602112;
    float* sum_kp     = keep_prob + 25088;
    float* logdet_arr = sum_kp + 128;             // (unused, kept for layout)
    float* M          = ws;                       // 128*196*208 floats
    float* tpart      = partials;                 // 2048 f (dead after keep)

    short* Wq_h = (short*)(logdet_arr + 128);
    short* Wq_l = Wq_h + 589824;
    short* W1_h = Wq_l + 589824;
    short* W1_l = W1_h + 589824;
    short* Wk_h = W1_l + 589824;
    short* Wk_l = Wk_h + 393216;
    short* Wv_h = Wk_l + 393216;
    short* Wv_l = Wv_h + 393216;
    short* Wd_h = Wv_l + 393216;
    short* Wd_l = Wd_h + 196608;
    short* Xh = Wd_l + 196608;                    // 19,267,584 shorts each
    short* Xl = Xh + 19267584;
    short* Th = Xl + 19267584;                    //  2,097,152 shorts each
    short* Tl = Th + 2097152;
    short* Fh = Xh;                               // overlay: X dead after q+phi
    short* Fl = Xl;

    dim3 blk(256);

    split_all<<<dim3(8448), blk, 0, stream>>>(Wq, W1, Wk, Wv, Wdpp,
                                              Wq_h, Wq_l, W1_h, W1_l,
                                              Wk_h, Wk_l, Wv_h, Wv_l,
                                              Wd_h, Wd_l);
    split_x<<<dim3(9408), blk, 0, stream>>>(x, Xh, Xl);
    split_text<<<dim3(1024), blk, 0, stream>>>(text, Th, Tl);

    // k+v projections merged by z (no swizzle: A is L2-resident, 384 blocks)
    mfma_gemm<0,0,0><<<dim3(32,6,2), blk, 0, stream>>>(
        Th, Tl, Wk_h, Wk_l, bk, kbuf, 768,
        Wv_h, Wv_l, bv, vbuf, 768, 512, nullptr, nullptr);
    // q + phi merged by y (y<6 -> q, y>=6 -> phi), XCD swizzle (1568 % 8 == 0)
    mfma_gemm<0,1,1><<<dim3(196,8,1), blk, 0, stream>>>(
        Xh, Xl, Wq_h, Wq_l, bq, q, 768,
        Wd_h, Wd_l, nullptr, phi, 256, 768, nullptr, nullptr);
    attn_kernel<<<dim3(B_*H_), blk, 0, stream>>>(q, kbuf, vbuf, x, Fh, Fl);
    // MLP with gelu/W2 epilogue, XCD swizzle (1176 % 8 == 0)
    mfma_gemm<1,0,1><<<dim3(196,6,1), blk, 0, stream>>>(
        Fh, Fl, W1_h, W1_l, b1, nullptr, 768,
        W1_h, W1_l, b1, nullptr, 768, 768, W2, partials);
    keep_kernel<<<dim3(98), blk, 0, stream>>>(partials, b2, gumbel, out, keep_prob);
    batch_reduce<<<dim3(B_), blk, 0, stream>>>(keep_prob, sum_kp);
    pw_scale<<<dim3(6272), blk, 0, stream>>>(phi, keep_prob, sum_kp);
    gram_kernel<<<dim3(2,2,B_), blk, 0, stream>>>(phi, M,
                                                  1.0f/(256.0f*196.0f*0.01f));
    taylor_gemm<<<dim3(2,2,B_), blk, 0, stream>>>(M, tpart);
    finalize_kernel<<<dim3(1), dim3(1), 0, stream>>>(sum_kp, tpart, out);
}

// Round 17
// 514.040 us; speedup vs baseline: 1.3944x; 1.1040x over previous
//
#include <hip/hip_runtime.h>
#include <math.h>

#define B_   128
#define L_   197
#define C_   768
#define Nv_  196
#define Lt_  32
#define Ct_  512
#define H_   12
#define DH_  64
#define DPP_ 256
#define MTOK 25088   // B_*Nv_
#define MS_  224     // padded M size (196 -> 224, rows and cols, zero pad)

typedef __attribute__((ext_vector_type(8))) short bf16x8_t;
typedef __attribute__((ext_vector_type(4))) float f32x4_t;

// async global->LDS, 16B per lane; dest = wave-uniform base + lane*16
__device__ __forceinline__ void gload_lds16(const short* g, short* l) {
    __builtin_amdgcn_global_load_lds(
        (const __attribute__((address_space(1))) unsigned int*)g,
        (__attribute__((address_space(3))) unsigned int*)l,
        16, 0, 0);
}

// split fp32 -> bf16 hi (truncate) + bf16 lo (RNE of remainder)
__device__ __forceinline__ void split_bf16(float a, unsigned &h, unsigned &l) {
    unsigned u = __float_as_uint(a);
    unsigned hu = u & 0xffff0000u;
    h = hu >> 16;
    float lf = a - __uint_as_float(hu);
    unsigned ul = __float_as_uint(lf);
    l = (ul + 0x7fffu + ((ul >> 16) & 1u)) >> 16;
}

__device__ __forceinline__ float bf16_to_f(short s) {
    return __uint_as_float(((unsigned)(unsigned short)s) << 16);
}

__device__ __forceinline__ void split8_pack(const float* av, uint4& Hh, uint4& Ll) {
    unsigned hv[8], lv[8];
#pragma unroll
    for (int j = 0; j < 8; ++j) split_bf16(av[j], hv[j], lv[j]);
    Hh.x = hv[0] | (hv[1] << 16); Hh.y = hv[2] | (hv[3] << 16);
    Hh.z = hv[4] | (hv[5] << 16); Hh.w = hv[6] | (hv[7] << 16);
    Ll.x = lv[0] | (lv[1] << 16); Ll.y = lv[2] | (lv[3] << 16);
    Ll.z = lv[4] | (lv[5] << 16); Ll.w = lv[6] | (lv[7] << 16);
}

// ---------------------------------------------------------------------------
// fused weight pre-split — r9-verified
// ---------------------------------------------------------------------------
#define NWQ 589824
#define NWK 393216
#define NWD 196608
__global__ __launch_bounds__(256)
void split_all(const float* __restrict__ Wq, const float* __restrict__ W1,
               const float* __restrict__ Wk, const float* __restrict__ Wv,
               const float* __restrict__ Wd,
               short* __restrict__ Wq_h, short* __restrict__ Wq_l,
               short* __restrict__ W1_h, short* __restrict__ W1_l,
               short* __restrict__ Wk_h, short* __restrict__ Wk_l,
               short* __restrict__ Wv_h, short* __restrict__ Wv_l,
               short* __restrict__ Wd_h, short* __restrict__ Wd_l)
{
    int j = blockIdx.x * 256 + threadIdx.x;   // total 2,162,688 = 8448*256
    const float* src; short *hi, *lo;
    if (j < NWQ)                { src = Wq; hi = Wq_h; lo = Wq_l; }
    else if ((j -= NWQ) < NWQ)  { src = W1; hi = W1_h; lo = W1_l; }
    else if ((j -= NWQ) < NWK)  { src = Wk; hi = Wk_h; lo = Wk_l; }
    else if ((j -= NWK) < NWK)  { src = Wv; hi = Wv_h; lo = Wv_l; }
    else                        { j -= NWK;  src = Wd; hi = Wd_h; lo = Wd_l; }
    unsigned h, l;
    split_bf16(src[j], h, l);
    hi[j] = (short)h; lo[j] = (short)l;
}

// ---------------------------------------------------------------------------
// activation pre-splits — r11-verified
// ---------------------------------------------------------------------------
__global__ __launch_bounds__(256)
void split_x(const float* __restrict__ x, short* __restrict__ Xh,
             short* __restrict__ Xl)
{
    int idx = blockIdx.x * 256 + threadIdx.x;    // 2,408,448 chunks of 8
    int m = idx / 96, c8 = (idx - m * 96) * 8;
    int b = m / Nv_, n = m - b * Nv_;
    const float* src = x + ((size_t)(n + 1) * B_ + b) * C_ + c8;
    float av[8];
    *(float4*)&av[0] = *(const float4*)src;
    *(float4*)&av[4] = *(const float4*)(src + 4);
    uint4 Hh, Ll;
    split8_pack(av, Hh, Ll);
    *(uint4*)&Xh[(size_t)m * C_ + c8] = Hh;
    *(uint4*)&Xl[(size_t)m * C_ + c8] = Ll;
}

__global__ __launch_bounds__(256)
void split_text(const float* __restrict__ t, short* __restrict__ Th,
                short* __restrict__ Tl)
{
    int idx = blockIdx.x * 256 + threadIdx.x;    // 262,144 chunks of 8
    const float* src = t + (size_t)idx * 8;
    float av[8];
    *(float4*)&av[0] = *(const float4*)src;
    *(float4*)&av[4] = *(const float4*)(src + 4);
    uint4 Hh, Ll;
    split8_pack(av, Hh, Ll);
    *(uint4*)&Th[(size_t)idx * 8] = Hh;
    *(uint4*)&Tl[(size_t)idx * 8] = Ll;
}

// ---------------------------------------------------------------------------
// 3-term split-bf16 MFMA GEMM (r15/r16-verified): gld_lds, linear 32KB LDS,
// both-sides XOR swizzle (0 conflicts), SELY/SWZ variants.
// ---------------------------------------------------------------------------
template<int EPI, int SELY, int SWZ>
__global__ __launch_bounds__(256)
void mfma_gemm(const short* __restrict__ Ah_g, const short* __restrict__ Al_g,
               const short* __restrict__ Bh1, const short* __restrict__ Bl1,
               const float* __restrict__ bias1, float* __restrict__ C1, int Nst1,
               const short* Bh2, const short* Bl2, const float* bias2,
               float* C2, int Nst2,
               int Kd, const float* __restrict__ W2, float* __restrict__ partials)
{
    int bx = blockIdx.x, by = blockIdx.y;
    if (SWZ) {
        const int NX = gridDim.x, NY = gridDim.y;
        const int total = NX * NY;
        int flat = by * NX + bx;
        int g = (flat & 7) * (total >> 3) + (flat >> 3);
        bx = g / NY; by = g % NY;
    }
    const bool sel = SELY ? (by >= 6) : (blockIdx.z != 0);
    const short* Bh_g = sel ? Bh2 : Bh1;
    const short* Bl_g = sel ? Bl2 : Bl1;
    const float* bias = sel ? bias2 : bias1;
    float* Cst        = sel ? C2 : C1;
    const int Nst     = sel ? Nst2 : Nst1;
    const int yy      = (SELY && sel) ? by - 6 : by;

    __shared__ short Ah[128 * 32], Al[128 * 32], Bh[128 * 32], Bl[128 * 32];
    const int tid = threadIdx.x;
    const int m0 = bx * 128, n0 = yy * 128;
    const int l = tid & 63, wid = tid >> 6;
    const int wr = wid >> 1, wc = wid & 1;
    const int lr = l & 15, lq = l >> 4;

    const int sr = wid * 32 + (l >> 2);
    const int sc = 8 * ((l & 3) ^ ((l >> 3) & 3));   // pre-swizzled chunk
    const short* a0  = Ah_g + (size_t)(m0 + sr) * Kd + sc;
    const short* a1  = Ah_g + (size_t)(m0 + sr + 16) * Kd + sc;
    const short* al0 = Al_g + (size_t)(m0 + sr) * Kd + sc;
    const short* al1 = Al_g + (size_t)(m0 + sr + 16) * Kd + sc;
    const short* b0  = Bh_g + (size_t)(n0 + sr) * Kd + sc;
    const short* b1  = Bh_g + (size_t)(n0 + sr + 16) * Kd + sc;
    const short* bl0 = Bl_g + (size_t)(n0 + sr) * Kd + sc;
    const short* bl1 = Bl_g + (size_t)(n0 + sr + 16) * Kd + sc;
    short* dA0  = &Ah[(wid * 32) * 32];
    short* dA1  = &Ah[(wid * 32 + 16) * 32];
    short* dAl0 = &Al[(wid * 32) * 32];
    short* dAl1 = &Al[(wid * 32 + 16) * 32];
    short* dB0  = &Bh[(wid * 32) * 32];
    short* dB1  = &Bh[(wid * 32 + 16) * 32];
    short* dBl0 = &Bl[(wid * 32) * 32];
    short* dBl1 = &Bl[(wid * 32 + 16) * 32];

    const int swzr = (lr >> 1) & 3;     // frag-read swizzle

    f32x4_t acc[4][4];
#pragma unroll
    for (int m = 0; m < 4; ++m)
#pragma unroll
        for (int n = 0; n < 4; ++n) {
            acc[m][n][0] = 0.f; acc[m][n][1] = 0.f;
            acc[m][n][2] = 0.f; acc[m][n][3] = 0.f;
        }

    for (int k0 = 0; k0 < Kd; k0 += 32) {
        gload_lds16(a0  + k0, dA0);
        gload_lds16(a1  + k0, dA1);
        gload_lds16(al0 + k0, dAl0);
        gload_lds16(al1 + k0, dAl1);
        gload_lds16(b0  + k0, dB0);
        gload_lds16(b1  + k0, dB1);
        gload_lds16(bl0 + k0, dBl0);
        gload_lds16(bl1 + k0, dBl1);
        __syncthreads();

        bf16x8_t ahf[4], alf[4], bhf[4], blf[4];
#pragma unroll
        for (int m = 0; m < 4; ++m) {
            int ro = (wr * 64 + m * 16 + lr) * 32 + ((lq ^ swzr) * 8);
            ahf[m] = *(const bf16x8_t*)&Ah[ro];
            alf[m] = *(const bf16x8_t*)&Al[ro];
        }
#pragma unroll
        for (int n = 0; n < 4; ++n) {
            int ro = (wc * 64 + n * 16 + lr) * 32 + ((lq ^ swzr) * 8);
            bhf[n] = *(const bf16x8_t*)&Bh[ro];
            blf[n] = *(const bf16x8_t*)&Bl[ro];
        }
#pragma unroll
        for (int m = 0; m < 4; ++m)
#pragma unroll
            for (int n = 0; n < 4; ++n) {
                acc[m][n] = __builtin_amdgcn_mfma_f32_16x16x32_bf16(ahf[m], bhf[n], acc[m][n], 0, 0, 0);
                acc[m][n] = __builtin_amdgcn_mfma_f32_16x16x32_bf16(ahf[m], blf[n], acc[m][n], 0, 0, 0);
                acc[m][n] = __builtin_amdgcn_mfma_f32_16x16x32_bf16(alf[m], bhf[n], acc[m][n], 0, 0, 0);
            }
        __syncthreads();
    }

    if constexpr (EPI == 0) {
#pragma unroll
        for (int n = 0; n < 4; ++n) {
            int col = n0 + wc * 64 + n * 16 + lr;
            float bv = bias ? bias[col] : 0.f;
#pragma unroll
            for (int m = 0; m < 4; ++m) {
                int rowb = m0 + wr * 64 + m * 16 + lq * 4;
#pragma unroll
                for (int r = 0; r < 4; ++r)
                    Cst[(size_t)(rowb + r) * Nst + col] = acc[m][n][r] + bv;
            }
        }
    } else {
        int coln[4]; float b1v[4], w20[4], w21[4];
#pragma unroll
        for (int n = 0; n < 4; ++n) {
            coln[n] = n0 + wc * 64 + n * 16 + lr;
            b1v[n] = bias[coln[n]];
            w20[n] = W2[coln[n]];
            w21[n] = W2[C_ + coln[n]];
        }
        const int pi = (yy * 2 + wc) * 2;
#pragma unroll
        for (int m = 0; m < 4; ++m)
#pragma unroll
            for (int r = 0; r < 4; ++r) {
                float p0 = 0.f, p1 = 0.f;
#pragma unroll
                for (int n = 0; n < 4; ++n) {
                    float h = acc[m][n][r] + b1v[n];
                    float gl = h / (1.f + expf(-1.702f * h));
                    p0 = fmaf(gl, w20[n], p0);
                    p1 = fmaf(gl, w21[n], p1);
                }
#pragma unroll
                for (int off = 8; off; off >>= 1) {
                    p0 += __shfl_xor(p0, off, 16);
                    p1 += __shfl_xor(p1, off, 16);
                }
                if (lr == 0) {
                    int row = m0 + wr * 64 + m * 16 + lq * 4 + r;
                    partials[(size_t)row * 24 + pi + 0] = p0;
                    partials[(size_t)row * 24 + pi + 1] = p1;
                }
            }
    }
}

// ---------------------------------------------------------------------------
// gram_mfma: M = Ppw@Ppw^T*scale + eps*I from pre-split bf16 (3-term),
// output pre-split bf16 Mh/Ml, 224x224 per batch, rows/cols 196..223 zero.
// Inner loop = r15-verified pattern, K=256. Error ~1e-5 rel (tol 2e-2).
// ---------------------------------------------------------------------------
__global__ __launch_bounds__(256)
void gram_mfma(const short* __restrict__ Ph, const short* __restrict__ Pl,
               short* __restrict__ Mh_g, short* __restrict__ Ml_g, float scale)
{
    __shared__ short Ah[128 * 32], Al[128 * 32], Bh[128 * 32], Bl[128 * 32];
    const int tid = threadIdx.x;
    const int m0 = blockIdx.x * 128, n0 = blockIdx.y * 128;
    const int bz = blockIdx.z;
    const int l = tid & 63, wid = tid >> 6;
    const int wr = wid >> 1, wc = wid & 1;
    const int lr = l & 15, lq = l >> 4;

    const size_t rbase = (size_t)bz * Nv_;   // row base into Ppw (slack in-bounds)
    const int sr = wid * 32 + (l >> 2);
    const int sc = 8 * ((l & 3) ^ ((l >> 3) & 3));
    const short* a0  = Ph + (rbase + m0 + sr) * DPP_ + sc;
    const short* a1  = Ph + (rbase + m0 + sr + 16) * DPP_ + sc;
    const short* al0 = Pl + (rbase + m0 + sr) * DPP_ + sc;
    const short* al1 = Pl + (rbase + m0 + sr + 16) * DPP_ + sc;
    const short* b0  = Ph + (rbase + n0 + sr) * DPP_ + sc;
    const short* b1  = Ph + (rbase + n0 + sr + 16) * DPP_ + sc;
    const short* bl0 = Pl + (rbase + n0 + sr) * DPP_ + sc;
    const short* bl1 = Pl + (rbase + n0 + sr + 16) * DPP_ + sc;
    short* dA0  = &Ah[(wid * 32) * 32];
    short* dA1  = &Ah[(wid * 32 + 16) * 32];
    short* dAl0 = &Al[(wid * 32) * 32];
    short* dAl1 = &Al[(wid * 32 + 16) * 32];
    short* dB0  = &Bh[(wid * 32) * 32];
    short* dB1  = &Bh[(wid * 32 + 16) * 32];
    short* dBl0 = &Bl[(wid * 32) * 32];
    short* dBl1 = &Bl[(wid * 32 + 16) * 32];
    const int swzr = (lr >> 1) & 3;

    f32x4_t acc[4][4];
#pragma unroll
    for (int m = 0; m < 4; ++m)
#pragma unroll
        for (int n = 0; n < 4; ++n) {
            acc[m][n][0] = 0.f; acc[m][n][1] = 0.f;
            acc[m][n][2] = 0.f; acc[m][n][3] = 0.f;
        }

    for (int k0 = 0; k0 < DPP_; k0 += 32) {
        gload_lds16(a0  + k0, dA0);
        gload_lds16(a1  + k0, dA1);
        gload_lds16(al0 + k0, dAl0);
        gload_lds16(al1 + k0, dAl1);
        gload_lds16(b0  + k0, dB0);
        gload_lds16(b1  + k0, dB1);
        gload_lds16(bl0 + k0, dBl0);
        gload_lds16(bl1 + k0, dBl1);
        __syncthreads();
        bf16x8_t ahf[4], alf[4], bhf[4], blf[4];
#pragma unroll
        for (int m = 0; m < 4; ++m) {
            int ro = (wr * 64 + m * 16 + lr) * 32 + ((lq ^ swzr) * 8);
            ahf[m] = *(const bf16x8_t*)&Ah[ro];
            alf[m] = *(const bf16x8_t*)&Al[ro];
        }
#pragma unroll
        for (int n = 0; n < 4; ++n) {
            int ro = (wc * 64 + n * 16 + lr) * 32 + ((lq ^ swzr) * 8);
            bhf[n] = *(const bf16x8_t*)&Bh[ro];
            blf[n] = *(const bf16x8_t*)&Bl[ro];
        }
#pragma unroll
        for (int m = 0; m < 4; ++m)
#pragma unroll
            for (int n = 0; n < 4; ++n) {
                acc[m][n] = __builtin_amdgcn_mfma_f32_16x16x32_bf16(ahf[m], bhf[n], acc[m][n], 0, 0, 0);
                acc[m][n] = __builtin_amdgcn_mfma_f32_16x16x32_bf16(ahf[m], blf[n], acc[m][n], 0, 0, 0);
                acc[m][n] = __builtin_amdgcn_mfma_f32_16x16x32_bf16(alf[m], bhf[n], acc[m][n], 0, 0, 0);
            }
        __syncthreads();
    }

    short* Mhb = Mh_g + (size_t)bz * MS_ * MS_;
    short* Mlb = Ml_g + (size_t)bz * MS_ * MS_;
#pragma unroll
    for (int n = 0; n < 4; ++n) {
        int gc = n0 + wc * 64 + n * 16 + lr;
#pragma unroll
        for (int m = 0; m < 4; ++m) {
            int rowb = m0 + wr * 64 + m * 16 + lq * 4;
#pragma unroll
            for (int r = 0; r < 4; ++r) {
                int gr = rowb + r;
                if (gr < MS_ && gc < MS_) {
                    unsigned hh = 0, ll = 0;
                    if (gr < Nv_ && gc < Nv_) {
                        float v = acc[m][n][r] * scale;
                        if (gr == gc) v += 1e-5f;
                        split_bf16(v, hh, ll);
                    }
                    Mhb[(size_t)gr * MS_ + gc] = (short)hh;
                    Mlb[(size_t)gr * MS_ + gc] = (short)ll;
                }
            }
        }
    }
}

// ---------------------------------------------------------------------------
// taylor_mfma: M2 = M@M^T via 3-term MFMA (K=224, pads zero); epilogue
// computes trace partials t1..t4 (mij reconstructed = hi+lo), deterministic
// reduction -> tpart[bz][blk][4]. Same finalize as r14.
// ---------------------------------------------------------------------------
__global__ __launch_bounds__(256)
void taylor_mfma(const short* __restrict__ Mh_g, const short* __restrict__ Ml_g,
                 float* __restrict__ tpart)
{
    __shared__ short Ah[128 * 32], Al[128 * 32], Bh[128 * 32], Bl[128 * 32];
    __shared__ float wred[4][4];
    const int tid = threadIdx.x;
    const int m0 = blockIdx.x * 128, n0 = blockIdx.y * 128;
    const int bz = blockIdx.z;
    const int l = tid & 63, wid = tid >> 6;
    const int wr = wid >> 1, wc = wid & 1;
    const int lr = l & 15, lq = l >> 4;

    const size_t rbase = (size_t)bz * MS_;   // row base (slack slab in-bounds)
    const int sr = wid * 32 + (l >> 2);
    const int sc = 8 * ((l & 3) ^ ((l >> 3) & 3));
    const short* a0  = Mh_g + (rbase + m0 + sr) * MS_ + sc;
    const short* a1  = Mh_g + (rbase + m0 + sr + 16) * MS_ + sc;
    const short* al0 = Ml_g + (rbase + m0 + sr) * MS_ + sc;
    const short* al1 = Ml_g + (rbase + m0 + sr + 16) * MS_ + sc;
    const short* b0  = Mh_g + (rbase + n0 + sr) * MS_ + sc;
    const short* b1  = Mh_g + (rbase + n0 + sr + 16) * MS_ + sc;
    const short* bl0 = Ml_g + (rbase + n0 + sr) * MS_ + sc;
    const short* bl1 = Ml_g + (rbase + n0 + sr + 16) * MS_ + sc;
    short* dA0  = &Ah[(wid * 32) * 32];
    short* dA1  = &Ah[(wid * 32 + 16) * 32];
    short* dAl0 = &Al[(wid * 32) * 32];
    short* dAl1 = &Al[(wid * 32 + 16) * 32];
    short* dB0  = &Bh[(wid * 32) * 32];
    short* dB1  = &Bh[(wid * 32 + 16) * 32];
    short* dBl0 = &Bl[(wid * 32) * 32];
    short* dBl1 = &Bl[(wid * 32 + 16) * 32];
    const int swzr = (lr >> 1) & 3;

    f32x4_t acc[4][4];
#pragma unroll
    for (int m = 0; m < 4; ++m)
#pragma unroll
        for (int n = 0; n < 4; ++n) {
            acc[m][n][0] = 0.f; acc[m][n][1] = 0.f;
            acc[m][n][2] = 0.f; acc[m][n][3] = 0.f;
        }

    for (int k0 = 0; k0 < MS_; k0 += 32) {   // 7 k-steps
        gload_lds16(a0  + k0, dA0);
        gload_lds16(a1  + k0, dA1);
        gload_lds16(al0 + k0, dAl0);
        gload_lds16(al1 + k0, dAl1);
        gload_lds16(b0  + k0, dB0);
        gload_lds16(b1  + k0, dB1);
        gload_lds16(bl0 + k0, dBl0);
        gload_lds16(bl1 + k0, dBl1);
        __syncthreads();
        bf16x8_t ahf[4], alf[4], bhf[4], blf[4];
#pragma unroll
        for (int m = 0; m < 4; ++m) {
            int ro = (wr * 64 + m * 16 + lr) * 32 + ((lq ^ swzr) * 8);
            ahf[m] = *(const bf16x8_t*)&Ah[ro];
            alf[m] = *(const bf16x8_t*)&Al[ro];
        }
#pragma unroll
        for (int n = 0; n < 4; ++n) {
            int ro = (wc * 64 + n * 16 + lr) * 32 + ((lq ^ swzr) * 8);
            bhf[n] = *(const bf16x8_t*)&Bh[ro];
            blf[n] = *(const bf16x8_t*)&Bl[ro];
        }
#pragma unroll
        for (int m = 0; m < 4; ++m)
#pragma unroll
            for (int n = 0; n < 4; ++n) {
                acc[m][n] = __builtin_amdgcn_mfma_f32_16x16x32_bf16(ahf[m], bhf[n], acc[m][n], 0, 0, 0);
                acc[m][n] = __builtin_amdgcn_mfma_f32_16x16x32_bf16(ahf[m], blf[n], acc[m][n], 0, 0, 0);
                acc[m][n] = __builtin_amdgcn_mfma_f32_16x16x32_bf16(alf[m], bhf[n], acc[m][n], 0, 0, 0);
            }
        __syncthreads();
    }

    const short* Mhb = Mh_g + (size_t)bz * MS_ * MS_;
    const short* Mlb = Ml_g + (size_t)bz * MS_ * MS_;
    float t1 = 0.f, t2 = 0.f, t3 = 0.f, t4 = 0.f;
#pragma unroll
    for (int n = 0; n < 4; ++n) {
        int gc = n0 + wc * 64 + n * 16 + lr;
#pragma unroll
        for (int m = 0; m < 4; ++m) {
            int rowb = m0 + wr * 64 + m * 16 + lq * 4;
#pragma unroll
            for (int r = 0; r < 4; ++r) {
                int gr = rowb + r;
                if (gr < Nv_ && gc < Nv_) {
                    float mij = bf16_to_f(Mhb[(size_t)gr * MS_ + gc])
                              + bf16_to_f(Mlb[(size_t)gr * MS_ + gc]);
                    float m2 = acc[m][n][r];
                    if (gr == gc) t1 += mij;
                    t2 = fmaf(mij, mij, t2);
                    t3 = fmaf(m2, mij, t3);
                    t4 = fmaf(m2, m2, t4);
                }
            }
        }
    }
#pragma unroll
    for (int off = 32; off; off >>= 1) {
        t1 += __shfl_xor(t1, off, 64);
        t2 += __shfl_xor(t2, off, 64);
        t3 += __shfl_xor(t3, off, 64);
        t4 += __shfl_xor(t4, off, 64);
    }
    if (l == 0) {
        wred[wid][0] = t1; wred[wid][1] = t2; wred[wid][2] = t3; wred[wid][3] = t4;
    }
    __syncthreads();
    if (tid == 0) {
        const int blk = blockIdx.y * 2 + blockIdx.x;
        float* dst = tpart + ((size_t)bz * 4 + blk) * 4;
        dst[0] = wred[0][0] + wred[1][0] + wred[2][0] + wred[3][0];
        dst[1] = wred[0][1] + wred[1][1] + wred[2][1] + wred[3][1];
        dst[2] = wred[0][2] + wred[1][2] + wred[2][2] + wred[3][2];
        dst[3] = wred[0][3] + wred[1][3] + wred[2][3] + wred[3][3];
    }
}

// ---------------------------------------------------------------------------
// Attention per (b,h) — r10/r11-verified.
// ---------------------------------------------------------------------------
__global__ __launch_bounds__(256)
void attn_kernel(const float* __restrict__ q, const float* __restrict__ k,
                 const float* __restrict__ v, const float* __restrict__ x,
                 short* __restrict__ Fh, short* __restrict__ Fl)
{
    __shared__ float Ks[Lt_][DH_ + 4];
    __shared__ float Vs[Lt_][DH_ + 1];
    __shared__ float qs[16][DH_];
    __shared__ float as[16][Lt_];
    const int bh = blockIdx.x;
    const int b = bh / H_, h = bh - b * H_;
    const int tid = threadIdx.x;
    const int wv = tid >> 6, lane = tid & 63;
    const int half = lane >> 5;
    const int key = lane & 31;

    for (int idx = tid; idx < Lt_ * 16; idx += 256) {
        int l = idx >> 4, dq = (idx & 15) << 2;
        size_t off = ((size_t)(b * Lt_ + l)) * C_ + h * DH_ + dq;
        float4 kv4 = *(const float4*)(k + off);
        Ks[l][dq] = kv4.x; Ks[l][dq + 1] = kv4.y; Ks[l][dq + 2] = kv4.z; Ks[l][dq + 3] = kv4.w;
        float4 vv4 = *(const float4*)(v + off);
        Vs[l][dq] = vv4.x; Vs[l][dq + 1] = vv4.y; Vs[l][dq + 2] = vv4.z; Vs[l][dq + 3] = vv4.w;
    }
    __syncthreads();

    const size_t qbase = (size_t)b * Nv_ * C_ + h * DH_ + lane;
    const size_t xbase = (size_t)b * C_ + h * DH_ + lane;

    float qv[4], xv[4];
#pragma unroll
    for (int j = 0; j < 4; ++j) {
        qv[j] = q[qbase + (size_t)(wv * 4 + j) * C_];
        xv[j] = x[xbase + (size_t)(wv * 4 + j + 1) * B_ * C_];
    }

    for (int it = 0; it < 13; ++it) {
        const int base = it * 16 + wv * 4;
        if (base > 192) break;
        float cq[4], cx[4];
#pragma unroll
        for (int j = 0; j < 4; ++j) { cq[j] = qv[j]; cx[j] = xv[j]; }
        const int nbase = base + 16;
        if (nbase <= 192) {
#pragma unroll
            for (int j = 0; j < 4; ++j) {
                qv[j] = q[qbase + (size_t)(nbase + j) * C_];
                xv[j] = x[xbase + (size_t)(nbase + j + 1) * B_ * C_];
            }
        }
        const int ws = wv * 4;
#pragma unroll
        for (int j = 0; j < 4; ++j) qs[ws + j][lane] = cq[j];

        const int s0 = ws + half * 2;
        float s1 = 0.f, s2 = 0.f;
#pragma unroll
        for (int d4 = 0; d4 < DH_; d4 += 4) {
            float4 k4  = *(const float4*)&Ks[key][d4];
            float4 q4a = *(const float4*)&qs[s0][d4];
            float4 q4b = *(const float4*)&qs[s0 + 1][d4];
            s1 = fmaf(q4a.x, k4.x, s1); s2 = fmaf(q4b.x, k4.x, s2);
            s1 = fmaf(q4a.y, k4.y, s1); s2 = fmaf(q4b.y, k4.y, s2);
            s1 = fmaf(q4a.z, k4.z, s1); s2 = fmaf(q4b.z, k4.z, s2);
            s1 = fmaf(q4a.w, k4.w, s1); s2 = fmaf(q4b.w, k4.w, s2);
        }
        s1 *= 0.125f; s2 *= 0.125f;
        float mx1 = s1, mx2 = s2;
#pragma unroll
        for (int off = 16; off; off >>= 1) {
            mx1 = fmaxf(mx1, __shfl_xor(mx1, off, 32));
            mx2 = fmaxf(mx2, __shfl_xor(mx2, off, 32));
        }
        float p1v = expf(s1 - mx1);
        float p2v = expf(s2 - mx2);
        float su1 = p1v, su2 = p2v;
#pragma unroll
        for (int off = 16; off; off >>= 1) {
            su1 += __shfl_xor(su1, off, 32);
            su2 += __shfl_xor(su2, off, 32);
        }
        as[s0][key] = p1v / su1;
        as[s0 + 1][key] = p2v / su2;

        float c0 = 0.f, c1 = 0.f, c2 = 0.f, c3 = 0.f;
#pragma unroll
        for (int l4 = 0; l4 < Lt_; l4 += 4) {
            float4 a0 = *(const float4*)&as[ws + 0][l4];
            float4 a1 = *(const float4*)&as[ws + 1][l4];
            float4 a2 = *(const float4*)&as[ws + 2][l4];
            float4 a3 = *(const float4*)&as[ws + 3][l4];
            float v0 = Vs[l4 + 0][lane], v1 = Vs[l4 + 1][lane];
            float v2 = Vs[l4 + 2][lane], v3 = Vs[l4 + 3][lane];
            c0 = fmaf(a0.x, v0, c0); c1 = fmaf(a1.x, v0, c1);
            c2 = fmaf(a2.x, v0, c2); c3 = fmaf(a3.x, v0, c3);
            c0 = fmaf(a0.y, v1, c0); c1 = fmaf(a1.y, v1, c1);
            c2 = fmaf(a2.y, v1, c2); c3 = fmaf(a3.y, v1, c3);
            c0 = fmaf(a0.z, v2, c0); c1 = fmaf(a1.z, v2, c1);
            c2 = fmaf(a2.z, v2, c2); c3 = fmaf(a3.z, v2, c3);
            c0 = fmaf(a0.w, v3, c0); c1 = fmaf(a1.w, v3, c1);
            c2 = fmaf(a2.w, v3, c2); c3 = fmaf(a3.w, v3, c3);
        }
        float fo[4] = {c0 + cx[0], c1 + cx[1], c2 + cx[2], c3 + cx[3]};
#pragma unroll
        for (int j = 0; j < 4; ++j) {
            unsigned hh, ll;
            split_bf16(fo[j], hh, ll);
            Fh[qbase + (size_t)(base + j) * C_] = (short)hh;
            Fl[qbase + (size_t)(base + j) * C_] = (short)ll;
        }
    }
}

// ---------------------------------------------------------------------------
// keep decisions (r6-verified numerics)
// ---------------------------------------------------------------------------
__global__ __launch_bounds__(256)
void keep_kernel(const float* __restrict__ partials, const float* __restrict__ b2,
                 const float* __restrict__ gumbel, float* __restrict__ policy,
                 float* __restrict__ keep_prob)
{
    int m = blockIdx.x * 256 + threadIdx.x;
    int b = m / Nv_, n = m - b * Nv_;
    float l0 = b2[0], l1 = b2[1];
#pragma unroll
    for (int t = 0; t < 12; ++t) {
        l0 += partials[(size_t)m * 24 + t * 2 + 0];
        l1 += partials[(size_t)m * 24 + t * 2 + 1];
    }
    const float UHI = (float)(1.0 - 1e-6);
    float U0 = fminf(fmaxf(gumbel[(size_t)m * 2 + 0], 1e-6f), UHI);
    float U1 = fminf(fmaxf(gumbel[(size_t)m * 2 + 1], 1e-6f), UHI);
    float t0 = (float)log((double)U0);
    float g0 = -(float)log((double)(-t0));
    float t1 = (float)log((double)U1);
    float g1 = -(float)log((double)(-t1));
    float dlog = (l1 + g1) - (l0 + g0);
    float kp = 1.f / (1.f + expf(-dlog));
    policy[(size_t)b * 197 + 1 + n] = (dlog > 0.f) ? 1.f : 0.f;
    if (n == 0) policy[(size_t)b * 197] = 1.f;
    keep_prob[m] = kp;
}

__global__ __launch_bounds__(256)
void batch_reduce(const float* __restrict__ keep_prob, float* __restrict__ sum_kp)
{
    __shared__ float part[4];
    int b = blockIdx.x, tid = threadIdx.x;
    float vs = (tid < Nv_) ? keep_prob[(size_t)b * Nv_ + tid] : 0.f;
#pragma unroll
    for (int off = 32; off; off >>= 1) vs += __shfl_xor(vs, off, 64);
    if ((tid & 63) == 0) part[tid >> 6] = vs;
    __syncthreads();
    if (tid == 0) sum_kp[b] = part[0] + part[1] + part[2] + part[3];
}

// phi row-normalize*weight -> pre-split bf16 Ph/Pl (gram consumes split only)
__global__ __launch_bounds__(256)
void pw_scale(const float* __restrict__ phi, const float* __restrict__ keep_prob,
              const float* __restrict__ sum_kp,
              short* __restrict__ Ph, short* __restrict__ Pl)
{
    int m = blockIdx.x * 4 + (threadIdx.x >> 6);
    int lane = threadIdx.x & 63;
    const float4* row = (const float4*)phi + (size_t)m * 64;
    float4 vv = row[lane];
    float ss = vv.x * vv.x + vv.y * vv.y + vv.z * vv.z + vv.w * vv.w;
#pragma unroll
    for (int off = 32; off; off >>= 1) ss += __shfl_xor(ss, off, 64);
    float nrm = fmaxf(sqrtf(ss), 1e-12f);
    int b = m / Nv_;
    float kp = keep_prob[m];
    float meanw = sum_kp[b] * (1.f / 196.f);
    float wn = fmaxf(kp / (meanw + 1e-12f), 1e-6f);
    float sc = sqrtf(wn) / nrm;
    float vals[4] = {vv.x * sc, vv.y * sc, vv.z * sc, vv.w * sc};
    unsigned h[4], lo[4];
#pragma unroll
    for (int j = 0; j < 4; ++j) split_bf16(vals[j], h[j], lo[j]);
    uint2 Hp, Lp;
    Hp.x = h[0] | (h[1] << 16);  Hp.y = h[2] | (h[3] << 16);
    Lp.x = lo[0] | (lo[1] << 16); Lp.y = lo[2] | (lo[3] << 16);
    *(uint2*)&Ph[(size_t)m * DPP_ + lane * 4] = Hp;
    *(uint2*)&Pl[(size_t)m * DPP_ + lane * 4] = Lp;
}

// deterministic serial finalize: loss_ratio + Taylor logdet combine
__global__ void finalize_kernel(const float* __restrict__ sum_kp,
                                const float* __restrict__ tpart,
                                float* __restrict__ out)
{
    float tot = 0.f, ld = 0.f;
    for (int b = 0; b < B_; ++b) {
        tot += sum_kp[b];
        float s1 = 0.f, s2 = 0.f, s3 = 0.f, s4 = 0.f;
        for (int blk = 0; blk < 4; ++blk) {
            const float* p = tpart + ((size_t)b * 4 + blk) * 4;
            s1 += p[0]; s2 += p[1]; s3 += p[2]; s4 += p[3];
        }
        ld += s1 - 0.5f * s2 + (1.f / 3.f) * s3 - 0.25f * s4;
    }
    float mean = tot * (1.f / 25088.f);
    float d = mean - 0.7f;
    out[25216] = d * d;
    out[25217] = -ld * (1.f / 128.f);
}

// ---------------------------------------------------------------------------
extern "C" void kernel_launch(void* const* d_in, const int* in_sizes, int n_in,
                              void* d_out, int out_size, void* d_ws, size_t ws_size,
                              hipStream_t stream)
{
    const float* x      = (const float*)d_in[0];
    const float* text   = (const float*)d_in[1];
    const float* gumbel = (const float*)d_in[2];
    const float* Wq     = (const float*)d_in[3];
    const float* bq     = (const float*)d_in[4];
    const float* Wk     = (const float*)d_in[5];
    const float* bk     = (const float*)d_in[6];
    const float* Wv     = (const float*)d_in[7];
    const float* bv     = (const float*)d_in[8];
    const float* W1     = (const float*)d_in[9];
    const float* b1     = (const float*)d_in[10];
    const float* W2     = (const float*)d_in[11];
    const float* b2     = (const float*)d_in[12];
    const float* Wdpp   = (const float*)d_in[13];
    float* out = (float*)d_out;

    float* ws = (float*)d_ws;
    float* q          = ws;                       // 19,267,584 f ; Mh/Ml overlay
    float* kbuf       = q + 19267584;
    float* vbuf       = kbuf + 3145728;
    float* phi        = vbuf + 3145728;
    float* partials   = phi + 6422528;            // 602,112 f; tpart overlays
    float* keep_prob  = partials + 602112;
    float* sum_kp     = keep_prob + 25088;
    float* logdet_arr = sum_kp + 128;             // (layout keeper)
    float* tpart      = partials;                 // 2048 f (dead after keep)

    // M split (overlays q region, dead after attn): 129 slabs x 224 x 224
    short* Mh = (short*)ws;                       // 6,472,704 shorts
    short* Ml = Mh + 6472704;

    short* Wq_h = (short*)(logdet_arr + 128);
    short* Wq_l = Wq_h + 589824;
    short* W1_h = Wq_l + 589824;
    short* W1_l = W1_h + 589824;
    short* Wk_h = W1_l + 589824;
    short* Wk_l = Wk_h + 393216;
    short* Wv_h = Wk_l + 393216;
    short* Wv_l = Wv_h + 393216;
    short* Wd_h = Wv_l + 393216;
    short* Wd_l = Wd_h + 196608;
    short* Xh = Wd_l + 196608;                    // 19,267,584 shorts each
    short* Xl = Xh + 19267584;
    short* Th = Xl + 19267584;                    //  2,097,152 shorts each
    short* Tl = Th + 2097152;
    short* Fh = Xh;                               // overlay: X dead after q+phi
    short* Fl = Xl;
    short* Ph = Xh;                               // overlay: F dead after MLP
    short* Pl = Xl;                               // (needs 6.49M shorts, fits)

    dim3 blk(256);

    split_all<<<dim3(8448), blk, 0, stream>>>(Wq, W1, Wk, Wv, Wdpp,
                                              Wq_h, Wq_l, W1_h, W1_l,
                                              Wk_h, Wk_l, Wv_h, Wv_l,
                                              Wd_h, Wd_l);
    split_x<<<dim3(9408), blk, 0, stream>>>(x, Xh, Xl);
    split_text<<<dim3(1024), blk, 0, stream>>>(text, Th, Tl);

    // k+v projections merged by z
    mfma_gemm<0,0,0><<<dim3(32,6,2), blk, 0, stream>>>(
        Th, Tl, Wk_h, Wk_l, bk, kbuf, 768,
        Wv_h, Wv_l, bv, vbuf, 768, 512, nullptr, nullptr);
    // q + phi merged by y, XCD swizzle
    mfma_gemm<0,1,1><<<dim3(196,8,1), blk, 0, stream>>>(
        Xh, Xl, Wq_h, Wq_l, bq, q, 768,
        Wd_h, Wd_l, nullptr, phi, 256, 768, nullptr, nullptr);
    attn_kernel<<<dim3(B_*H_), blk, 0, stream>>>(q, kbuf, vbuf, x, Fh, Fl);
    // MLP with gelu/W2 epilogue, XCD swizzle
    mfma_gemm<1,0,1><<<dim3(196,6,1), blk, 0, stream>>>(
        Fh, Fl, W1_h, W1_l, b1, nullptr, 768,
        W1_h, W1_l, b1, nullptr, 768, 768, W2, partials);
    keep_kernel<<<dim3(98), blk, 0, stream>>>(partials, b2, gumbel, out, keep_prob);
    batch_reduce<<<dim3(B_), blk, 0, stream>>>(keep_prob, sum_kp);
    // pw -> pre-split Ph/Pl (overlays dead F region)
    pw_scale<<<dim3(6272), blk, 0, stream>>>(phi, keep_prob, sum_kp, Ph, Pl);
    // gram (MFMA) -> pre-split M (224x224, zero-padded), overlays dead q
    gram_mfma<<<dim3(2,2,B_), blk, 0, stream>>>(Ph, Pl, Mh, Ml,
                                                1.0f/(256.0f*196.0f*0.01f));
    // taylor traces (MFMA)
    taylor_mfma<<<dim3(2,2,B_), blk, 0, stream>>>(Mh, Ml, tpart);
    finalize_kernel<<<dim3(1), dim3(1), 0, stream>>>(sum_kp, tpart, out);
}

// Round 18
// 489.925 us; speedup vs baseline: 1.4631x; 1.0492x over previous
//
#include <hip/hip_runtime.h>
#include <math.h>

#define B_   128
#define L_   197
#define C_   768
#define Nv_  196
#define Lt_  32
#define Ct_  512
#define H_   12
#define DH_  64
#define DPP_ 256
#define MTOK 25088   // B_*Nv_
#define MS_  224     // padded M size (196 -> 224, rows and cols, zero pad)

typedef __attribute__((ext_vector_type(8))) short bf16x8_t;
typedef __attribute__((ext_vector_type(4))) float f32x4_t;

// async global->LDS, 16B per lane; dest = wave-uniform base + lane*16
__device__ __forceinline__ void gload_lds16(const short* g, short* l) {
    __builtin_amdgcn_global_load_lds(
        (const __attribute__((address_space(1))) unsigned int*)g,
        (__attribute__((address_space(3))) unsigned int*)l,
        16, 0, 0);
}

// split fp32 -> bf16 hi (truncate) + bf16 lo (RNE of remainder)
__device__ __forceinline__ void split_bf16(float a, unsigned &h, unsigned &l) {
    unsigned u = __float_as_uint(a);
    unsigned hu = u & 0xffff0000u;
    h = hu >> 16;
    float lf = a - __uint_as_float(hu);
    unsigned ul = __float_as_uint(lf);
    l = (ul + 0x7fffu + ((ul >> 16) & 1u)) >> 16;
}

__device__ __forceinline__ float bf16_to_f(short s) {
    return __uint_as_float(((unsigned)(unsigned short)s) << 16);
}

__device__ __forceinline__ void split8_pack(const float* av, uint4& Hh, uint4& Ll) {
    unsigned hv[8], lv[8];
#pragma unroll
    for (int j = 0; j < 8; ++j) split_bf16(av[j], hv[j], lv[j]);
    Hh.x = hv[0] | (hv[1] << 16); Hh.y = hv[2] | (hv[3] << 16);
    Hh.z = hv[4] | (hv[5] << 16); Hh.w = hv[6] | (hv[7] << 16);
    Ll.x = lv[0] | (lv[1] << 16); Ll.y = lv[2] | (lv[3] << 16);
    Ll.z = lv[4] | (lv[5] << 16); Ll.w = lv[6] | (lv[7] << 16);
}

// ---------------------------------------------------------------------------
// fused pre-splits: one launch covers weights + X-gather + text.
// Block ranges: [0,8448) weights, [8448,17856) X, [17856,18880) text.
// Bodies identical to r17's split_all / split_x / split_text.
// ---------------------------------------------------------------------------
#define NWQ 589824
#define NWK 393216
#define NWD 196608
__global__ __launch_bounds__(256)
void splits_fused(const float* __restrict__ Wq, const float* __restrict__ W1,
                  const float* __restrict__ Wk, const float* __restrict__ Wv,
                  const float* __restrict__ Wd,
                  short* __restrict__ Wq_h, short* __restrict__ Wq_l,
                  short* __restrict__ W1_h, short* __restrict__ W1_l,
                  short* __restrict__ Wk_h, short* __restrict__ Wk_l,
                  short* __restrict__ Wv_h, short* __restrict__ Wv_l,
                  short* __restrict__ Wd_h, short* __restrict__ Wd_l,
                  const float* __restrict__ x, short* __restrict__ Xh,
                  short* __restrict__ Xl,
                  const float* __restrict__ t, short* __restrict__ Th,
                  short* __restrict__ Tl)
{
    const int bid = blockIdx.x;
    if (bid < 8448) {
        int j = bid * 256 + threadIdx.x;
        const float* src; short *hi, *lo;
        if (j < NWQ)                { src = Wq; hi = Wq_h; lo = Wq_l; }
        else if ((j -= NWQ) < NWQ)  { src = W1; hi = W1_h; lo = W1_l; }
        else if ((j -= NWQ) < NWK)  { src = Wk; hi = Wk_h; lo = Wk_l; }
        else if ((j -= NWK) < NWK)  { src = Wv; hi = Wv_h; lo = Wv_l; }
        else                        { j -= NWK;  src = Wd; hi = Wd_h; lo = Wd_l; }
        unsigned h, l;
        split_bf16(src[j], h, l);
        hi[j] = (short)h; lo[j] = (short)l;
    } else if (bid < 17856) {
        int idx = (bid - 8448) * 256 + threadIdx.x;
        int m = idx / 96, c8 = (idx - m * 96) * 8;
        int b = m / Nv_, n = m - b * Nv_;
        const float* src = x + ((size_t)(n + 1) * B_ + b) * C_ + c8;
        float av[8];
        *(float4*)&av[0] = *(const float4*)src;
        *(float4*)&av[4] = *(const float4*)(src + 4);
        uint4 Hh, Ll;
        split8_pack(av, Hh, Ll);
        *(uint4*)&Xh[(size_t)m * C_ + c8] = Hh;
        *(uint4*)&Xl[(size_t)m * C_ + c8] = Ll;
    } else {
        int idx = (bid - 17856) * 256 + threadIdx.x;
        const float* src = t + (size_t)idx * 8;
        float av[8];
        *(float4*)&av[0] = *(const float4*)src;
        *(float4*)&av[4] = *(const float4*)(src + 4);
        uint4 Hh, Ll;
        split8_pack(av, Hh, Ll);
        *(uint4*)&Th[(size_t)idx * 8] = Hh;
        *(uint4*)&Tl[(size_t)idx * 8] = Ll;
    }
}

// ---------------------------------------------------------------------------
// mega_gemm: q + phi + k + v projections in ONE launch (1952 blocks).
//  id < 1568: q+phi with the r17-identical XCD swizzle (bit-identical tiles)
//  id >= 1568: kv pair (A = text split, Kd = 512)
// Inner loop = r15/r16/r17-verified: gld_lds width 16, linear 32KB LDS,
// both-sides XOR swizzle (0 bank conflicts), 3-term split-bf16 MFMA.
// ---------------------------------------------------------------------------
__global__ __launch_bounds__(256)
void mega_gemm(const short* __restrict__ Xh_g, const short* __restrict__ Xl_g,
               const short* __restrict__ Wqh, const short* __restrict__ Wql,
               const float* __restrict__ bq, float* __restrict__ qout,
               const short* __restrict__ Wdh, const short* __restrict__ Wdl,
               float* __restrict__ phiout,
               const short* __restrict__ Th_g, const short* __restrict__ Tl_g,
               const short* __restrict__ Wkh, const short* __restrict__ Wkl,
               const float* __restrict__ bk, float* __restrict__ kout,
               const short* __restrict__ Wvh, const short* __restrict__ Wvl,
               const float* __restrict__ bv, float* __restrict__ vout)
{
    const int id = blockIdx.x;
    const short *Ah_g, *Al_g, *Bh_g, *Bl_g;
    const float* bias; float* Cst;
    int Nst, Kd, m0, n0;
    if (id < 1568) {
        int g = (id & 7) * 196 + (id >> 3);     // r17 swizzle, total=1568
        int bx = g >> 3, by = g & 7;            // g/8, g%8 (NY=8)
        m0 = bx * 128;
        Ah_g = Xh_g; Al_g = Xl_g; Kd = 768;
        if (by >= 6) { Bh_g = Wdh; Bl_g = Wdl; bias = nullptr; Cst = phiout;
                       Nst = 256; n0 = (by - 6) * 128; }
        else         { Bh_g = Wqh; Bl_g = Wql; bias = bq; Cst = qout;
                       Nst = 768; n0 = by * 128; }
    } else {
        int id2 = id - 1568;                    // 0..383
        int z = id2 / 192, rem = id2 - z * 192;
        int bx = rem / 6, by = rem - (rem / 6) * 6;
        m0 = bx * 128; n0 = by * 128;
        Ah_g = Th_g; Al_g = Tl_g; Kd = 512; Nst = 768;
        if (z) { Bh_g = Wvh; Bl_g = Wvl; bias = bv; Cst = vout; }
        else   { Bh_g = Wkh; Bl_g = Wkl; bias = bk; Cst = kout; }
    }

    __shared__ short Ah[128 * 32], Al[128 * 32], Bh[128 * 32], Bl[128 * 32];
    const int tid = threadIdx.x;
    const int l = tid & 63, wid = tid >> 6;
    const int wr = wid >> 1, wc = wid & 1;
    const int lr = l & 15, lq = l >> 4;

    const int sr = wid * 32 + (l >> 2);
    const int sc = 8 * ((l & 3) ^ ((l >> 3) & 3));   // pre-swizzled chunk
    const short* a0  = Ah_g + (size_t)(m0 + sr) * Kd + sc;
    const short* a1  = Ah_g + (size_t)(m0 + sr + 16) * Kd + sc;
    const short* al0 = Al_g + (size_t)(m0 + sr) * Kd + sc;
    const short* al1 = Al_g + (size_t)(m0 + sr + 16) * Kd + sc;
    const short* b0  = Bh_g + (size_t)(n0 + sr) * Kd + sc;
    const short* b1  = Bh_g + (size_t)(n0 + sr + 16) * Kd + sc;
    const short* bl0 = Bl_g + (size_t)(n0 + sr) * Kd + sc;
    const short* bl1 = Bl_g + (size_t)(n0 + sr + 16) * Kd + sc;
    short* dA0  = &Ah[(wid * 32) * 32];
    short* dA1  = &Ah[(wid * 32 + 16) * 32];
    short* dAl0 = &Al[(wid * 32) * 32];
    short* dAl1 = &Al[(wid * 32 + 16) * 32];
    short* dB0  = &Bh[(wid * 32) * 32];
    short* dB1  = &Bh[(wid * 32 + 16) * 32];
    short* dBl0 = &Bl[(wid * 32) * 32];
    short* dBl1 = &Bl[(wid * 32 + 16) * 32];
    const int swzr = (lr >> 1) & 3;

    f32x4_t acc[4][4];
#pragma unroll
    for (int m = 0; m < 4; ++m)
#pragma unroll
        for (int n = 0; n < 4; ++n) {
            acc[m][n][0] = 0.f; acc[m][n][1] = 0.f;
            acc[m][n][2] = 0.f; acc[m][n][3] = 0.f;
        }

    for (int k0 = 0; k0 < Kd; k0 += 32) {
        gload_lds16(a0  + k0, dA0);
        gload_lds16(a1  + k0, dA1);
        gload_lds16(al0 + k0, dAl0);
        gload_lds16(al1 + k0, dAl1);
        gload_lds16(b0  + k0, dB0);
        gload_lds16(b1  + k0, dB1);
        gload_lds16(bl0 + k0, dBl0);
        gload_lds16(bl1 + k0, dBl1);
        __syncthreads();

        bf16x8_t ahf[4], alf[4], bhf[4], blf[4];
#pragma unroll
        for (int m = 0; m < 4; ++m) {
            int ro = (wr * 64 + m * 16 + lr) * 32 + ((lq ^ swzr) * 8);
            ahf[m] = *(const bf16x8_t*)&Ah[ro];
            alf[m] = *(const bf16x8_t*)&Al[ro];
        }
#pragma unroll
        for (int n = 0; n < 4; ++n) {
            int ro = (wc * 64 + n * 16 + lr) * 32 + ((lq ^ swzr) * 8);
            bhf[n] = *(const bf16x8_t*)&Bh[ro];
            blf[n] = *(const bf16x8_t*)&Bl[ro];
        }
#pragma unroll
        for (int m = 0; m < 4; ++m)
#pragma unroll
            for (int n = 0; n < 4; ++n) {
                acc[m][n] = __builtin_amdgcn_mfma_f32_16x16x32_bf16(ahf[m], bhf[n], acc[m][n], 0, 0, 0);
                acc[m][n] = __builtin_amdgcn_mfma_f32_16x16x32_bf16(ahf[m], blf[n], acc[m][n], 0, 0, 0);
                acc[m][n] = __builtin_amdgcn_mfma_f32_16x16x32_bf16(alf[m], bhf[n], acc[m][n], 0, 0, 0);
            }
        __syncthreads();
    }

#pragma unroll
    for (int n = 0; n < 4; ++n) {
        int col = n0 + wc * 64 + n * 16 + lr;
        float bv2 = bias ? bias[col] : 0.f;
#pragma unroll
        for (int m = 0; m < 4; ++m) {
            int rowb = m0 + wr * 64 + m * 16 + lq * 4;
#pragma unroll
            for (int r = 0; r < 4; ++r)
                Cst[(size_t)(rowb + r) * Nst + col] = acc[m][n][r] + bv2;
        }
    }
}

// ---------------------------------------------------------------------------
// MLP GEMM (r15/r16/r17-verified): EPI=1 gelu/W2 epilogue, XCD swizzle.
// ---------------------------------------------------------------------------
__global__ __launch_bounds__(256)
void mlp_gemm(const short* __restrict__ Ah_g, const short* __restrict__ Al_g,
              const short* __restrict__ Bh_g, const short* __restrict__ Bl_g,
              const float* __restrict__ bias, int Kd,
              const float* __restrict__ W2, float* __restrict__ partials)
{
    int bx = blockIdx.x, by = blockIdx.y;
    {
        const int NX = gridDim.x, NY = gridDim.y;
        const int total = NX * NY;
        int flat = by * NX + bx;
        int g = (flat & 7) * (total >> 3) + (flat >> 3);
        bx = g / NY; by = g % NY;
    }
    __shared__ short Ah[128 * 32], Al[128 * 32], Bh[128 * 32], Bl[128 * 32];
    const int tid = threadIdx.x;
    const int m0 = bx * 128, n0 = by * 128;
    const int l = tid & 63, wid = tid >> 6;
    const int wr = wid >> 1, wc = wid & 1;
    const int lr = l & 15, lq = l >> 4;

    const int sr = wid * 32 + (l >> 2);
    const int sc = 8 * ((l & 3) ^ ((l >> 3) & 3));
    const short* a0  = Ah_g + (size_t)(m0 + sr) * Kd + sc;
    const short* a1  = Ah_g + (size_t)(m0 + sr + 16) * Kd + sc;
    const short* al0 = Al_g + (size_t)(m0 + sr) * Kd + sc;
    const short* al1 = Al_g + (size_t)(m0 + sr + 16) * Kd + sc;
    const short* b0  = Bh_g + (size_t)(n0 + sr) * Kd + sc;
    const short* b1  = Bh_g + (size_t)(n0 + sr + 16) * Kd + sc;
    const short* bl0 = Bl_g + (size_t)(n0 + sr) * Kd + sc;
    const short* bl1 = Bl_g + (size_t)(n0 + sr + 16) * Kd + sc;
    short* dA0  = &Ah[(wid * 32) * 32];
    short* dA1  = &Ah[(wid * 32 + 16) * 32];
    short* dAl0 = &Al[(wid * 32) * 32];
    short* dAl1 = &Al[(wid * 32 + 16) * 32];
    short* dB0  = &Bh[(wid * 32) * 32];
    short* dB1  = &Bh[(wid * 32 + 16) * 32];
    short* dBl0 = &Bl[(wid * 32) * 32];
    short* dBl1 = &Bl[(wid * 32 + 16) * 32];
    const int swzr = (lr >> 1) & 3;

    f32x4_t acc[4][4];
#pragma unroll
    for (int m = 0; m < 4; ++m)
#pragma unroll
        for (int n = 0; n < 4; ++n) {
            acc[m][n][0] = 0.f; acc[m][n][1] = 0.f;
            acc[m][n][2] = 0.f; acc[m][n][3] = 0.f;
        }

    for (int k0 = 0; k0 < Kd; k0 += 32) {
        gload_lds16(a0  + k0, dA0);
        gload_lds16(a1  + k0, dA1);
        gload_lds16(al0 + k0, dAl0);
        gload_lds16(al1 + k0, dAl1);
        gload_lds16(b0  + k0, dB0);
        gload_lds16(b1  + k0, dB1);
        gload_lds16(bl0 + k0, dBl0);
        gload_lds16(bl1 + k0, dBl1);
        __syncthreads();
        bf16x8_t ahf[4], alf[4], bhf[4], blf[4];
#pragma unroll
        for (int m = 0; m < 4; ++m) {
            int ro = (wr * 64 + m * 16 + lr) * 32 + ((lq ^ swzr) * 8);
            ahf[m] = *(const bf16x8_t*)&Ah[ro];
            alf[m] = *(const bf16x8_t*)&Al[ro];
        }
#pragma unroll
        for (int n = 0; n < 4; ++n) {
            int ro = (wc * 64 + n * 16 + lr) * 32 + ((lq ^ swzr) * 8);
            bhf[n] = *(const bf16x8_t*)&Bh[ro];
            blf[n] = *(const bf16x8_t*)&Bl[ro];
        }
#pragma unroll
        for (int m = 0; m < 4; ++m)
#pragma unroll
            for (int n = 0; n < 4; ++n) {
                acc[m][n] = __builtin_amdgcn_mfma_f32_16x16x32_bf16(ahf[m], bhf[n], acc[m][n], 0, 0, 0);
                acc[m][n] = __builtin_amdgcn_mfma_f32_16x16x32_bf16(ahf[m], blf[n], acc[m][n], 0, 0, 0);
                acc[m][n] = __builtin_amdgcn_mfma_f32_16x16x32_bf16(alf[m], bhf[n], acc[m][n], 0, 0, 0);
            }
        __syncthreads();
    }

    int coln[4]; float b1v[4], w20[4], w21[4];
#pragma unroll
    for (int n = 0; n < 4; ++n) {
        coln[n] = n0 + wc * 64 + n * 16 + lr;
        b1v[n] = bias[coln[n]];
        w20[n] = W2[coln[n]];
        w21[n] = W2[C_ + coln[n]];
    }
    const int pi = (by * 2 + wc) * 2;
#pragma unroll
    for (int m = 0; m < 4; ++m)
#pragma unroll
        for (int r = 0; r < 4; ++r) {
            float p0 = 0.f, p1 = 0.f;
#pragma unroll
            for (int n = 0; n < 4; ++n) {
                float h = acc[m][n][r] + b1v[n];
                float gl = h / (1.f + expf(-1.702f * h));
                p0 = fmaf(gl, w20[n], p0);
                p1 = fmaf(gl, w21[n], p1);
            }
#pragma unroll
            for (int off = 8; off; off >>= 1) {
                p0 += __shfl_xor(p0, off, 16);
                p1 += __shfl_xor(p1, off, 16);
            }
            if (lr == 0) {
                int row = m0 + wr * 64 + m * 16 + lq * 4 + r;
                partials[(size_t)row * 24 + pi + 0] = p0;
                partials[(size_t)row * 24 + pi + 1] = p1;
            }
        }
}

// ---------------------------------------------------------------------------
// gram_mfma (r17-verified): M = Ppw@Ppw^T*scale + eps*I -> pre-split bf16.
// ---------------------------------------------------------------------------
__global__ __launch_bounds__(256)
void gram_mfma(const short* __restrict__ Ph, const short* __restrict__ Pl,
               short* __restrict__ Mh_g, short* __restrict__ Ml_g, float scale)
{
    __shared__ short Ah[128 * 32], Al[128 * 32], Bh[128 * 32], Bl[128 * 32];
    const int tid = threadIdx.x;
    const int m0 = blockIdx.x * 128, n0 = blockIdx.y * 128;
    const int bz = blockIdx.z;
    const int l = tid & 63, wid = tid >> 6;
    const int wr = wid >> 1, wc = wid & 1;
    const int lr = l & 15, lq = l >> 4;

    const size_t rbase = (size_t)bz * Nv_;
    const int sr = wid * 32 + (l >> 2);
    const int sc = 8 * ((l & 3) ^ ((l >> 3) & 3));
    const short* a0  = Ph + (rbase + m0 + sr) * DPP_ + sc;
    const short* a1  = Ph + (rbase + m0 + sr + 16) * DPP_ + sc;
    const short* al0 = Pl + (rbase + m0 + sr) * DPP_ + sc;
    const short* al1 = Pl + (rbase + m0 + sr + 16) * DPP_ + sc;
    const short* b0  = Ph + (rbase + n0 + sr) * DPP_ + sc;
    const short* b1  = Ph + (rbase + n0 + sr + 16) * DPP_ + sc;
    const short* bl0 = Pl + (rbase + n0 + sr) * DPP_ + sc;
    const short* bl1 = Pl + (rbase + n0 + sr + 16) * DPP_ + sc;
    short* dA0  = &Ah[(wid * 32) * 32];
    short* dA1  = &Ah[(wid * 32 + 16) * 32];
    short* dAl0 = &Al[(wid * 32) * 32];
    short* dAl1 = &Al[(wid * 32 + 16) * 32];
    short* dB0  = &Bh[(wid * 32) * 32];
    short* dB1  = &Bh[(wid * 32 + 16) * 32];
    short* dBl0 = &Bl[(wid * 32) * 32];
    short* dBl1 = &Bl[(wid * 32 + 16) * 32];
    const int swzr = (lr >> 1) & 3;

    f32x4_t acc[4][4];
#pragma unroll
    for (int m = 0; m < 4; ++m)
#pragma unroll
        for (int n = 0; n < 4; ++n) {
            acc[m][n][0] = 0.f; acc[m][n][1] = 0.f;
            acc[m][n][2] = 0.f; acc[m][n][3] = 0.f;
        }

    for (int k0 = 0; k0 < DPP_; k0 += 32) {
        gload_lds16(a0  + k0, dA0);
        gload_lds16(a1  + k0, dA1);
        gload_lds16(al0 + k0, dAl0);
        gload_lds16(al1 + k0, dAl1);
        gload_lds16(b0  + k0, dB0);
        gload_lds16(b1  + k0, dB1);
        gload_lds16(bl0 + k0, dBl0);
        gload_lds16(bl1 + k0, dBl1);
        __syncthreads();
        bf16x8_t ahf[4], alf[4], bhf[4], blf[4];
#pragma unroll
        for (int m = 0; m < 4; ++m) {
            int ro = (wr * 64 + m * 16 + lr) * 32 + ((lq ^ swzr) * 8);
            ahf[m] = *(const bf16x8_t*)&Ah[ro];
            alf[m] = *(const bf16x8_t*)&Al[ro];
        }
#pragma unroll
        for (int n = 0; n < 4; ++n) {
            int ro = (wc * 64 + n * 16 + lr) * 32 + ((lq ^ swzr) * 8);
            bhf[n] = *(const bf16x8_t*)&Bh[ro];
            blf[n] = *(const bf16x8_t*)&Bl[ro];
        }
#pragma unroll
        for (int m = 0; m < 4; ++m)
#pragma unroll
            for (int n = 0; n < 4; ++n) {
                acc[m][n] = __builtin_amdgcn_mfma_f32_16x16x32_bf16(ahf[m], bhf[n], acc[m][n], 0, 0, 0);
                acc[m][n] = __builtin_amdgcn_mfma_f32_16x16x32_bf16(ahf[m], blf[n], acc[m][n], 0, 0, 0);
                acc[m][n] = __builtin_amdgcn_mfma_f32_16x16x32_bf16(alf[m], bhf[n], acc[m][n], 0, 0, 0);
            }
        __syncthreads();
    }

    short* Mhb = Mh_g + (size_t)bz * MS_ * MS_;
    short* Mlb = Ml_g + (size_t)bz * MS_ * MS_;
#pragma unroll
    for (int n = 0; n < 4; ++n) {
        int gc = n0 + wc * 64 + n * 16 + lr;
#pragma unroll
        for (int m = 0; m < 4; ++m) {
            int rowb = m0 + wr * 64 + m * 16 + lq * 4;
#pragma unroll
            for (int r = 0; r < 4; ++r) {
                int gr = rowb + r;
                if (gr < MS_ && gc < MS_) {
                    unsigned hh = 0, ll = 0;
                    if (gr < Nv_ && gc < Nv_) {
                        float v = acc[m][n][r] * scale;
                        if (gr == gc) v += 1e-5f;
                        split_bf16(v, hh, ll);
                    }
                    Mhb[(size_t)gr * MS_ + gc] = (short)hh;
                    Mlb[(size_t)gr * MS_ + gc] = (short)ll;
                }
            }
        }
    }
}

// ---------------------------------------------------------------------------
// taylor_mfma (r17-verified): trace partials of M^2/M^3/M^4.
// ---------------------------------------------------------------------------
__global__ __launch_bounds__(256)
void taylor_mfma(const short* __restrict__ Mh_g, const short* __restrict__ Ml_g,
                 float* __restrict__ tpart)
{
    __shared__ short Ah[128 * 32], Al[128 * 32], Bh[128 * 32], Bl[128 * 32];
    __shared__ float wred[4][4];
    const int tid = threadIdx.x;
    const int m0 = blockIdx.x * 128, n0 = blockIdx.y * 128;
    const int bz = blockIdx.z;
    const int l = tid & 63, wid = tid >> 6;
    const int wr = wid >> 1, wc = wid & 1;
    const int lr = l & 15, lq = l >> 4;

    const size_t rbase = (size_t)bz * MS_;
    const int sr = wid * 32 + (l >> 2);
    const int sc = 8 * ((l & 3) ^ ((l >> 3) & 3));
    const short* a0  = Mh_g + (rbase + m0 + sr) * MS_ + sc;
    const short* a1  = Mh_g + (rbase + m0 + sr + 16) * MS_ + sc;
    const short* al0 = Ml_g + (rbase + m0 + sr) * MS_ + sc;
    const short* al1 = Ml_g + (rbase + m0 + sr + 16) * MS_ + sc;
    const short* b0  = Mh_g + (rbase + n0 + sr) * MS_ + sc;
    const short* b1  = Mh_g + (rbase + n0 + sr + 16) * MS_ + sc;
    const short* bl0 = Ml_g + (rbase + n0 + sr) * MS_ + sc;
    const short* bl1 = Ml_g + (rbase + n0 + sr + 16) * MS_ + sc;
    short* dA0  = &Ah[(wid * 32) * 32];
    short* dA1  = &Ah[(wid * 32 + 16) * 32];
    short* dAl0 = &Al[(wid * 32) * 32];
    short* dAl1 = &Al[(wid * 32 + 16) * 32];
    short* dB0  = &Bh[(wid * 32) * 32];
    short* dB1  = &Bh[(wid * 32 + 16) * 32];
    short* dBl0 = &Bl[(wid * 32) * 32];
    short* dBl1 = &Bl[(wid * 32 + 16) * 32];
    const int swzr = (lr >> 1) & 3;

    f32x4_t acc[4][4];
#pragma unroll
    for (int m = 0; m < 4; ++m)
#pragma unroll
        for (int n = 0; n < 4; ++n) {
            acc[m][n][0] = 0.f; acc[m][n][1] = 0.f;
            acc[m][n][2] = 0.f; acc[m][n][3] = 0.f;
        }

    for (int k0 = 0; k0 < MS_; k0 += 32) {
        gload_lds16(a0  + k0, dA0);
        gload_lds16(a1  + k0, dA1);
        gload_lds16(al0 + k0, dAl0);
        gload_lds16(al1 + k0, dAl1);
        gload_lds16(b0  + k0, dB0);
        gload_lds16(b1  + k0, dB1);
        gload_lds16(bl0 + k0, dBl0);
        gload_lds16(bl1 + k0, dBl1);
        __syncthreads();
        bf16x8_t ahf[4], alf[4], bhf[4], blf[4];
#pragma unroll
        for (int m = 0; m < 4; ++m) {
            int ro = (wr * 64 + m * 16 + lr) * 32 + ((lq ^ swzr) * 8);
            ahf[m] = *(const bf16x8_t*)&Ah[ro];
            alf[m] = *(const bf16x8_t*)&Al[ro];
        }
#pragma unroll
        for (int n = 0; n < 4; ++n) {
            int ro = (wc * 64 + n * 16 + lr) * 32 + ((lq ^ swzr) * 8);
            bhf[n] = *(const bf16x8_t*)&Bh[ro];
            blf[n] = *(const bf16x8_t*)&Bl[ro];
        }
#pragma unroll
        for (int m = 0; m < 4; ++m)
#pragma unroll
            for (int n = 0; n < 4; ++n) {
                acc[m][n] = __builtin_amdgcn_mfma_f32_16x16x32_bf16(ahf[m], bhf[n], acc[m][n], 0, 0, 0);
                acc[m][n] = __builtin_amdgcn_mfma_f32_16x16x32_bf16(ahf[m], blf[n], acc[m][n], 0, 0, 0);
                acc[m][n] = __builtin_amdgcn_mfma_f32_16x16x32_bf16(alf[m], bhf[n], acc[m][n], 0, 0, 0);
            }
        __syncthreads();
    }

    const short* Mhb = Mh_g + (size_t)bz * MS_ * MS_;
    const short* Mlb = Ml_g + (size_t)bz * MS_ * MS_;
    float t1 = 0.f, t2 = 0.f, t3 = 0.f, t4 = 0.f;
#pragma unroll
    for (int n = 0; n < 4; ++n) {
        int gc = n0 + wc * 64 + n * 16 + lr;
#pragma unroll
        for (int m = 0; m < 4; ++m) {
            int rowb = m0 + wr * 64 + m * 16 + lq * 4;
#pragma unroll
            for (int r = 0; r < 4; ++r) {
                int gr = rowb + r;
                if (gr < Nv_ && gc < Nv_) {
                    float mij = bf16_to_f(Mhb[(size_t)gr * MS_ + gc])
                              + bf16_to_f(Mlb[(size_t)gr * MS_ + gc]);
                    float m2 = acc[m][n][r];
                    if (gr == gc) t1 += mij;
                    t2 = fmaf(mij, mij, t2);
                    t3 = fmaf(m2, mij, t3);
                    t4 = fmaf(m2, m2, t4);
                }
            }
        }
    }
#pragma unroll
    for (int off = 32; off; off >>= 1) {
        t1 += __shfl_xor(t1, off, 64);
        t2 += __shfl_xor(t2, off, 64);
        t3 += __shfl_xor(t3, off, 64);
        t4 += __shfl_xor(t4, off, 64);
    }
    if (l == 0) {
        wred[wid][0] = t1; wred[wid][1] = t2; wred[wid][2] = t3; wred[wid][3] = t4;
    }
    __syncthreads();
    if (tid == 0) {
        const int blk = blockIdx.y * 2 + blockIdx.x;
        float* dst = tpart + ((size_t)bz * 4 + blk) * 4;
        dst[0] = wred[0][0] + wred[1][0] + wred[2][0] + wred[3][0];
        dst[1] = wred[0][1] + wred[1][1] + wred[2][1] + wred[3][1];
        dst[2] = wred[0][2] + wred[1][2] + wred[2][2] + wred[3][2];
        dst[3] = wred[0][3] + wred[1][3] + wred[2][3] + wred[3][3];
    }
}

// ---------------------------------------------------------------------------
// Attention per (b,h) — r10/r11-verified.
// ---------------------------------------------------------------------------
__global__ __launch_bounds__(256)
void attn_kernel(const float* __restrict__ q, const float* __restrict__ k,
                 const float* __restrict__ v, const float* __restrict__ x,
                 short* __restrict__ Fh, short* __restrict__ Fl)
{
    __shared__ float Ks[Lt_][DH_ + 4];
    __shared__ float Vs[Lt_][DH_ + 1];
    __shared__ float qs[16][DH_];
    __shared__ float as[16][Lt_];
    const int bh = blockIdx.x;
    const int b = bh / H_, h = bh - b * H_;
    const int tid = threadIdx.x;
    const int wv = tid >> 6, lane = tid & 63;
    const int half = lane >> 5;
    const int key = lane & 31;

    for (int idx = tid; idx < Lt_ * 16; idx += 256) {
        int l = idx >> 4, dq = (idx & 15) << 2;
        size_t off = ((size_t)(b * Lt_ + l)) * C_ + h * DH_ + dq;
        float4 kv4 = *(const float4*)(k + off);
        Ks[l][dq] = kv4.x; Ks[l][dq + 1] = kv4.y; Ks[l][dq + 2] = kv4.z; Ks[l][dq + 3] = kv4.w;
        float4 vv4 = *(const float4*)(v + off);
        Vs[l][dq] = vv4.x; Vs[l][dq + 1] = vv4.y; Vs[l][dq + 2] = vv4.z; Vs[l][dq + 3] = vv4.w;
    }
    __syncthreads();

    const size_t qbase = (size_t)b * Nv_ * C_ + h * DH_ + lane;
    const size_t xbase = (size_t)b * C_ + h * DH_ + lane;

    float qv[4], xv[4];
#pragma unroll
    for (int j = 0; j < 4; ++j) {
        qv[j] = q[qbase + (size_t)(wv * 4 + j) * C_];
        xv[j] = x[xbase + (size_t)(wv * 4 + j + 1) * B_ * C_];
    }

    for (int it = 0; it < 13; ++it) {
        const int base = it * 16 + wv * 4;
        if (base > 192) break;
        float cq[4], cx[4];
#pragma unroll
        for (int j = 0; j < 4; ++j) { cq[j] = qv[j]; cx[j] = xv[j]; }
        const int nbase = base + 16;
        if (nbase <= 192) {
#pragma unroll
            for (int j = 0; j < 4; ++j) {
                qv[j] = q[qbase + (size_t)(nbase + j) * C_];
                xv[j] = x[xbase + (size_t)(nbase + j + 1) * B_ * C_];
            }
        }
        const int ws = wv * 4;
#pragma unroll
        for (int j = 0; j < 4; ++j) qs[ws + j][lane] = cq[j];

        const int s0 = ws + half * 2;
        float s1 = 0.f, s2 = 0.f;
#pragma unroll
        for (int d4 = 0; d4 < DH_; d4 += 4) {
            float4 k4  = *(const float4*)&Ks[key][d4];
            float4 q4a = *(const float4*)&qs[s0][d4];
            float4 q4b = *(const float4*)&qs[s0 + 1][d4];
            s1 = fmaf(q4a.x, k4.x, s1); s2 = fmaf(q4b.x, k4.x, s2);
            s1 = fmaf(q4a.y, k4.y, s1); s2 = fmaf(q4b.y, k4.y, s2);
            s1 = fmaf(q4a.z, k4.z, s1); s2 = fmaf(q4b.z, k4.z, s2);
            s1 = fmaf(q4a.w, k4.w, s1); s2 = fmaf(q4b.w, k4.w, s2);
        }
        s1 *= 0.125f; s2 *= 0.125f;
        float mx1 = s1, mx2 = s2;
#pragma unroll
        for (int off = 16; off; off >>= 1) {
            mx1 = fmaxf(mx1, __shfl_xor(mx1, off, 32));
            mx2 = fmaxf(mx2, __shfl_xor(mx2, off, 32));
        }
        float p1v = expf(s1 - mx1);
        float p2v = expf(s2 - mx2);
        float su1 = p1v, su2 = p2v;
#pragma unroll
        for (int off = 16; off; off >>= 1) {
            su1 += __shfl_xor(su1, off, 32);
            su2 += __shfl_xor(su2, off, 32);
        }
        as[s0][key] = p1v / su1;
        as[s0 + 1][key] = p2v / su2;

        float c0 = 0.f, c1 = 0.f, c2 = 0.f, c3 = 0.f;
#pragma unroll
        for (int l4 = 0; l4 < Lt_; l4 += 4) {
            float4 a0 = *(const float4*)&as[ws + 0][l4];
            float4 a1 = *(const float4*)&as[ws + 1][l4];
            float4 a2 = *(const float4*)&as[ws + 2][l4];
            float4 a3 = *(const float4*)&as[ws + 3][l4];
            float v0 = Vs[l4 + 0][lane], v1 = Vs[l4 + 1][lane];
            float v2 = Vs[l4 + 2][lane], v3 = Vs[l4 + 3][lane];
            c0 = fmaf(a0.x, v0, c0); c1 = fmaf(a1.x, v0, c1);
            c2 = fmaf(a2.x, v0, c2); c3 = fmaf(a3.x, v0, c3);
            c0 = fmaf(a0.y, v1, c0); c1 = fmaf(a1.y, v1, c1);
            c2 = fmaf(a2.y, v1, c2); c3 = fmaf(a3.y, v1, c3);
            c0 = fmaf(a0.z, v2, c0); c1 = fmaf(a1.z, v2, c1);
            c2 = fmaf(a2.z, v2, c2); c3 = fmaf(a3.z, v2, c3);
            c0 = fmaf(a0.w, v3, c0); c1 = fmaf(a1.w, v3, c1);
            c2 = fmaf(a2.w, v3, c2); c3 = fmaf(a3.w, v3, c3);
        }
        float fo[4] = {c0 + cx[0], c1 + cx[1], c2 + cx[2], c3 + cx[3]};
#pragma unroll
        for (int j = 0; j < 4; ++j) {
            unsigned hh, ll;
            split_bf16(fo[j], hh, ll);
            Fh[qbase + (size_t)(base + j) * C_] = (short)hh;
            Fl[qbase + (size_t)(base + j) * C_] = (short)ll;
        }
    }
}

// ---------------------------------------------------------------------------
// keep + batch_reduce fused: one block per batch. kp math identical to r17;
// reduction identical to r17's batch_reduce (tid<196 ? kp : 0, 64-wide
// butterfly, 4 parts) -> sum_kp bit-identical.
// ---------------------------------------------------------------------------
__global__ __launch_bounds__(256)
void keep_fused(const float* __restrict__ partials, const float* __restrict__ b2,
                const float* __restrict__ gumbel, float* __restrict__ policy,
                float* __restrict__ keep_prob, float* __restrict__ sum_kp)
{
    __shared__ float part[4];
    const int b = blockIdx.x, tid = threadIdx.x;
    float kp = 0.f;
    if (tid < Nv_) {
        int m = b * Nv_ + tid;
        float l0 = b2[0], l1 = b2[1];
#pragma unroll
        for (int t = 0; t < 12; ++t) {
            l0 += partials[(size_t)m * 24 + t * 2 + 0];
            l1 += partials[(size_t)m * 24 + t * 2 + 1];
        }
        const float UHI = (float)(1.0 - 1e-6);
        float U0 = fminf(fmaxf(gumbel[(size_t)m * 2 + 0], 1e-6f), UHI);
        float U1 = fminf(fmaxf(gumbel[(size_t)m * 2 + 1], 1e-6f), UHI);
        float t0 = (float)log((double)U0);
        float g0 = -(float)log((double)(-t0));
        float t1 = (float)log((double)U1);
        float g1 = -(float)log((double)(-t1));
        float dlog = (l1 + g1) - (l0 + g0);
        kp = 1.f / (1.f + expf(-dlog));
        policy[(size_t)b * 197 + 1 + tid] = (dlog > 0.f) ? 1.f : 0.f;
        keep_prob[m] = kp;
    }
    if (tid == 0) policy[(size_t)b * 197] = 1.f;
    float vs = kp;
#pragma unroll
    for (int off = 32; off; off >>= 1) vs += __shfl_xor(vs, off, 64);
    if ((tid & 63) == 0) part[tid >> 6] = vs;
    __syncthreads();
    if (tid == 0) sum_kp[b] = part[0] + part[1] + part[2] + part[3];
}

// phi row-normalize*weight -> pre-split bf16 Ph/Pl (r17-verified)
__global__ __launch_bounds__(256)
void pw_scale(const float* __restrict__ phi, const float* __restrict__ keep_prob,
              const float* __restrict__ sum_kp,
              short* __restrict__ Ph, short* __restrict__ Pl)
{
    int m = blockIdx.x * 4 + (threadIdx.x >> 6);
    int lane = threadIdx.x & 63;
    const float4* row = (const float4*)phi + (size_t)m * 64;
    float4 vv = row[lane];
    float ss = vv.x * vv.x + vv.y * vv.y + vv.z * vv.z + vv.w * vv.w;
#pragma unroll
    for (int off = 32; off; off >>= 1) ss += __shfl_xor(ss, off, 64);
    float nrm = fmaxf(sqrtf(ss), 1e-12f);
    int b = m / Nv_;
    float kp = keep_prob[m];
    float meanw = sum_kp[b] * (1.f / 196.f);
    float wn = fmaxf(kp / (meanw + 1e-12f), 1e-6f);
    float sc = sqrtf(wn) / nrm;
    float vals[4] = {vv.x * sc, vv.y * sc, vv.z * sc, vv.w * sc};
    unsigned h[4], lo[4];
#pragma unroll
    for (int j = 0; j < 4; ++j) split_bf16(vals[j], h[j], lo[j]);
    uint2 Hp, Lp;
    Hp.x = h[0] | (h[1] << 16);  Hp.y = h[2] | (h[3] << 16);
    Lp.x = lo[0] | (lo[1] << 16); Lp.y = lo[2] | (lo[3] << 16);
    *(uint2*)&Ph[(size_t)m * DPP_ + lane * 4] = Hp;
    *(uint2*)&Pl[(size_t)m * DPP_ + lane * 4] = Lp;
}

// deterministic serial finalize (r14-verified)
__global__ void finalize_kernel(const float* __restrict__ sum_kp,
                                const float* __restrict__ tpart,
                                float* __restrict__ out)
{
    float tot = 0.f, ld = 0.f;
    for (int b = 0; b < B_; ++b) {
        tot += sum_kp[b];
        float s1 = 0.f, s2 = 0.f, s3 = 0.f, s4 = 0.f;
        for (int blk = 0; blk < 4; ++blk) {
            const float* p = tpart + ((size_t)b * 4 + blk) * 4;
            s1 += p[0]; s2 += p[1]; s3 += p[2]; s4 += p[3];
        }
        ld += s1 - 0.5f * s2 + (1.f / 3.f) * s3 - 0.25f * s4;
    }
    float mean = tot * (1.f / 25088.f);
    float d = mean - 0.7f;
    out[25216] = d * d;
    out[25217] = -ld * (1.f / 128.f);
}

// ---------------------------------------------------------------------------
extern "C" void kernel_launch(void* const* d_in, const int* in_sizes, int n_in,
                              void* d_out, int out_size, void* d_ws, size_t ws_size,
                              hipStream_t stream)
{
    const float* x      = (const float*)d_in[0];
    const float* text   = (const float*)d_in[1];
    const float* gumbel = (const float*)d_in[2];
    const float* Wq     = (const float*)d_in[3];
    const float* bq     = (const float*)d_in[4];
    const float* Wk     = (const float*)d_in[5];
    const float* bk     = (const float*)d_in[6];
    const float* Wv     = (const float*)d_in[7];
    const float* bv     = (const float*)d_in[8];
    const float* W1     = (const float*)d_in[9];
    const float* b1     = (const float*)d_in[10];
    const float* W2     = (const float*)d_in[11];
    const float* b2     = (const float*)d_in[12];
    const float* Wdpp   = (const float*)d_in[13];
    float* out = (float*)d_out;

    float* ws = (float*)d_ws;
    float* q          = ws;                       // 19,267,584 f ; Mh/Ml overlay
    float* kbuf       = q + 19267584;
    float* vbuf       = kbuf + 3145728;
    float* phi        = vbuf + 3145728;
    float* partials   = phi + 6422528;            // 602,112 f; tpart overlays
    float* keep_prob  = partials + 602112;
    float* sum_kp     = keep_prob + 25088;
    float* logdet_arr = sum_kp + 128;             // (layout keeper)
    float* tpart      = partials;                 // dead after keep

    short* Mh = (short*)ws;                       // 129 slabs x 224 x 224
    short* Ml = Mh + 6472704;

    short* Wq_h = (short*)(logdet_arr + 128);
    short* Wq_l = Wq_h + 589824;
    short* W1_h = Wq_l + 589824;
    short* W1_l = W1_h + 589824;
    short* Wk_h = W1_l + 589824;
    short* Wk_l = Wk_h + 393216;
    short* Wv_h = Wk_l + 393216;
    short* Wv_l = Wv_h + 393216;
    short* Wd_h = Wv_l + 393216;
    short* Wd_l = Wd_h + 196608;
    short* Xh = Wd_l + 196608;                    // 19,267,584 shorts each
    short* Xl = Xh + 19267584;
    short* Th = Xl + 19267584;                    //  2,097,152 shorts each
    short* Tl = Th + 2097152;
    short* Fh = Xh;                               // overlay: X dead after mega
    short* Fl = Xl;
    short* Ph = Xh;                               // overlay: F dead after MLP
    short* Pl = Xl;

    dim3 blk(256);

    // all pre-splits in one launch (weights + X-gather + text)
    splits_fused<<<dim3(18880), blk, 0, stream>>>(
        Wq, W1, Wk, Wv, Wdpp,
        Wq_h, Wq_l, W1_h, W1_l, Wk_h, Wk_l, Wv_h, Wv_l, Wd_h, Wd_l,
        x, Xh, Xl, text, Th, Tl);

    // q + phi + k + v in ONE launch (1952 blocks)
    mega_gemm<<<dim3(1952), blk, 0, stream>>>(
        Xh, Xl, Wq_h, Wq_l, bq, q, Wd_h, Wd_l, phi,
        Th, Tl, Wk_h, Wk_l, bk, kbuf, Wv_h, Wv_l, bv, vbuf);

    attn_kernel<<<dim3(B_*H_), blk, 0, stream>>>(q, kbuf, vbuf, x, Fh, Fl);

    // MLP with gelu/W2 epilogue, XCD swizzle
    mlp_gemm<<<dim3(196,6,1), blk, 0, stream>>>(
        Fh, Fl, W1_h, W1_l, b1, 768, W2, partials);

    // keep + batch reduce fused (one block per batch)
    keep_fused<<<dim3(B_), blk, 0, stream>>>(partials, b2, gumbel, out,
                                             keep_prob, sum_kp);
    pw_scale<<<dim3(6272), blk, 0, stream>>>(phi, keep_prob, sum_kp, Ph, Pl);
    gram_mfma<<<dim3(2,2,B_), blk, 0, stream>>>(Ph, Pl, Mh, Ml,
                                                1.0f/(256.0f*196.0f*0.01f));
    taylor_mfma<<<dim3(2,2,B_), blk, 0, stream>>>(Mh, Ml, tpart);
    finalize_kernel<<<dim3(1), dim3(1), 0, stream>>>(sum_kp, tpart, out);
}